// Round 4
// baseline (2643.162 us; speedup 1.0000x reference)
//
#include <hip/hip_runtime.h>
#include <hip/hip_bf16.h>
#include <math.h>

#define TOKENS 2048
#define HIDDEN 2048
#define NH 16
#define HD 128
#define SEQ 1024
#define MOE_I 1408
#define SH_I 5632
#define K3 6144   // 3*HIDDEN cat-K for 2-limb split GEMMs

typedef __hip_bfloat16 bf16;
typedef short bf16x8 __attribute__((ext_vector_type(8)));
typedef short bf16x4 __attribute__((ext_vector_type(4)));
typedef float f32x4 __attribute__((ext_vector_type(4)));

__device__ __forceinline__ float b2f(bf16 x) { return __bfloat162float(x); }
__device__ __forceinline__ bf16 f2b(float x) { return __float2bfloat16(x); }
__device__ __forceinline__ short bcast(bf16 x) { return __builtin_bit_cast(short, x); }
// 2-limb split: v ~= hi + lo, |v - hi - lo| <= 2^-18 |v|
__device__ __forceinline__ void split2(float v, short& hi, short& lo) {
    bf16 h = f2b(v);
    bf16 l = f2b(v - b2f(h));
    hi = bcast(h); lo = bcast(l);
}

__device__ __forceinline__ void load_lds16(const void* g, void* l) {
    __builtin_amdgcn_global_load_lds(
        (const __attribute__((address_space(1))) unsigned int*)g,
        (__attribute__((address_space(3))) unsigned int*)l, 16, 0, 0);
}

// ---------------------------------------------------------------------------
// RMSNorm (plain): fp32 row -> bf16 row. One block of 256 per row.
__global__ __launch_bounds__(256) void rmsnorm_k(
    const float* __restrict__ x, const float* __restrict__ w, bf16* __restrict__ out)
{
    const int row = blockIdx.x, tid = threadIdx.x;
    const float4* xr = (const float4*)(x + (size_t)row * HIDDEN);
    float4 v1 = xr[tid], v2 = xr[tid + 256];
    float ss = v1.x*v1.x + v1.y*v1.y + v1.z*v1.z + v1.w*v1.w
             + v2.x*v2.x + v2.y*v2.y + v2.z*v2.z + v2.w*v2.w;
    #pragma unroll
    for (int off = 1; off < 64; off <<= 1) ss += __shfl_xor(ss, off);
    __shared__ float ps[4];
    if ((tid & 63) == 0) ps[tid >> 6] = ss;
    __syncthreads();
    float tot = ps[0] + ps[1] + ps[2] + ps[3];
    float r = rsqrtf(tot * (1.0f / HIDDEN) + 1e-6f);
    int i1 = tid * 4, i2 = 1024 + tid * 4;
    bf16* o = out + (size_t)row * HIDDEN;
    o[i1+0] = f2b(v1.x * r * w[i1+0]);
    o[i1+1] = f2b(v1.y * r * w[i1+1]);
    o[i1+2] = f2b(v1.z * r * w[i1+2]);
    o[i1+3] = f2b(v1.w * r * w[i1+3]);
    o[i2+0] = f2b(v2.x * r * w[i2+0]);
    o[i2+1] = f2b(v2.y * r * w[i2+1]);
    o[i2+2] = f2b(v2.z * r * w[i2+2]);
    o[i2+3] = f2b(v2.w * r * w[i2+3]);
}

// RMSNorm + 2-limb split to cat layout [row][K3]: [0..H)=hi, [H..2H)=lo, [2H..3H)=hi
__global__ __launch_bounds__(256) void rmsnorm3_k(
    const float* __restrict__ x, const float* __restrict__ w, bf16* __restrict__ out)
{
    const int row = blockIdx.x, tid = threadIdx.x;
    const float4* xr = (const float4*)(x + (size_t)row * HIDDEN);
    float4 v1 = xr[tid], v2 = xr[tid + 256];
    float ss = v1.x*v1.x + v1.y*v1.y + v1.z*v1.z + v1.w*v1.w
             + v2.x*v2.x + v2.y*v2.y + v2.z*v2.z + v2.w*v2.w;
    #pragma unroll
    for (int off = 1; off < 64; off <<= 1) ss += __shfl_xor(ss, off);
    __shared__ float ps[4];
    if ((tid & 63) == 0) ps[tid >> 6] = ss;
    __syncthreads();
    float tot = ps[0] + ps[1] + ps[2] + ps[3];
    float r = rsqrtf(tot * (1.0f / HIDDEN) + 1e-6f);
    bf16* o = out + (size_t)row * K3;
    float vv[8] = {v1.x, v1.y, v1.z, v1.w, v2.x, v2.y, v2.z, v2.w};
    int idx[8]  = {tid*4, tid*4+1, tid*4+2, tid*4+3,
                   1024+tid*4, 1024+tid*4+1, 1024+tid*4+2, 1024+tid*4+3};
    #pragma unroll
    for (int u = 0; u < 8; u++) {
        short hi, lo; split2(vv[u] * r * w[idx[u]], hi, lo);
        bf16 hb = __builtin_bit_cast(bf16, hi), lb = __builtin_bit_cast(bf16, lo);
        o[idx[u]] = hb; o[HIDDEN + idx[u]] = lb; o[2*HIDDEN + idx[u]] = hb;
    }
}

// ---------------------------------------------------------------------------
// Plain transpose+convert: W (K x N fp32) -> Wt (N x K bf16)
__global__ __launch_bounds__(256) void transpose_w(
    const float* __restrict__ W, bf16* __restrict__ Wt, int K, int N)
{
    __shared__ float t[32][33];
    const int n0 = blockIdx.x * 32, k0 = blockIdx.y * 32;
    const int tx = threadIdx.x & 31, ty = threadIdx.x >> 5;
    #pragma unroll
    for (int i = 0; i < 4; i++)
        t[ty + i*8][tx] = W[(size_t)(k0 + ty + i*8) * N + n0 + tx];
    __syncthreads();
    #pragma unroll
    for (int i = 0; i < 4; i++)
        Wt[(size_t)(n0 + ty + i*8) * K + k0 + tx] = f2b(t[tx][ty + i*8]);
}

// Split transpose: W (K x N fp32) -> Wt2 (N x 3K bf16), [0..K)=hi, [K..2K)=hi, [2K..3K)=lo
__global__ __launch_bounds__(256) void transpose_w3(
    const float* __restrict__ W, bf16* __restrict__ Wt2, int K, int N)
{
    __shared__ float t[32][33];
    const int n0 = blockIdx.x * 32, k0 = blockIdx.y * 32;
    const int tx = threadIdx.x & 31, ty = threadIdx.x >> 5;
    #pragma unroll
    for (int i = 0; i < 4; i++)
        t[ty + i*8][tx] = W[(size_t)(k0 + ty + i*8) * N + n0 + tx];
    __syncthreads();
    #pragma unroll
    for (int i = 0; i < 4; i++) {
        float v = t[tx][ty + i*8];
        short hi, lo; split2(v, hi, lo);
        bf16 hb = __builtin_bit_cast(bf16, hi), lb = __builtin_bit_cast(bf16, lo);
        bf16* o = Wt2 + (size_t)(n0 + ty + i*8) * (3*K) + k0 + tx;
        o[0] = hb; o[K] = hb; o[2*K] = lb;
    }
}

// ---------------------------------------------------------------------------
// GEMM: C[M,N] = A[M,K](bf16) @ Bt[N,K](bf16)^T, 128x128x32 tile.
// epi: 0=bf16, 1=bf16+bias, 2=f32+resid, 3=f32 += rowscale*acc, 4=f32, 5=f32+bias
__global__ __launch_bounds__(256) void gemm_bt(
    const bf16* __restrict__ A, const bf16* __restrict__ Bt,
    float* __restrict__ Cf, bf16* __restrict__ Cb,
    const float* __restrict__ bias, const float* __restrict__ resid,
    const float* __restrict__ rowscale, int rs_stride,
    int M, int N, int K, int epi)
{
    __shared__ __align__(16) bf16 As[128 * 32];
    __shared__ __align__(16) bf16 Bs[128 * 32];
    const int tid = threadIdx.x;
    const int lane = tid & 63, wid = tid >> 6;
    const int l16 = lane & 15, lh = lane >> 4;
    const int wr = wid >> 1, wc = wid & 1;
    const int m0 = blockIdx.x * 128, n0 = blockIdx.y * 128;
    const int f = tid * 8;
    const int r0 = f >> 5, c0 = f & 31;

    f32x4 acc[4][4];
    #pragma unroll
    for (int m = 0; m < 4; m++)
        #pragma unroll
        for (int n = 0; n < 4; n++) acc[m][n] = (f32x4){0.f, 0.f, 0.f, 0.f};

    const bf16* Ag0 = A + (size_t)(m0 + r0) * K + c0;
    const bf16* Ag1 = Ag0 + (size_t)64 * K;
    const bf16* Bg0 = Bt + (size_t)(n0 + r0) * K + c0;
    const bf16* Bg1 = Bg0 + (size_t)64 * K;

    for (int k0 = 0; k0 < K; k0 += 32) {
        __syncthreads();
        load_lds16(Ag0 + k0, As + f);
        load_lds16(Ag1 + k0, As + f + 2048);
        load_lds16(Bg0 + k0, Bs + f);
        load_lds16(Bg1 + k0, Bs + f + 2048);
        __syncthreads();
        bf16x8 a[4], b[4];
        #pragma unroll
        for (int m = 0; m < 4; m++)
            a[m] = *(const bf16x8*)&As[(wr*64 + m*16 + l16) * 32 + lh*8];
        #pragma unroll
        for (int n = 0; n < 4; n++)
            b[n] = *(const bf16x8*)&Bs[(wc*64 + n*16 + l16) * 32 + lh*8];
        #pragma unroll
        for (int m = 0; m < 4; m++)
            #pragma unroll
            for (int n = 0; n < 4; n++)
                acc[m][n] = __builtin_amdgcn_mfma_f32_16x16x32_bf16(a[m], b[n], acc[m][n], 0, 0, 0);
    }

    #pragma unroll
    for (int m = 0; m < 4; m++) {
        const int grow_base = m0 + wr*64 + m*16 + lh*4;
        #pragma unroll
        for (int n = 0; n < 4; n++) {
            const int gcol = n0 + wc*64 + n*16 + l16;
            #pragma unroll
            for (int j = 0; j < 4; j++) {
                const int grow = grow_base + j;
                const size_t o = (size_t)grow * N + gcol;
                const float v = acc[m][n][j];
                if (epi == 0)      Cb[o] = f2b(v);
                else if (epi == 1) Cb[o] = f2b(v + bias[gcol]);
                else if (epi == 2) Cf[o] = v + resid[o];
                else if (epi == 3) Cf[o] += rowscale[(size_t)grow * rs_stride] * v;
                else if (epi == 5) Cf[o] = v + bias[gcol];
                else               Cf[o] = v;
            }
        }
    }
}

// ---------------------------------------------------------------------------
// RoPE in place on fp32 q,k, layout [B][S][NH][HD]. One thread per (t,h,d<64).
__global__ void rope_f32_k(float* __restrict__ q, float* __restrict__ k)
{
    const int idx = blockIdx.x * 256 + threadIdx.x;
    const int d  = idx & 63;
    const int hh = (idx >> 6) & 15;
    const size_t base = (size_t)(idx >> 10) * HIDDEN + hh * HD;
    const int s = (idx >> 10) & 1023;
    const float fr = (float)s * powf(1.0e6f, -(float)d * (1.0f / 64.0f));
    float c, sn;
    sincosf(fr, &sn, &c);
    float q0 = q[base + d], q1 = q[base + d + 64];
    q[base + d]      = q0 * c - q1 * sn;
    q[base + d + 64] = q1 * c + q0 * sn;
    float k0 = k[base + d], k1 = k[base + d + 64];
    k[base + d]      = k0 * c - k1 * sn;
    k[base + d + 64] = k1 * c + k0 * sn;
}

// ---------------------------------------------------------------------------
// V transpose + split: vf fp32 [B][S][NH][HD] -> vth, vtl [B][NH][HD][S] bf16
__global__ __launch_bounds__(256) void transpose_v3_k(
    const float* __restrict__ v, bf16* __restrict__ vth, bf16* __restrict__ vtl)
{
    __shared__ float t[32][33];
    const int s0 = blockIdx.x * 32, d0 = blockIdx.y * 32;
    const int bh = blockIdx.z, b = bh >> 4, h = bh & 15;
    const int tx = threadIdx.x & 31, ty = threadIdx.x >> 5;
    const float* vb = v + ((size_t)b * SEQ) * HIDDEN + h * HD;
    #pragma unroll
    for (int i = 0; i < 4; i++)
        t[ty + i*8][tx] = vb[(size_t)(s0 + ty + i*8) * HIDDEN + d0 + tx];
    __syncthreads();
    const size_t ob = ((size_t)bh * HD) * SEQ;
    #pragma unroll
    for (int i = 0; i < 4; i++) {
        float val = t[tx][ty + i*8];
        short hi, lo; split2(val, hi, lo);
        const size_t o = ob + (size_t)(d0 + ty + i*8) * SEQ + s0 + tx;
        vth[o] = __builtin_bit_cast(bf16, hi);
        vtl[o] = __builtin_bit_cast(bf16, lo);
    }
}

// ---------------------------------------------------------------------------
// Flash attention, causal, 2-limb precision (3-product MFMA for QK^T and PV).
// Block = 4 waves, 64 q rows. grid (S/64, B*NH).
__global__ __launch_bounds__(256) void attn3_k(
    const float* __restrict__ qf, const float* __restrict__ kf,
    const bf16* __restrict__ vth, const bf16* __restrict__ vtl,
    bf16* __restrict__ ctx2)
{
    __shared__ __align__(16) bf16 Ksh[32 * 128], Ksl[32 * 128];
    __shared__ __align__(16) bf16 Vth[128 * 32], Vtl[128 * 32];
    __shared__ __align__(16) bf16 Ph[4][16 * 32], Pl[4][16 * 32];
    const int tid = threadIdx.x, lane = tid & 63, wid = tid >> 6;
    const int l16 = lane & 15, lh = lane >> 4;
    const int bh = blockIdx.y, b = bh >> 4, h = bh & 15;
    const int qbase = blockIdx.x * 64;
    const int qw = qbase + wid * 16;
    const float* qp = qf + ((size_t)b * SEQ) * HIDDEN + h * HD;
    const float* kp = kf + ((size_t)b * SEQ) * HIDDEN + h * HD;
    const bf16* vph = vth + ((size_t)bh * HD) * SEQ;
    const bf16* vpl = vtl + ((size_t)bh * HD) * SEQ;

    // Q fragments, split in-register
    bf16x8 aqh[4], aql[4];
    #pragma unroll
    for (int c = 0; c < 4; c++) {
        const float* qrow = qp + (size_t)(qw + l16) * HIDDEN + c*32 + lh*8;
        #pragma unroll
        for (int u = 0; u < 8; u++) {
            short hi, lo; split2(qrow[u], hi, lo);
            aqh[c][u] = hi; aql[c][u] = lo;
        }
    }

    f32x4 o[8];
    #pragma unroll
    for (int n = 0; n < 8; n++) o[n] = (f32x4){0.f, 0.f, 0.f, 0.f};
    float mj[4], lj[4];
    #pragma unroll
    for (int j = 0; j < 4; j++) { mj[j] = -1e30f; lj[j] = 0.f; }

    const int f = tid * 8;
    const int kr = tid >> 3, kc = (tid & 7) * 16;   // K staging: row 0..31, col base
    const int kt_end = qbase / 32 + 2;
    for (int kt = 0; kt < kt_end; ++kt) {
        const int kv0 = kt * 32;
        __syncthreads();
        // K tile: fp32 load -> split -> LDS [32][128] hi/lo
        {
            const float* krow = kp + (size_t)(kv0 + kr) * HIDDEN + kc;
            #pragma unroll
            for (int u = 0; u < 4; u++) {
                float4 kv4 = *(const float4*)(krow + u*4);
                short h0, l0, h1, l1, h2s, l2s, h3, l3;
                split2(kv4.x, h0, l0); split2(kv4.y, h1, l1);
                split2(kv4.z, h2s, l2s); split2(kv4.w, h3, l3);
                bf16x4 h4, l4;
                h4[0] = h0; h4[1] = h1; h4[2] = h2s; h4[3] = h3;
                l4[0] = l0; l4[1] = l1; l4[2] = l2s; l4[3] = l3;
                *(bf16x4*)&Ksh[kr*128 + kc + u*4] = h4;
                *(bf16x4*)&Ksl[kr*128 + kc + u*4] = l4;
            }
        }
        // V tiles (pre-split) via global_load_lds: [128][32] hi/lo
        load_lds16(vph + (size_t)(f >> 5) * SEQ + kv0 + (f & 31), Vth + f);
        load_lds16(vph + (size_t)((f >> 5) + 64) * SEQ + kv0 + (f & 31), Vth + f + 2048);
        load_lds16(vpl + (size_t)(f >> 5) * SEQ + kv0 + (f & 31), Vtl + f);
        load_lds16(vpl + (size_t)((f >> 5) + 64) * SEQ + kv0 + (f & 31), Vtl + f + 2048);
        __syncthreads();

        f32x4 s0a = (f32x4){0.f,0.f,0.f,0.f}, s1a = (f32x4){0.f,0.f,0.f,0.f};
        #pragma unroll
        for (int c = 0; c < 4; c++) {
            bf16x8 bk0h = *(const bf16x8*)&Ksh[(l16) * 128 + c*32 + lh*8];
            bf16x8 bk0l = *(const bf16x8*)&Ksl[(l16) * 128 + c*32 + lh*8];
            bf16x8 bk1h = *(const bf16x8*)&Ksh[(l16 + 16) * 128 + c*32 + lh*8];
            bf16x8 bk1l = *(const bf16x8*)&Ksl[(l16 + 16) * 128 + c*32 + lh*8];
            s0a = __builtin_amdgcn_mfma_f32_16x16x32_bf16(aqh[c], bk0h, s0a, 0, 0, 0);
            s0a = __builtin_amdgcn_mfma_f32_16x16x32_bf16(aql[c], bk0h, s0a, 0, 0, 0);
            s0a = __builtin_amdgcn_mfma_f32_16x16x32_bf16(aqh[c], bk0l, s0a, 0, 0, 0);
            s1a = __builtin_amdgcn_mfma_f32_16x16x32_bf16(aqh[c], bk1h, s1a, 0, 0, 0);
            s1a = __builtin_amdgcn_mfma_f32_16x16x32_bf16(aql[c], bk1h, s1a, 0, 0, 0);
            s1a = __builtin_amdgcn_mfma_f32_16x16x32_bf16(aqh[c], bk1l, s1a, 0, 0, 0);
        }
        const float scale = 0.08838834764831845f;  // 1/sqrt(128)
        #pragma unroll
        for (int j = 0; j < 4; j++) {
            const int qrow = qw + lh*4 + j;
            float s0 = s0a[j] * scale, s1 = s1a[j] * scale;
            if (kv0 + l16 > qrow)      s0 = -1e30f;
            if (kv0 + l16 + 16 > qrow) s1 = -1e30f;
            float mx = fmaxf(s0, s1);
            #pragma unroll
            for (int off = 1; off < 16; off <<= 1) mx = fmaxf(mx, __shfl_xor(mx, off, 16));
            const float nm = fmaxf(mj[j], mx);
            const float al = __expf(mj[j] - nm);
            const float p0 = __expf(s0 - nm), p1 = __expf(s1 - nm);
            float rs = p0 + p1;
            #pragma unroll
            for (int off = 1; off < 16; off <<= 1) rs += __shfl_xor(rs, off, 16);
            lj[j] = lj[j] * al + rs;
            mj[j] = nm;
            #pragma unroll
            for (int n = 0; n < 8; n++) o[n][j] *= al;
            short h0, l0, h1, l1;
            split2(p0, h0, l0); split2(p1, h1, l1);
            Ph[wid][(lh*4 + j) * 32 + l16]      = __builtin_bit_cast(bf16, h0);
            Pl[wid][(lh*4 + j) * 32 + l16]      = __builtin_bit_cast(bf16, l0);
            Ph[wid][(lh*4 + j) * 32 + l16 + 16] = __builtin_bit_cast(bf16, h1);
            Pl[wid][(lh*4 + j) * 32 + l16 + 16] = __builtin_bit_cast(bf16, l1);
        }
        __syncthreads();
        const bf16x8 aph = *(const bf16x8*)&Ph[wid][l16 * 32 + lh*8];
        const bf16x8 apl = *(const bf16x8*)&Pl[wid][l16 * 32 + lh*8];
        #pragma unroll
        for (int n = 0; n < 8; n++) {
            bf16x8 bvh = *(const bf16x8*)&Vth[(n*16 + l16) * 32 + lh*8];
            bf16x8 bvl = *(const bf16x8*)&Vtl[(n*16 + l16) * 32 + lh*8];
            o[n] = __builtin_amdgcn_mfma_f32_16x16x32_bf16(aph, bvh, o[n], 0, 0, 0);
            o[n] = __builtin_amdgcn_mfma_f32_16x16x32_bf16(apl, bvh, o[n], 0, 0, 0);
            o[n] = __builtin_amdgcn_mfma_f32_16x16x32_bf16(aph, bvl, o[n], 0, 0, 0);
        }
    }

    float inv[4];
    #pragma unroll
    for (int j = 0; j < 4; j++) inv[j] = 1.0f / lj[j];
    #pragma unroll
    for (int n = 0; n < 8; n++)
        #pragma unroll
        for (int j = 0; j < 4; j++) {
            const float v = o[n][j] * inv[j];
            short hi, lo; split2(v, hi, lo);
            const size_t base = ((size_t)b * SEQ + (qw + lh*4 + j)) * K3 + h * HD + n*16 + l16;
            ctx2[base]          = __builtin_bit_cast(bf16, hi);
            ctx2[base + HIDDEN] = __builtin_bit_cast(bf16, lo);
            ctx2[base + 2*HIDDEN] = __builtin_bit_cast(bf16, hi);
        }
}

// ---------------------------------------------------------------------------
// Router in fp32 from the fp32 residual x1 (recomputes rmsnorm per token).
__global__ __launch_bounds__(256) void router_k(
    const float* __restrict__ x1, const float* __restrict__ wln,
    const float* __restrict__ wr, const float* __restrict__ weg,
    float* __restrict__ combine, float* __restrict__ sigeg)
{
    const int wid = threadIdx.x >> 6, lane = threadIdx.x & 63;
    const int t = blockIdx.x * 4 + wid;
    const float* xr = x1 + (size_t)t * HIDDEN;
    float ss = 0.f;
    for (int c = lane; c < HIDDEN; c += 64) { const float v = xr[c]; ss += v * v; }
    #pragma unroll
    for (int off = 1; off < 64; off <<= 1) ss += __shfl_xor(ss, off);
    const float r = rsqrtf(ss * (1.0f / HIDDEN) + 1e-6f);

    float acc[9];
    #pragma unroll
    for (int e = 0; e < 9; e++) acc[e] = 0.f;
    for (int c = lane; c < HIDDEN; c += 64) {
        const float hv = xr[c] * r * wln[c];
        const float* wrow = wr + (size_t)c * 8;
        #pragma unroll
        for (int e = 0; e < 8; e++) acc[e] += hv * wrow[e];
        acc[8] += hv * weg[c];
    }
    #pragma unroll
    for (int e = 0; e < 9; e++)
        #pragma unroll
        for (int off = 1; off < 64; off <<= 1) acc[e] += __shfl_xor(acc[e], off);
    float mx = acc[0];
    #pragma unroll
    for (int e = 1; e < 8; e++) mx = fmaxf(mx, acc[e]);
    float p[8], s = 0.f;
    #pragma unroll
    for (int e = 0; e < 8; e++) { p[e] = expf(acc[e] - mx); s += p[e]; }
    const float invs = 1.0f / s;
    #pragma unroll
    for (int e = 0; e < 8; e++) p[e] *= invs;
    int i1 = 0;
    #pragma unroll
    for (int e = 1; e < 8; e++) if (p[e] > p[i1]) i1 = e;
    int i2 = (i1 == 0) ? 1 : 0;
    #pragma unroll
    for (int e = 0; e < 8; e++) if (e != i1 && p[e] > p[i2]) i2 = e;
    if (lane < 8) combine[(size_t)t * 8 + lane] = (lane == i1 || lane == i2) ? p[lane] : 0.f;
    if (lane == 0) sigeg[t] = 1.0f / (1.0f + expf(-acc[8]));
}

// ---------------------------------------------------------------------------
__global__ void silu_mul_k(const bf16* __restrict__ g, const bf16* __restrict__ u,
                           bf16* __restrict__ a, int n)
{
    const int i = (blockIdx.x * 256 + threadIdx.x) * 4;
    if (i >= n) return;
    #pragma unroll
    for (int c = 0; c < 4; c++) {
        const float gv = b2f(g[i + c]), uv = b2f(u[i + c]);
        a[i + c] = f2b(gv / (1.0f + __expf(-gv)) * uv);
    }
}

__global__ void add2_k(const float* __restrict__ x1, const float* __restrict__ routed,
                       float* __restrict__ out)
{
    const int i = blockIdx.x * 256 + threadIdx.x;
    const float4 a = ((const float4*)x1)[i];
    const float4 b = ((const float4*)routed)[i];
    float4 r; r.x = a.x + b.x; r.y = a.y + b.y; r.z = a.z + b.z; r.w = a.w + b.w;
    ((float4*)out)[i] = r;
}

// ---------------------------------------------------------------------------
extern "C" void kernel_launch(void* const* d_in, const int* in_sizes, int n_in,
                              void* d_out, int out_size, void* d_ws, size_t ws_size,
                              hipStream_t stream)
{
    const float* x     = (const float*)d_in[0];
    const float* w_ln1 = (const float*)d_in[1];
    const float* wq    = (const float*)d_in[2];
    const float* bq    = (const float*)d_in[3];
    const float* wk    = (const float*)d_in[4];
    const float* bk    = (const float*)d_in[5];
    const float* wv    = (const float*)d_in[6];
    const float* bv    = (const float*)d_in[7];
    const float* wo    = (const float*)d_in[8];
    const float* w_ln2 = (const float*)d_in[9];
    const float* w_rt  = (const float*)d_in[10];
    const float* w_ge  = (const float*)d_in[11];
    const float* w_ue  = (const float*)d_in[12];
    const float* w_de  = (const float*)d_in[13];
    const float* w_sg  = (const float*)d_in[14];
    const float* w_su  = (const float*)d_in[15];
    const float* w_sd  = (const float*)d_in[16];
    const float* w_eg  = (const float*)d_in[17];
    float* out = (float*)d_out;
    (void)in_sizes; (void)n_in; (void)out_size; (void)ws_size;

    char* ws = (char*)d_ws;
    bf16*  hcat = (bf16*)(ws);
    bf16*  wt   = (bf16*)(ws + 25165824);
    float* qf   = (float*)(ws + 50331648);
    float* kf   = (float*)(ws + 67108864);
    float* vf   = (float*)(ws + 83886080);
    bf16*  vth  = (bf16*)(ws + 100663296);
    bf16*  vtl  = (bf16*)(ws + 109051904);
    bf16*  ctx2 = (bf16*)(ws + 117440512);
    float* x1   = (float*)(ws + 142606336);
    bf16*  h2   = (bf16*)(ws + 159383552);
    float* comb = (float*)(ws + 167772160);
    float* seg  = (float*)(ws + 167837696);
    bf16*  gb   = (bf16*)(ws);
    bf16*  ub   = (bf16*)(ws + 50331648);
    bf16*  ab   = (bf16*)(ws + 83886080);
    float* routed = (float*)(ws + 117440512);

    // 1) RMSNorm 1 -> split-cat h
    rmsnorm3_k<<<TOKENS, 256, 0, stream>>>(x, w_ln1, hcat);

    // 2) QKV projections at K3 precision -> fp32 q,k,v
    transpose_w3<<<dim3(64, 64), 256, 0, stream>>>(wq, wt, HIDDEN, HIDDEN);
    gemm_bt<<<dim3(16, 16), 256, 0, stream>>>(hcat, wt, qf, nullptr, bq, nullptr, nullptr, 0,
                                              TOKENS, HIDDEN, K3, 5);
    transpose_w3<<<dim3(64, 64), 256, 0, stream>>>(wk, wt, HIDDEN, HIDDEN);
    gemm_bt<<<dim3(16, 16), 256, 0, stream>>>(hcat, wt, kf, nullptr, bk, nullptr, nullptr, 0,
                                              TOKENS, HIDDEN, K3, 5);
    transpose_w3<<<dim3(64, 64), 256, 0, stream>>>(wv, wt, HIDDEN, HIDDEN);
    gemm_bt<<<dim3(16, 16), 256, 0, stream>>>(hcat, wt, vf, nullptr, bv, nullptr, nullptr, 0,
                                              TOKENS, HIDDEN, K3, 5);

    // 3) RoPE (fp32, in place) + V transpose/split + attention (2-limb)
    rope_f32_k<<<8192, 256, 0, stream>>>(qf, kf);
    transpose_v3_k<<<dim3(32, 4, 32), 256, 0, stream>>>(vf, vth, vtl);
    attn3_k<<<dim3(16, 32), 256, 0, stream>>>(qf, kf, vth, vtl, ctx2);

    // 4) Output projection (K3) + residual -> fp32 x1
    transpose_w3<<<dim3(64, 64), 256, 0, stream>>>(wo, wt, HIDDEN, HIDDEN);
    gemm_bt<<<dim3(16, 16), 256, 0, stream>>>(ctx2, wt, x1, nullptr, nullptr, x, nullptr, 0,
                                              TOKENS, HIDDEN, K3, 2);

    // 5) RMSNorm 2 (bf16 for MoE GEMMs) + fp32 router
    rmsnorm_k<<<TOKENS, 256, 0, stream>>>(x1, w_ln2, h2);
    router_k<<<TOKENS / 4, 256, 0, stream>>>(x1, w_ln2, w_rt, w_eg, comb, seg);

    // 6) MoE experts (dense bf16, weighted accumulate into routed)
    hipMemsetAsync(routed, 0, (size_t)TOKENS * HIDDEN * 4, stream);
    for (int e = 0; e < 8; e++) {
        const float* ge = w_ge + (size_t)e * HIDDEN * MOE_I;
        const float* ue = w_ue + (size_t)e * HIDDEN * MOE_I;
        const float* de = w_de + (size_t)e * MOE_I * HIDDEN;
        transpose_w<<<dim3(44, 64), 256, 0, stream>>>(ge, wt, HIDDEN, MOE_I);
        gemm_bt<<<dim3(16, 11), 256, 0, stream>>>(h2, wt, nullptr, gb, nullptr, nullptr, nullptr, 0,
                                                  TOKENS, MOE_I, HIDDEN, 0);
        transpose_w<<<dim3(44, 64), 256, 0, stream>>>(ue, wt, HIDDEN, MOE_I);
        gemm_bt<<<dim3(16, 11), 256, 0, stream>>>(h2, wt, nullptr, ub, nullptr, nullptr, nullptr, 0,
                                                  TOKENS, MOE_I, HIDDEN, 0);
        silu_mul_k<<<(TOKENS * MOE_I) / 1024, 256, 0, stream>>>(gb, ub, ab, TOKENS * MOE_I);
        transpose_w<<<dim3(64, 44), 256, 0, stream>>>(de, wt, MOE_I, HIDDEN);
        gemm_bt<<<dim3(16, 16), 256, 0, stream>>>(ab, wt, routed, nullptr, nullptr, nullptr,
                                                  comb + e, 8, TOKENS, HIDDEN, MOE_I, 3);
    }

    // 7) Shared expert (sigmoid-gated, accumulated into routed)
    transpose_w<<<dim3(176, 64), 256, 0, stream>>>(w_sg, wt, HIDDEN, SH_I);
    gemm_bt<<<dim3(16, 44), 256, 0, stream>>>(h2, wt, nullptr, gb, nullptr, nullptr, nullptr, 0,
                                              TOKENS, SH_I, HIDDEN, 0);
    transpose_w<<<dim3(176, 64), 256, 0, stream>>>(w_su, wt, HIDDEN, SH_I);
    gemm_bt<<<dim3(16, 44), 256, 0, stream>>>(h2, wt, nullptr, ub, nullptr, nullptr, nullptr, 0,
                                              TOKENS, SH_I, HIDDEN, 0);
    silu_mul_k<<<(TOKENS * SH_I) / 1024, 256, 0, stream>>>(gb, ub, ab, TOKENS * SH_I);
    transpose_w<<<dim3(64, 176), 256, 0, stream>>>(w_sd, wt, SH_I, HIDDEN);
    gemm_bt<<<dim3(16, 16), 256, 0, stream>>>(ab, wt, routed, nullptr, nullptr, nullptr,
                                              seg, 1, TOKENS, HIDDEN, SH_I, 3);

    // 8) Final: out = x1 + (routed + gated shared)
    add2_k<<<(TOKENS * HIDDEN) / 1024, 256, 0, stream>>>(x1, routed, out);
}

// Round 5
// 1348.063 us; speedup vs baseline: 1.9607x; 1.9607x over previous
//
#include <hip/hip_runtime.h>
#include <hip/hip_bf16.h>
#include <math.h>

#define TOKENS 2048
#define HIDDEN 2048
#define NH 16
#define HD 128
#define SEQ 1024
#define MOE_I 1408
#define SH_I 5632
#define K3 6144      // 3*HIDDEN cat-K for 2-limb split GEMMs
#define MAXROWS 5120 // max padded gathered rows (4096 entries + 8*127 pad, rounded)

typedef __hip_bfloat16 bf16;
typedef short bf16x8 __attribute__((ext_vector_type(8)));
typedef short bf16x4 __attribute__((ext_vector_type(4)));
typedef float f32x4 __attribute__((ext_vector_type(4)));

__device__ __forceinline__ float b2f(bf16 x) { return __bfloat162float(x); }
__device__ __forceinline__ bf16 f2b(float x) { return __float2bfloat16(x); }
__device__ __forceinline__ short bcast(bf16 x) { return __builtin_bit_cast(short, x); }
__device__ __forceinline__ void split2(float v, short& hi, short& lo) {
    bf16 h = f2b(v);
    bf16 l = f2b(v - b2f(h));
    hi = bcast(h); lo = bcast(l);
}

__device__ __forceinline__ void load_lds16(const void* g, void* l) {
    __builtin_amdgcn_global_load_lds(
        (const __attribute__((address_space(1))) unsigned int*)g,
        (__attribute__((address_space(3))) unsigned int*)l, 16, 0, 0);
}

// ---------------------------------------------------------------------------
__global__ __launch_bounds__(256) void rmsnorm_k(
    const float* __restrict__ x, const float* __restrict__ w, bf16* __restrict__ out)
{
    const int row = blockIdx.x, tid = threadIdx.x;
    const float4* xr = (const float4*)(x + (size_t)row * HIDDEN);
    float4 v1 = xr[tid], v2 = xr[tid + 256];
    float ss = v1.x*v1.x + v1.y*v1.y + v1.z*v1.z + v1.w*v1.w
             + v2.x*v2.x + v2.y*v2.y + v2.z*v2.z + v2.w*v2.w;
    #pragma unroll
    for (int off = 1; off < 64; off <<= 1) ss += __shfl_xor(ss, off);
    __shared__ float ps[4];
    if ((tid & 63) == 0) ps[tid >> 6] = ss;
    __syncthreads();
    float tot = ps[0] + ps[1] + ps[2] + ps[3];
    float r = rsqrtf(tot * (1.0f / HIDDEN) + 1e-6f);
    int i1 = tid * 4, i2 = 1024 + tid * 4;
    bf16* o = out + (size_t)row * HIDDEN;
    o[i1+0] = f2b(v1.x * r * w[i1+0]);
    o[i1+1] = f2b(v1.y * r * w[i1+1]);
    o[i1+2] = f2b(v1.z * r * w[i1+2]);
    o[i1+3] = f2b(v1.w * r * w[i1+3]);
    o[i2+0] = f2b(v2.x * r * w[i2+0]);
    o[i2+1] = f2b(v2.y * r * w[i2+1]);
    o[i2+2] = f2b(v2.z * r * w[i2+2]);
    o[i2+3] = f2b(v2.w * r * w[i2+3]);
}

// RMSNorm + 2-limb split, cat layout [row][K3]: [0..H)=hi, [H..2H)=lo, [2H..3H)=hi
__global__ __launch_bounds__(256) void rmsnorm3_k(
    const float* __restrict__ x, const float* __restrict__ w, bf16* __restrict__ out)
{
    const int row = blockIdx.x, tid = threadIdx.x;
    const float4* xr = (const float4*)(x + (size_t)row * HIDDEN);
    float4 v1 = xr[tid], v2 = xr[tid + 256];
    float ss = v1.x*v1.x + v1.y*v1.y + v1.z*v1.z + v1.w*v1.w
             + v2.x*v2.x + v2.y*v2.y + v2.z*v2.z + v2.w*v2.w;
    #pragma unroll
    for (int off = 1; off < 64; off <<= 1) ss += __shfl_xor(ss, off);
    __shared__ float ps[4];
    if ((tid & 63) == 0) ps[tid >> 6] = ss;
    __syncthreads();
    float tot = ps[0] + ps[1] + ps[2] + ps[3];
    float r = rsqrtf(tot * (1.0f / HIDDEN) + 1e-6f);
    bf16* o = out + (size_t)row * K3;
    float vv[8] = {v1.x, v1.y, v1.z, v1.w, v2.x, v2.y, v2.z, v2.w};
    int idx[8]  = {tid*4, tid*4+1, tid*4+2, tid*4+3,
                   1024+tid*4, 1024+tid*4+1, 1024+tid*4+2, 1024+tid*4+3};
    #pragma unroll
    for (int u = 0; u < 8; u++) {
        short hi, lo; split2(vv[u] * r * w[idx[u]], hi, lo);
        bf16 hb = __builtin_bit_cast(bf16, hi), lb = __builtin_bit_cast(bf16, lo);
        o[idx[u]] = hb; o[HIDDEN + idx[u]] = lb; o[2*HIDDEN + idx[u]] = hb;
    }
}

// ---------------------------------------------------------------------------
// Transpose+convert with z-batch: W[z] (K x N fp32) -> Wt[z] rows (nOff..nOff+N)
__global__ __launch_bounds__(256) void transpose_wz(
    const float* __restrict__ W, bf16* __restrict__ Wt, int K, int N,
    int nOff, long zsrc, long zdst)
{
    __shared__ float t[32][33];
    W  += (size_t)blockIdx.z * zsrc;
    Wt += (size_t)blockIdx.z * zdst;
    const int n0 = blockIdx.x * 32, k0 = blockIdx.y * 32;
    const int tx = threadIdx.x & 31, ty = threadIdx.x >> 5;
    #pragma unroll
    for (int i = 0; i < 4; i++)
        t[ty + i*8][tx] = W[(size_t)(k0 + ty + i*8) * N + n0 + tx];
    __syncthreads();
    #pragma unroll
    for (int i = 0; i < 4; i++)
        Wt[(size_t)(nOff + n0 + ty + i*8) * K + k0 + tx] = f2b(t[tx][ty + i*8]);
}

// Split transpose: W (K x N fp32) -> Wt2 (N x 3K bf16): [0..K)=hi, [K..2K)=hi, [2K..3K)=lo
__global__ __launch_bounds__(256) void transpose_w3(
    const float* __restrict__ W, bf16* __restrict__ Wt2, int K, int N)
{
    __shared__ float t[32][33];
    const int n0 = blockIdx.x * 32, k0 = blockIdx.y * 32;
    const int tx = threadIdx.x & 31, ty = threadIdx.x >> 5;
    #pragma unroll
    for (int i = 0; i < 4; i++)
        t[ty + i*8][tx] = W[(size_t)(k0 + ty + i*8) * N + n0 + tx];
    __syncthreads();
    #pragma unroll
    for (int i = 0; i < 4; i++) {
        float v = t[tx][ty + i*8];
        short hi, lo; split2(v, hi, lo);
        bf16 hb = __builtin_bit_cast(bf16, hi), lb = __builtin_bit_cast(bf16, lo);
        bf16* o = Wt2 + (size_t)(n0 + ty + i*8) * (3*K) + k0 + tx;
        o[0] = hb; o[K] = hb; o[2*K] = lb;
    }
}

// ---------------------------------------------------------------------------
// Dense GEMM: C[M,N] = A[M,ldA] @ Bt[N,ldB]^T over K cols starting at z*K.
// epi: 0=bf16 store, 2=f32 atomicAdd(v + z0?resid), 3=f32 atomicAdd(rowscale*v),
//      5=f32 atomicAdd(v + z0?bias)
__global__ __launch_bounds__(256) void gemm_bt(
    const bf16* __restrict__ A, const bf16* __restrict__ Bt,
    float* __restrict__ Cf, bf16* __restrict__ Cb,
    const float* __restrict__ bias, const float* __restrict__ resid,
    const float* __restrict__ rowscale, int rs_stride,
    int M, int N, int K, int ldA, int ldB, int epi)
{
    __shared__ __align__(16) bf16 As[128 * 32];
    __shared__ __align__(16) bf16 Bs[128 * 32];
    const int tid = threadIdx.x;
    const int lane = tid & 63, wid = tid >> 6;
    const int l16 = lane & 15, lh = lane >> 4;
    const int wr = wid >> 1, wc = wid & 1;
    const int m0 = blockIdx.x * 128, n0 = blockIdx.y * 128;
    const int f = tid * 8;
    const int r0 = f >> 5, c0 = f & 31;
    const size_t koff = (size_t)blockIdx.z * K;

    f32x4 acc[4][4];
    #pragma unroll
    for (int m = 0; m < 4; m++)
        #pragma unroll
        for (int n = 0; n < 4; n++) acc[m][n] = (f32x4){0.f, 0.f, 0.f, 0.f};

    const bf16* Ag0 = A + (size_t)(m0 + r0) * ldA + koff + c0;
    const bf16* Ag1 = Ag0 + (size_t)64 * ldA;
    const bf16* Bg0 = Bt + (size_t)(n0 + r0) * ldB + koff + c0;
    const bf16* Bg1 = Bg0 + (size_t)64 * ldB;

    for (int k0 = 0; k0 < K; k0 += 32) {
        __syncthreads();
        load_lds16(Ag0 + k0, As + f);
        load_lds16(Ag1 + k0, As + f + 2048);
        load_lds16(Bg0 + k0, Bs + f);
        load_lds16(Bg1 + k0, Bs + f + 2048);
        __syncthreads();
        bf16x8 a[4], b[4];
        #pragma unroll
        for (int m = 0; m < 4; m++)
            a[m] = *(const bf16x8*)&As[(wr*64 + m*16 + l16) * 32 + lh*8];
        #pragma unroll
        for (int n = 0; n < 4; n++)
            b[n] = *(const bf16x8*)&Bs[(wc*64 + n*16 + l16) * 32 + lh*8];
        #pragma unroll
        for (int m = 0; m < 4; m++)
            #pragma unroll
            for (int n = 0; n < 4; n++)
                acc[m][n] = __builtin_amdgcn_mfma_f32_16x16x32_bf16(a[m], b[n], acc[m][n], 0, 0, 0);
    }

    const bool z0 = (blockIdx.z == 0);
    #pragma unroll
    for (int m = 0; m < 4; m++) {
        const int grow_base = m0 + wr*64 + m*16 + lh*4;
        #pragma unroll
        for (int n = 0; n < 4; n++) {
            const int gcol = n0 + wc*64 + n*16 + l16;
            #pragma unroll
            for (int j = 0; j < 4; j++) {
                const int grow = grow_base + j;
                const size_t o = (size_t)grow * N + gcol;
                const float v = acc[m][n][j];
                if (epi == 0)      Cb[o] = f2b(v);
                else if (epi == 2) atomicAdd(&Cf[o], v + (z0 ? resid[o] : 0.f));
                else if (epi == 3) atomicAdd(&Cf[o], rowscale[(size_t)grow * rs_stride] * v);
                else if (epi == 5) atomicAdd(&Cf[o], v + (z0 ? bias[gcol] : 0.f));
            }
        }
    }
}

// ---------------------------------------------------------------------------
// Gathered MoE gate|up GEMM: rows = perm-gathered tokens of expert blockIdx.z.
// A = h2 [T][2048], Bt = wtgu[e] [2816][2048], C = gb [padrow][2816] bf16.
__global__ __launch_bounds__(256) void gemm_gu(
    const bf16* __restrict__ A, const bf16* __restrict__ BtAll,
    const int* __restrict__ offc, const int* __restrict__ perm,
    bf16* __restrict__ C)
{
    const int e = blockIdx.z;
    const int off = offc[8 + e];
    const int padCnt = offc[9 + e] - off;
    const int m0 = blockIdx.x * 128;
    if (m0 >= padCnt) return;
    __shared__ __align__(16) bf16 As[128 * 32];
    __shared__ __align__(16) bf16 Bs[128 * 32];
    const int tid = threadIdx.x;
    const int lane = tid & 63, wid = tid >> 6;
    const int l16 = lane & 15, lh = lane >> 4;
    const int wr = wid >> 1, wc = wid & 1;
    const int n0 = blockIdx.y * 128;
    const int f = tid * 8;
    const int r0 = f >> 5, c0 = f & 31;
    const bf16* Bt = BtAll + (size_t)e * 2816 * 2048;

    int t0 = perm[off + m0 + r0];      if (t0 < 0) t0 = 0;
    int t1 = perm[off + m0 + r0 + 64]; if (t1 < 0) t1 = 0;

    f32x4 acc[4][4];
    #pragma unroll
    for (int m = 0; m < 4; m++)
        #pragma unroll
        for (int n = 0; n < 4; n++) acc[m][n] = (f32x4){0.f, 0.f, 0.f, 0.f};

    const bf16* Ag0 = A + (size_t)t0 * 2048 + c0;
    const bf16* Ag1 = A + (size_t)t1 * 2048 + c0;
    const bf16* Bg0 = Bt + (size_t)(n0 + r0) * 2048 + c0;
    const bf16* Bg1 = Bg0 + (size_t)64 * 2048;

    for (int k0 = 0; k0 < 2048; k0 += 32) {
        __syncthreads();
        load_lds16(Ag0 + k0, As + f);
        load_lds16(Ag1 + k0, As + f + 2048);
        load_lds16(Bg0 + k0, Bs + f);
        load_lds16(Bg1 + k0, Bs + f + 2048);
        __syncthreads();
        bf16x8 a[4], b[4];
        #pragma unroll
        for (int m = 0; m < 4; m++)
            a[m] = *(const bf16x8*)&As[(wr*64 + m*16 + l16) * 32 + lh*8];
        #pragma unroll
        for (int n = 0; n < 4; n++)
            b[n] = *(const bf16x8*)&Bs[(wc*64 + n*16 + l16) * 32 + lh*8];
        #pragma unroll
        for (int m = 0; m < 4; m++)
            #pragma unroll
            for (int n = 0; n < 4; n++)
                acc[m][n] = __builtin_amdgcn_mfma_f32_16x16x32_bf16(a[m], b[n], acc[m][n], 0, 0, 0);
    }

    #pragma unroll
    for (int m = 0; m < 4; m++) {
        const int grow_base = m0 + wr*64 + m*16 + lh*4;
        #pragma unroll
        for (int n = 0; n < 4; n++) {
            const int gcol = n0 + wc*64 + n*16 + l16;
            #pragma unroll
            for (int j = 0; j < 4; j++)
                C[(size_t)(off + grow_base + j) * 2816 + gcol] = f2b(acc[m][n][j]);
        }
    }
}

// Gathered MoE down GEMM: A = ab [padrow][1408], Bt = wtd[e] [2048][1408];
// scatter: routed[tok] += comb[tok][e] * v  (atomic).
__global__ __launch_bounds__(256) void gemm_down(
    const bf16* __restrict__ A, const bf16* __restrict__ BtAll,
    const int* __restrict__ offc, const int* __restrict__ perm,
    const float* __restrict__ comb, float* __restrict__ routed)
{
    const int e = blockIdx.z;
    const int off = offc[8 + e];
    const int padCnt = offc[9 + e] - off;
    const int m0 = blockIdx.x * 128;
    if (m0 >= padCnt) return;
    __shared__ __align__(16) bf16 As[128 * 32];
    __shared__ __align__(16) bf16 Bs[128 * 32];
    const int tid = threadIdx.x;
    const int lane = tid & 63, wid = tid >> 6;
    const int l16 = lane & 15, lh = lane >> 4;
    const int wr = wid >> 1, wc = wid & 1;
    const int n0 = blockIdx.y * 128;
    const int f = tid * 8;
    const int r0 = f >> 5, c0 = f & 31;
    const bf16* Bt = BtAll + (size_t)e * 2048 * 1408;

    f32x4 acc[4][4];
    #pragma unroll
    for (int m = 0; m < 4; m++)
        #pragma unroll
        for (int n = 0; n < 4; n++) acc[m][n] = (f32x4){0.f, 0.f, 0.f, 0.f};

    const bf16* Ag0 = A + (size_t)(off + m0 + r0) * 1408 + c0;
    const bf16* Ag1 = Ag0 + (size_t)64 * 1408;
    const bf16* Bg0 = Bt + (size_t)(n0 + r0) * 1408 + c0;
    const bf16* Bg1 = Bg0 + (size_t)64 * 1408;

    for (int k0 = 0; k0 < 1408; k0 += 32) {
        __syncthreads();
        load_lds16(Ag0 + k0, As + f);
        load_lds16(Ag1 + k0, As + f + 2048);
        load_lds16(Bg0 + k0, Bs + f);
        load_lds16(Bg1 + k0, Bs + f + 2048);
        __syncthreads();
        bf16x8 a[4], b[4];
        #pragma unroll
        for (int m = 0; m < 4; m++)
            a[m] = *(const bf16x8*)&As[(wr*64 + m*16 + l16) * 32 + lh*8];
        #pragma unroll
        for (int n = 0; n < 4; n++)
            b[n] = *(const bf16x8*)&Bs[(wc*64 + n*16 + l16) * 32 + lh*8];
        #pragma unroll
        for (int m = 0; m < 4; m++)
            #pragma unroll
            for (int n = 0; n < 4; n++)
                acc[m][n] = __builtin_amdgcn_mfma_f32_16x16x32_bf16(a[m], b[n], acc[m][n], 0, 0, 0);
    }

    #pragma unroll
    for (int m = 0; m < 4; m++) {
        const int grow_base = m0 + wr*64 + m*16 + lh*4;
        #pragma unroll
        for (int n = 0; n < 4; n++) {
            const int gcol = n0 + wc*64 + n*16 + l16;
            #pragma unroll
            for (int j = 0; j < 4; j++) {
                const int tok = perm[off + grow_base + j];
                if (tok >= 0)
                    atomicAdd(&routed[(size_t)tok * HIDDEN + gcol],
                              comb[(size_t)tok * 8 + e] * acc[m][n][j]);
            }
        }
    }
}

// ---------------------------------------------------------------------------
__global__ void rope_f32_k(float* __restrict__ q, float* __restrict__ k)
{
    const int idx = blockIdx.x * 256 + threadIdx.x;
    const int d  = idx & 63;
    const int hh = (idx >> 6) & 15;
    const size_t base = (size_t)(idx >> 10) * HIDDEN + hh * HD;
    const int s = (idx >> 10) & 1023;
    const float fr = (float)s * powf(1.0e6f, -(float)d * (1.0f / 64.0f));
    float c, sn;
    sincosf(fr, &sn, &c);
    float q0 = q[base + d], q1 = q[base + d + 64];
    q[base + d]      = q0 * c - q1 * sn;
    q[base + d + 64] = q1 * c + q0 * sn;
    float k0 = k[base + d], k1 = k[base + d + 64];
    k[base + d]      = k0 * c - k1 * sn;
    k[base + d + 64] = k1 * c + k0 * sn;
}

// ---------------------------------------------------------------------------
__global__ __launch_bounds__(256) void transpose_v3_k(
    const float* __restrict__ v, bf16* __restrict__ vth, bf16* __restrict__ vtl)
{
    __shared__ float t[32][33];
    const int s0 = blockIdx.x * 32, d0 = blockIdx.y * 32;
    const int bh = blockIdx.z, b = bh >> 4, h = bh & 15;
    const int tx = threadIdx.x & 31, ty = threadIdx.x >> 5;
    const float* vb = v + ((size_t)b * SEQ) * HIDDEN + h * HD;
    #pragma unroll
    for (int i = 0; i < 4; i++)
        t[ty + i*8][tx] = vb[(size_t)(s0 + ty + i*8) * HIDDEN + d0 + tx];
    __syncthreads();
    const size_t ob = ((size_t)bh * HD) * SEQ;
    #pragma unroll
    for (int i = 0; i < 4; i++) {
        float val = t[tx][ty + i*8];
        short hi, lo; split2(val, hi, lo);
        const size_t o = ob + (size_t)(d0 + ty + i*8) * SEQ + s0 + tx;
        vth[o] = __builtin_bit_cast(bf16, hi);
        vtl[o] = __builtin_bit_cast(bf16, lo);
    }
}

// ---------------------------------------------------------------------------
// Flash attention, causal, 2-limb precision. Block = 4 waves, 64 q rows.
__global__ __launch_bounds__(256) void attn3_k(
    const float* __restrict__ qf, const float* __restrict__ kf,
    const bf16* __restrict__ vth, const bf16* __restrict__ vtl,
    bf16* __restrict__ ctx2)
{
    __shared__ __align__(16) bf16 Ksh[32 * 128], Ksl[32 * 128];
    __shared__ __align__(16) bf16 Vth[128 * 32], Vtl[128 * 32];
    __shared__ __align__(16) bf16 Ph[4][16 * 32], Pl[4][16 * 32];
    const int tid = threadIdx.x, lane = tid & 63, wid = tid >> 6;
    const int l16 = lane & 15, lh = lane >> 4;
    const int bh = blockIdx.y, b = bh >> 4, h = bh & 15;
    const int qbase = blockIdx.x * 64;
    const int qw = qbase + wid * 16;
    const float* qp = qf + ((size_t)b * SEQ) * HIDDEN + h * HD;
    const float* kp = kf + ((size_t)b * SEQ) * HIDDEN + h * HD;
    const bf16* vph = vth + ((size_t)bh * HD) * SEQ;
    const bf16* vpl = vtl + ((size_t)bh * HD) * SEQ;

    bf16x8 aqh[4], aql[4];
    #pragma unroll
    for (int c = 0; c < 4; c++) {
        const float* qrow = qp + (size_t)(qw + l16) * HIDDEN + c*32 + lh*8;
        #pragma unroll
        for (int u = 0; u < 8; u++) {
            short hi, lo; split2(qrow[u], hi, lo);
            aqh[c][u] = hi; aql[c][u] = lo;
        }
    }

    f32x4 o[8];
    #pragma unroll
    for (int n = 0; n < 8; n++) o[n] = (f32x4){0.f, 0.f, 0.f, 0.f};
    float mj[4], lj[4];
    #pragma unroll
    for (int j = 0; j < 4; j++) { mj[j] = -1e30f; lj[j] = 0.f; }

    const int f = tid * 8;
    const int kr = tid >> 3, kc = (tid & 7) * 16;
    const int kt_end = qbase / 32 + 2;
    for (int kt = 0; kt < kt_end; ++kt) {
        const int kv0 = kt * 32;
        __syncthreads();
        {
            const float* krow = kp + (size_t)(kv0 + kr) * HIDDEN + kc;
            #pragma unroll
            for (int u = 0; u < 4; u++) {
                float4 kv4 = *(const float4*)(krow + u*4);
                short h0, l0, h1, l1, h2s, l2s, h3, l3;
                split2(kv4.x, h0, l0); split2(kv4.y, h1, l1);
                split2(kv4.z, h2s, l2s); split2(kv4.w, h3, l3);
                bf16x4 h4, l4;
                h4[0] = h0; h4[1] = h1; h4[2] = h2s; h4[3] = h3;
                l4[0] = l0; l4[1] = l1; l4[2] = l2s; l4[3] = l3;
                *(bf16x4*)&Ksh[kr*128 + kc + u*4] = h4;
                *(bf16x4*)&Ksl[kr*128 + kc + u*4] = l4;
            }
        }
        load_lds16(vph + (size_t)(f >> 5) * SEQ + kv0 + (f & 31), Vth + f);
        load_lds16(vph + (size_t)((f >> 5) + 64) * SEQ + kv0 + (f & 31), Vth + f + 2048);
        load_lds16(vpl + (size_t)(f >> 5) * SEQ + kv0 + (f & 31), Vtl + f);
        load_lds16(vpl + (size_t)((f >> 5) + 64) * SEQ + kv0 + (f & 31), Vtl + f + 2048);
        __syncthreads();

        f32x4 s0a = (f32x4){0.f,0.f,0.f,0.f}, s1a = (f32x4){0.f,0.f,0.f,0.f};
        #pragma unroll
        for (int c = 0; c < 4; c++) {
            bf16x8 bk0h = *(const bf16x8*)&Ksh[(l16) * 128 + c*32 + lh*8];
            bf16x8 bk0l = *(const bf16x8*)&Ksl[(l16) * 128 + c*32 + lh*8];
            bf16x8 bk1h = *(const bf16x8*)&Ksh[(l16 + 16) * 128 + c*32 + lh*8];
            bf16x8 bk1l = *(const bf16x8*)&Ksl[(l16 + 16) * 128 + c*32 + lh*8];
            s0a = __builtin_amdgcn_mfma_f32_16x16x32_bf16(aqh[c], bk0h, s0a, 0, 0, 0);
            s0a = __builtin_amdgcn_mfma_f32_16x16x32_bf16(aql[c], bk0h, s0a, 0, 0, 0);
            s0a = __builtin_amdgcn_mfma_f32_16x16x32_bf16(aqh[c], bk0l, s0a, 0, 0, 0);
            s1a = __builtin_amdgcn_mfma_f32_16x16x32_bf16(aqh[c], bk1h, s1a, 0, 0, 0);
            s1a = __builtin_amdgcn_mfma_f32_16x16x32_bf16(aql[c], bk1h, s1a, 0, 0, 0);
            s1a = __builtin_amdgcn_mfma_f32_16x16x32_bf16(aqh[c], bk1l, s1a, 0, 0, 0);
        }
        const float scale = 0.08838834764831845f;
        #pragma unroll
        for (int j = 0; j < 4; j++) {
            const int qrow = qw + lh*4 + j;
            float s0 = s0a[j] * scale, s1 = s1a[j] * scale;
            if (kv0 + l16 > qrow)      s0 = -1e30f;
            if (kv0 + l16 + 16 > qrow) s1 = -1e30f;
            float mx = fmaxf(s0, s1);
            #pragma unroll
            for (int off = 1; off < 16; off <<= 1) mx = fmaxf(mx, __shfl_xor(mx, off, 16));
            const float nm = fmaxf(mj[j], mx);
            const float al = __expf(mj[j] - nm);
            const float p0 = __expf(s0 - nm), p1 = __expf(s1 - nm);
            float rs = p0 + p1;
            #pragma unroll
            for (int off = 1; off < 16; off <<= 1) rs += __shfl_xor(rs, off, 16);
            lj[j] = lj[j] * al + rs;
            mj[j] = nm;
            #pragma unroll
            for (int n = 0; n < 8; n++) o[n][j] *= al;
            short h0, l0, h1, l1;
            split2(p0, h0, l0); split2(p1, h1, l1);
            Ph[wid][(lh*4 + j) * 32 + l16]      = __builtin_bit_cast(bf16, h0);
            Pl[wid][(lh*4 + j) * 32 + l16]      = __builtin_bit_cast(bf16, l0);
            Ph[wid][(lh*4 + j) * 32 + l16 + 16] = __builtin_bit_cast(bf16, h1);
            Pl[wid][(lh*4 + j) * 32 + l16 + 16] = __builtin_bit_cast(bf16, l1);
        }
        __syncthreads();
        const bf16x8 aph = *(const bf16x8*)&Ph[wid][l16 * 32 + lh*8];
        const bf16x8 apl = *(const bf16x8*)&Pl[wid][l16 * 32 + lh*8];
        #pragma unroll
        for (int n = 0; n < 8; n++) {
            bf16x8 bvh = *(const bf16x8*)&Vth[(n*16 + l16) * 32 + lh*8];
            bf16x8 bvl = *(const bf16x8*)&Vtl[(n*16 + l16) * 32 + lh*8];
            o[n] = __builtin_amdgcn_mfma_f32_16x16x32_bf16(aph, bvh, o[n], 0, 0, 0);
            o[n] = __builtin_amdgcn_mfma_f32_16x16x32_bf16(apl, bvh, o[n], 0, 0, 0);
            o[n] = __builtin_amdgcn_mfma_f32_16x16x32_bf16(aph, bvl, o[n], 0, 0, 0);
        }
    }

    float inv[4];
    #pragma unroll
    for (int j = 0; j < 4; j++) inv[j] = 1.0f / lj[j];
    #pragma unroll
    for (int n = 0; n < 8; n++)
        #pragma unroll
        for (int j = 0; j < 4; j++) {
            const float v = o[n][j] * inv[j];
            short hi, lo; split2(v, hi, lo);
            const size_t base = ((size_t)b * SEQ + (qw + lh*4 + j)) * K3 + h * HD + n*16 + l16;
            ctx2[base]            = __builtin_bit_cast(bf16, hi);
            ctx2[base + HIDDEN]   = __builtin_bit_cast(bf16, lo);
            ctx2[base + 2*HIDDEN] = __builtin_bit_cast(bf16, hi);
        }
}

// ---------------------------------------------------------------------------
// Router in fp32 from the fp32 residual x1.
__global__ __launch_bounds__(256) void router_k(
    const float* __restrict__ x1, const float* __restrict__ wln,
    const float* __restrict__ wr, const float* __restrict__ weg,
    float* __restrict__ combine, float* __restrict__ sigeg)
{
    const int wid = threadIdx.x >> 6, lane = threadIdx.x & 63;
    const int t = blockIdx.x * 4 + wid;
    const float* xr = x1 + (size_t)t * HIDDEN;
    float ss = 0.f;
    for (int c = lane; c < HIDDEN; c += 64) { const float v = xr[c]; ss += v * v; }
    #pragma unroll
    for (int off = 1; off < 64; off <<= 1) ss += __shfl_xor(ss, off);
    const float r = rsqrtf(ss * (1.0f / HIDDEN) + 1e-6f);

    float acc[9];
    #pragma unroll
    for (int e = 0; e < 9; e++) acc[e] = 0.f;
    for (int c = lane; c < HIDDEN; c += 64) {
        const float hv = xr[c] * r * wln[c];
        const float* wrow = wr + (size_t)c * 8;
        #pragma unroll
        for (int e = 0; e < 8; e++) acc[e] += hv * wrow[e];
        acc[8] += hv * weg[c];
    }
    #pragma unroll
    for (int e = 0; e < 9; e++)
        #pragma unroll
        for (int off = 1; off < 64; off <<= 1) acc[e] += __shfl_xor(acc[e], off);
    float mx = acc[0];
    #pragma unroll
    for (int e = 1; e < 8; e++) mx = fmaxf(mx, acc[e]);
    float p[8], s = 0.f;
    #pragma unroll
    for (int e = 0; e < 8; e++) { p[e] = expf(acc[e] - mx); s += p[e]; }
    const float invs = 1.0f / s;
    #pragma unroll
    for (int e = 0; e < 8; e++) p[e] *= invs;
    int i1 = 0;
    #pragma unroll
    for (int e = 1; e < 8; e++) if (p[e] > p[i1]) i1 = e;
    int i2 = (i1 == 0) ? 1 : 0;
    #pragma unroll
    for (int e = 0; e < 8; e++) if (e != i1 && p[e] > p[i2]) i2 = e;
    if (lane < 8) combine[(size_t)t * 8 + lane] = (lane == i1 || lane == i2) ? p[lane] : 0.f;
    if (lane == 0) sigeg[t] = 1.0f / (1.0f + expf(-acc[8]));
}

// ---------------------------------------------------------------------------
// Build per-expert padded token lists from combine (>0 == selected). One block.
__global__ __launch_bounds__(256) void count_fill_k(
    const float* __restrict__ comb, int* __restrict__ offc, int* __restrict__ perm)
{
    __shared__ int cnt[8], off[9], fil[8];
    const int tid = threadIdx.x;
    if (tid < 8) { cnt[tid] = 0; fil[tid] = 0; }
    __syncthreads();
    for (int t = tid; t < TOKENS; t += 256)
        #pragma unroll
        for (int e = 0; e < 8; e++)
            if (comb[(size_t)t * 8 + e] > 0.f) atomicAdd(&cnt[e], 1);
    __syncthreads();
    if (tid == 0) {
        off[0] = 0;
        for (int e = 0; e < 8; e++) off[e+1] = off[e] + ((cnt[e] + 127) & ~127);
    }
    __syncthreads();
    for (int i = tid; i < MAXROWS; i += 256) perm[i] = -1;
    __syncthreads();
    for (int t = tid; t < TOKENS; t += 256)
        #pragma unroll
        for (int e = 0; e < 8; e++)
            if (comb[(size_t)t * 8 + e] > 0.f) {
                int s = atomicAdd(&fil[e], 1);
                perm[off[e] + s] = t;
            }
    __syncthreads();
    if (tid < 9) offc[8 + tid] = off[tid];
}

// ---------------------------------------------------------------------------
// silu(g)*u from fused [row][ldg] buffer (g cols 0..I, u cols I..2I) -> a [row][I]
__global__ void silu_k(const bf16* __restrict__ g, bf16* __restrict__ a,
                       int I, int ldg, int rowsConst, const int* __restrict__ rowsPtr)
{
    const int idx = (blockIdx.x * 256 + threadIdx.x) * 4;
    const int rows = rowsPtr ? *rowsPtr : rowsConst;
    const int row = idx / I;
    if (row >= rows) return;
    const int col = idx - row * I;
    const bf16* gr = g + (size_t)row * ldg + col;
    bf16* ar = a + (size_t)row * I + col;
    #pragma unroll
    for (int c = 0; c < 4; c++) {
        const float gv = b2f(gr[c]), uv = b2f(gr[I + c]);
        ar[c] = f2b(gv / (1.0f + __expf(-gv)) * uv);
    }
}

__global__ void add2_k(const float* __restrict__ x1, const float* __restrict__ routed,
                       float* __restrict__ out)
{
    const int i = blockIdx.x * 256 + threadIdx.x;
    const float4 a = ((const float4*)x1)[i];
    const float4 b = ((const float4*)routed)[i];
    float4 r; r.x = a.x + b.x; r.y = a.y + b.y; r.z = a.z + b.z; r.w = a.w + b.w;
    ((float4*)out)[i] = r;
}

// ---------------------------------------------------------------------------
extern "C" void kernel_launch(void* const* d_in, const int* in_sizes, int n_in,
                              void* d_out, int out_size, void* d_ws, size_t ws_size,
                              hipStream_t stream)
{
    const float* x     = (const float*)d_in[0];
    const float* w_ln1 = (const float*)d_in[1];
    const float* wq    = (const float*)d_in[2];
    const float* bq    = (const float*)d_in[3];
    const float* wk    = (const float*)d_in[4];
    const float* bk    = (const float*)d_in[5];
    const float* wv    = (const float*)d_in[6];
    const float* bv    = (const float*)d_in[7];
    const float* wo    = (const float*)d_in[8];
    const float* w_ln2 = (const float*)d_in[9];
    const float* w_rt  = (const float*)d_in[10];
    const float* w_ge  = (const float*)d_in[11];
    const float* w_ue  = (const float*)d_in[12];
    const float* w_de  = (const float*)d_in[13];
    const float* w_sg  = (const float*)d_in[14];
    const float* w_su  = (const float*)d_in[15];
    const float* w_sd  = (const float*)d_in[16];
    const float* w_eg  = (const float*)d_in[17];
    float* out = (float*)d_out;
    (void)in_sizes; (void)n_in; (void)out_size; (void)ws_size;

    char* ws = (char*)d_ws;
    // persistent rails
    float* x1     = (float*)(ws + 0);            // 16.8M
    bf16*  h2     = (bf16*)(ws + 16777216);      // 8.4M
    float* comb   = (float*)(ws + 25165824);     // 64K
    float* seg    = (float*)(ws + 25231360);     // 8K
    int*   offc   = (int*)(ws + 25239552);       // 1K
    int*   perm   = (int*)(ws + 25240576);       // 20K
    float* routed = (float*)(ws + 25261056);     // 16.8M -> ends 42038272
    const size_t S = 42038272;
    // phase A (attention)
    bf16*  hcat = (bf16*)(ws + S);               // 25.2M
    bf16*  wt3  = (bf16*)(ws + S + 25165824);    // 25.2M
    float* qf   = (float*)(ws + S + 50331648);   // 16.8M
    float* kf   = (float*)(ws + S + 67108864);   // 16.8M
    float* vf   = (float*)(ws + S + 83886080);   // 16.8M (dead after transpose_v3)
    bf16*  vth  = (bf16*)(ws + S);               // 8.4M (over hcat, after QKV gemms)
    bf16*  vtl  = (bf16*)(ws + S + 8388608);     // 8.4M
    bf16*  ctx2 = (bf16*)(ws + S + 83886080);    // 25.2M (over vf)
    // phase B (MoE)
    bf16*  wtgu = (bf16*)(ws + S);               // 92.3M
    bf16*  gb   = (bf16*)(ws + S + 92274688);    // 28.8M -> ends S+121.1M (163.1M total)
    bf16*  ab   = (bf16*)(ws + S);               // 14.4M (over wtgu)
    bf16*  wtd  = (bf16*)(ws + S + 14417920);    // 46.1M
    // phase C (shared expert)
    bf16*  wtshgu = (bf16*)(ws + S);             // 46.1M
    bf16*  gsh    = (bf16*)(ws + S + 46137344);  // 46.1M
    bf16*  ash    = (bf16*)(ws + S + 92274688);  // 23.1M
    bf16*  wtshd  = (bf16*)(ws + S + 46137344);  // 23.1M (over gsh after silu)

    // 1) RMSNorm 1 -> split-cat h
    rmsnorm3_k<<<TOKENS, 256, 0, stream>>>(x, w_ln1, hcat);
    (void)hipMemsetAsync(qf, 0, (size_t)3 * TOKENS * HIDDEN * 4, stream);  // qf,kf,vf

    // 2) QKV projections at K3 precision, split-K z=2 -> fp32 q,k,v
    transpose_w3<<<dim3(64, 64), 256, 0, stream>>>(wq, wt3, HIDDEN, HIDDEN);
    gemm_bt<<<dim3(16, 16, 2), 256, 0, stream>>>(hcat, wt3, qf, nullptr, bq, nullptr, nullptr, 0,
                                                 TOKENS, HIDDEN, K3/2, K3, K3, 5);
    transpose_w3<<<dim3(64, 64), 256, 0, stream>>>(wk, wt3, HIDDEN, HIDDEN);
    gemm_bt<<<dim3(16, 16, 2), 256, 0, stream>>>(hcat, wt3, kf, nullptr, bk, nullptr, nullptr, 0,
                                                 TOKENS, HIDDEN, K3/2, K3, K3, 5);
    transpose_w3<<<dim3(64, 64), 256, 0, stream>>>(wv, wt3, HIDDEN, HIDDEN);
    gemm_bt<<<dim3(16, 16, 2), 256, 0, stream>>>(hcat, wt3, vf, nullptr, bv, nullptr, nullptr, 0,
                                                 TOKENS, HIDDEN, K3/2, K3, K3, 5);

    // 3) RoPE + V transpose/split + attention
    rope_f32_k<<<8192, 256, 0, stream>>>(qf, kf);
    transpose_v3_k<<<dim3(32, 4, 32), 256, 0, stream>>>(vf, vth, vtl);
    attn3_k<<<dim3(16, 32), 256, 0, stream>>>(qf, kf, vth, vtl, ctx2);

    // 4) Output projection (K3, split-K) + residual -> fp32 x1
    transpose_w3<<<dim3(64, 64), 256, 0, stream>>>(wo, wt3, HIDDEN, HIDDEN);
    (void)hipMemsetAsync(x1, 0, (size_t)TOKENS * HIDDEN * 4, stream);
    gemm_bt<<<dim3(16, 16, 2), 256, 0, stream>>>(ctx2, wt3, x1, nullptr, nullptr, x, nullptr, 0,
                                                 TOKENS, HIDDEN, K3/2, K3, K3, 2);

    // 5) RMSNorm 2 + fp32 router + expert token lists
    rmsnorm_k<<<TOKENS, 256, 0, stream>>>(x1, w_ln2, h2);
    router_k<<<TOKENS / 4, 256, 0, stream>>>(x1, w_ln2, w_rt, w_eg, comb, seg);
    count_fill_k<<<1, 256, 0, stream>>>(comb, offc, perm);
    (void)hipMemsetAsync(routed, 0, (size_t)TOKENS * HIDDEN * 4, stream);

    // 6) Sparse MoE: fused gate|up grouped GEMM -> silu -> down (atomic scatter)
    transpose_wz<<<dim3(44, 64, 8), 256, 0, stream>>>(w_ge, wtgu, HIDDEN, MOE_I, 0,
                                                      (long)HIDDEN*MOE_I, (long)2816*HIDDEN);
    transpose_wz<<<dim3(44, 64, 8), 256, 0, stream>>>(w_ue, wtgu, HIDDEN, MOE_I, MOE_I,
                                                      (long)HIDDEN*MOE_I, (long)2816*HIDDEN);
    gemm_gu<<<dim3(MAXROWS/128, 22, 8), 256, 0, stream>>>(h2, wtgu, offc, perm, gb);
    silu_k<<<(MAXROWS * MOE_I) / 1024, 256, 0, stream>>>(gb, ab, MOE_I, 2816, 0, offc + 16);
    transpose_wz<<<dim3(64, 44, 8), 256, 0, stream>>>(w_de, wtd, MOE_I, HIDDEN, 0,
                                                      (long)MOE_I*HIDDEN, (long)HIDDEN*MOE_I);
    gemm_down<<<dim3(MAXROWS/128, 16, 8), 256, 0, stream>>>(ab, wtd, offc, perm, comb, routed);

    // 7) Shared expert: fused gate|up (N=11264) -> silu -> down (split-K, gated)
    transpose_wz<<<dim3(176, 64, 1), 256, 0, stream>>>(w_sg, wtshgu, HIDDEN, SH_I, 0, 0, 0);
    transpose_wz<<<dim3(176, 64, 1), 256, 0, stream>>>(w_su, wtshgu, HIDDEN, SH_I, SH_I, 0, 0);
    gemm_bt<<<dim3(16, 88, 1), 256, 0, stream>>>(h2, wtshgu, nullptr, gsh, nullptr, nullptr,
                                                 nullptr, 0, TOKENS, 2*SH_I, HIDDEN, HIDDEN, HIDDEN, 0);
    silu_k<<<(TOKENS * SH_I) / 1024, 256, 0, stream>>>(gsh, ash, SH_I, 2*SH_I, TOKENS, nullptr);
    transpose_wz<<<dim3(64, 176, 1), 256, 0, stream>>>(w_sd, wtshd, SH_I, HIDDEN, 0, 0, 0);
    gemm_bt<<<dim3(16, 16, 2), 256, 0, stream>>>(ash, wtshd, routed, nullptr, nullptr, nullptr,
                                                 seg, 1, TOKENS, HIDDEN, SH_I/2, SH_I, SH_I, 3);

    // 8) Final: out = x1 + routed(+shared)
    add2_k<<<(TOKENS * HIDDEN) / 1024, 256, 0, stream>>>(x1, routed, out);
}

// Round 6
// 1167.251 us; speedup vs baseline: 2.2644x; 1.1549x over previous
//
#include <hip/hip_runtime.h>
#include <hip/hip_bf16.h>
#include <math.h>

#define TOKENS 2048
#define HIDDEN 2048
#define NH 16
#define HD 128
#define SEQ 1024
#define MOE_I 1408
#define SH_I 5632
#define K3 6144       // logical cat-K (hi.hi + lo.hi + hi.lo)
#define MAXROWS 5120

typedef __hip_bfloat16 bf16;
typedef short bf16x8 __attribute__((ext_vector_type(8)));
typedef short bf16x4 __attribute__((ext_vector_type(4)));
typedef float f32x4 __attribute__((ext_vector_type(4)));

__device__ __forceinline__ float b2f(bf16 x) { return __bfloat162float(x); }
__device__ __forceinline__ bf16 f2b(float x) { return __float2bfloat16(x); }
__device__ __forceinline__ void split2(float v, short& hi, short& lo) {
    bf16 h = f2b(v);
    bf16 l = f2b(v - b2f(h));
    hi = __builtin_bit_cast(short, h); lo = __builtin_bit_cast(short, l);
}

__device__ __forceinline__ void load_lds16(const void* g, void* l) {
    __builtin_amdgcn_global_load_lds(
        (const __attribute__((address_space(1))) unsigned int*)g,
        (__attribute__((address_space(3))) unsigned int*)l, 16, 0, 0);
}

// ---------------------------------------------------------------------------
__global__ __launch_bounds__(256) void rmsnorm3_k(
    const float* __restrict__ x, const float* __restrict__ w, bf16* __restrict__ out)
{
    const int row = blockIdx.x, tid = threadIdx.x;
    const float4* xr = (const float4*)(x + (size_t)row * HIDDEN);
    float4 v1 = xr[tid], v2 = xr[tid + 256];
    float ss = v1.x*v1.x + v1.y*v1.y + v1.z*v1.z + v1.w*v1.w
             + v2.x*v2.x + v2.y*v2.y + v2.z*v2.z + v2.w*v2.w;
    #pragma unroll
    for (int off = 1; off < 64; off <<= 1) ss += __shfl_xor(ss, off);
    __shared__ float ps[4];
    if ((tid & 63) == 0) ps[tid >> 6] = ss;
    __syncthreads();
    float tot = ps[0] + ps[1] + ps[2] + ps[3];
    float r = rsqrtf(tot * (1.0f / HIDDEN) + 1e-6f);
    bf16* o = out + (size_t)row * 4096;
    float vv[8] = {v1.x, v1.y, v1.z, v1.w, v2.x, v2.y, v2.z, v2.w};
    int idx[8]  = {tid*4, tid*4+1, tid*4+2, tid*4+3,
                   1024+tid*4, 1024+tid*4+1, 1024+tid*4+2, 1024+tid*4+3};
    #pragma unroll
    for (int u = 0; u < 8; u++) {
        short hi, lo; split2(vv[u] * r * w[idx[u]], hi, lo);
        o[idx[u]]        = __builtin_bit_cast(bf16, hi);
        o[2048 + idx[u]] = __builtin_bit_cast(bf16, lo);
    }
}

// ---------------------------------------------------------------------------
__global__ __launch_bounds__(256) void transpose_wz(
    const float* __restrict__ W, bf16* __restrict__ Wt, int K, int N,
    int nOff, long zsrc, long zdst)
{
    __shared__ float t[32][33];
    W  += (size_t)blockIdx.z * zsrc;
    Wt += (size_t)blockIdx.z * zdst;
    const int n0 = blockIdx.x * 32, k0 = blockIdx.y * 32;
    const int tx = threadIdx.x & 31, ty = threadIdx.x >> 5;
    #pragma unroll
    for (int i = 0; i < 4; i++)
        t[ty + i*8][tx] = W[(size_t)(k0 + ty + i*8) * N + n0 + tx];
    __syncthreads();
    #pragma unroll
    for (int i = 0; i < 4; i++)
        Wt[(size_t)(nOff + n0 + ty + i*8) * K + k0 + tx] = f2b(t[tx][ty + i*8]);
}

__global__ __launch_bounds__(256) void transpose_w3(
    const float* __restrict__ W, bf16* __restrict__ Wt2, int K, int N, int nOff)
{
    __shared__ float t[32][33];
    const int n0 = blockIdx.x * 32, k0 = blockIdx.y * 32;
    const int tx = threadIdx.x & 31, ty = threadIdx.x >> 5;
    #pragma unroll
    for (int i = 0; i < 4; i++)
        t[ty + i*8][tx] = W[(size_t)(k0 + ty + i*8) * N + n0 + tx];
    __syncthreads();
    #pragma unroll
    for (int i = 0; i < 4; i++) {
        float v = t[tx][ty + i*8];
        short hi, lo; split2(v, hi, lo);
        bf16* o = Wt2 + (size_t)(nOff + n0 + ty + i*8) * (2*K) + k0 + tx;
        o[0] = __builtin_bit_cast(bf16, hi);
        o[K] = __builtin_bit_cast(bf16, lo);
    }
}

// ---------------------------------------------------------------------------
// GEMM: C[M,N] = A @ Bt^T, 128x128x32 tile. koff = z*K (logical).
// limb3: A/B phys [hi|lo] (4096 wide), logical kcat in [0,6144) remapped.
// epi: 0 = bf16 store; 4 = f32 store at Cf + z*zCstride; 5 = f32 + bias store.
__global__ __launch_bounds__(256) void gemm_bt(
    const bf16* __restrict__ A, const bf16* __restrict__ Bt,
    float* __restrict__ Cf, bf16* __restrict__ Cb, const float* __restrict__ bias,
    int M, int N, int K, int ldA, int ldB, int ldC, long zCstride, int limb3, int epi)
{
    __shared__ __align__(16) bf16 As[128 * 32];
    __shared__ __align__(16) bf16 Bs[128 * 32];
    const int tid = threadIdx.x;
    const int lane = tid & 63, wid = tid >> 6;
    const int l16 = lane & 15, lh = lane >> 4;
    const int wr = wid >> 1, wc = wid & 1;
    const int m0 = blockIdx.x * 128, n0 = blockIdx.y * 128;
    const int f = tid * 8;
    const int r0 = f >> 5, c0 = f & 31;
    const int koff = blockIdx.z * K;

    f32x4 acc[4][4];
    #pragma unroll
    for (int m = 0; m < 4; m++)
        #pragma unroll
        for (int n = 0; n < 4; n++) acc[m][n] = (f32x4){0.f, 0.f, 0.f, 0.f};

    const bf16* Ag0 = A + (size_t)(m0 + r0) * ldA + c0;
    const bf16* Ag1 = Ag0 + (size_t)64 * ldA;
    const bf16* Bg0 = Bt + (size_t)(n0 + r0) * ldB + c0;
    const bf16* Bg1 = Bg0 + (size_t)64 * ldB;

    for (int k0 = 0; k0 < K; k0 += 32) {
        const int kcat = koff + k0;
        int ka = kcat, kb = kcat;
        if (limb3) {
            ka = (kcat >= 4096) ? kcat - 4096 : kcat;
            kb = (kcat >= 2048) ? kcat - 2048 : kcat;
        }
        __syncthreads();
        load_lds16(Ag0 + ka, As + f);
        load_lds16(Ag1 + ka, As + f + 2048);
        load_lds16(Bg0 + kb, Bs + f);
        load_lds16(Bg1 + kb, Bs + f + 2048);
        __syncthreads();
        bf16x8 a[4], b[4];
        #pragma unroll
        for (int m = 0; m < 4; m++)
            a[m] = *(const bf16x8*)&As[(wr*64 + m*16 + l16) * 32 + lh*8];
        #pragma unroll
        for (int n = 0; n < 4; n++)
            b[n] = *(const bf16x8*)&Bs[(wc*64 + n*16 + l16) * 32 + lh*8];
        #pragma unroll
        for (int m = 0; m < 4; m++)
            #pragma unroll
            for (int n = 0; n < 4; n++)
                acc[m][n] = __builtin_amdgcn_mfma_f32_16x16x32_bf16(a[m], b[n], acc[m][n], 0, 0, 0);
    }

    float* Cz = Cf + (size_t)blockIdx.z * zCstride;
    #pragma unroll
    for (int m = 0; m < 4; m++) {
        const int grow_base = m0 + wr*64 + m*16 + lh*4;
        #pragma unroll
        for (int n = 0; n < 4; n++) {
            const int gcol = n0 + wc*64 + n*16 + l16;
            #pragma unroll
            for (int j = 0; j < 4; j++) {
                const size_t o = (size_t)(grow_base + j) * ldC + gcol;
                const float v = acc[m][n][j];
                if (epi == 0)      Cb[o] = f2b(v);
                else if (epi == 4) Cz[o] = v;
                else               Cf[o] = v + bias[gcol];
            }
        }
    }
}

// ---------------------------------------------------------------------------
__global__ __launch_bounds__(256) void gemm_gu(
    const bf16* __restrict__ A, const bf16* __restrict__ BtAll,
    const int* __restrict__ offc, const int* __restrict__ perm,
    bf16* __restrict__ C)
{
    const int e = blockIdx.z;
    const int off = offc[8 + e];
    const int padCnt = offc[9 + e] - off;
    const int m0 = blockIdx.x * 128;
    if (m0 >= padCnt) return;
    __shared__ __align__(16) bf16 As[128 * 32];
    __shared__ __align__(16) bf16 Bs[128 * 32];
    const int tid = threadIdx.x;
    const int lane = tid & 63, wid = tid >> 6;
    const int l16 = lane & 15, lh = lane >> 4;
    const int wr = wid >> 1, wc = wid & 1;
    const int n0 = blockIdx.y * 128;
    const int f = tid * 8;
    const int r0 = f >> 5, c0 = f & 31;
    const bf16* Bt = BtAll + (size_t)e * 2816 * 2048;

    int t0 = perm[off + m0 + r0];      if (t0 < 0) t0 = 0;
    int t1 = perm[off + m0 + r0 + 64]; if (t1 < 0) t1 = 0;

    f32x4 acc[4][4];
    #pragma unroll
    for (int m = 0; m < 4; m++)
        #pragma unroll
        for (int n = 0; n < 4; n++) acc[m][n] = (f32x4){0.f, 0.f, 0.f, 0.f};

    const bf16* Ag0 = A + (size_t)t0 * 2048 + c0;
    const bf16* Ag1 = A + (size_t)t1 * 2048 + c0;
    const bf16* Bg0 = Bt + (size_t)(n0 + r0) * 2048 + c0;
    const bf16* Bg1 = Bg0 + (size_t)64 * 2048;

    for (int k0 = 0; k0 < 2048; k0 += 32) {
        __syncthreads();
        load_lds16(Ag0 + k0, As + f);
        load_lds16(Ag1 + k0, As + f + 2048);
        load_lds16(Bg0 + k0, Bs + f);
        load_lds16(Bg1 + k0, Bs + f + 2048);
        __syncthreads();
        bf16x8 a[4], b[4];
        #pragma unroll
        for (int m = 0; m < 4; m++)
            a[m] = *(const bf16x8*)&As[(wr*64 + m*16 + l16) * 32 + lh*8];
        #pragma unroll
        for (int n = 0; n < 4; n++)
            b[n] = *(const bf16x8*)&Bs[(wc*64 + n*16 + l16) * 32 + lh*8];
        #pragma unroll
        for (int m = 0; m < 4; m++)
            #pragma unroll
            for (int n = 0; n < 4; n++)
                acc[m][n] = __builtin_amdgcn_mfma_f32_16x16x32_bf16(a[m], b[n], acc[m][n], 0, 0, 0);
    }

    #pragma unroll
    for (int m = 0; m < 4; m++) {
        const int grow_base = m0 + wr*64 + m*16 + lh*4;
        #pragma unroll
        for (int n = 0; n < 4; n++) {
            const int gcol = n0 + wc*64 + n*16 + l16;
            #pragma unroll
            for (int j = 0; j < 4; j++)
                C[(size_t)(off + grow_base + j) * 2816 + gcol] = f2b(acc[m][n][j]);
        }
    }
}

__global__ __launch_bounds__(256) void gemm_down(
    const bf16* __restrict__ A, const bf16* __restrict__ BtAll,
    const int* __restrict__ offc, bf16* __restrict__ Y)
{
    const int e = blockIdx.z;
    const int off = offc[8 + e];
    const int padCnt = offc[9 + e] - off;
    const int m0 = blockIdx.x * 128;
    if (m0 >= padCnt) return;
    __shared__ __align__(16) bf16 As[128 * 32];
    __shared__ __align__(16) bf16 Bs[128 * 32];
    const int tid = threadIdx.x;
    const int lane = tid & 63, wid = tid >> 6;
    const int l16 = lane & 15, lh = lane >> 4;
    const int wr = wid >> 1, wc = wid & 1;
    const int n0 = blockIdx.y * 128;
    const int f = tid * 8;
    const int r0 = f >> 5, c0 = f & 31;
    const bf16* Bt = BtAll + (size_t)e * 2048 * 1408;

    f32x4 acc[4][4];
    #pragma unroll
    for (int m = 0; m < 4; m++)
        #pragma unroll
        for (int n = 0; n < 4; n++) acc[m][n] = (f32x4){0.f, 0.f, 0.f, 0.f};

    const bf16* Ag0 = A + (size_t)(off + m0 + r0) * 1408 + c0;
    const bf16* Ag1 = Ag0 + (size_t)64 * 1408;
    const bf16* Bg0 = Bt + (size_t)(n0 + r0) * 1408 + c0;
    const bf16* Bg1 = Bg0 + (size_t)64 * 1408;

    for (int k0 = 0; k0 < 1408; k0 += 32) {
        __syncthreads();
        load_lds16(Ag0 + k0, As + f);
        load_lds16(Ag1 + k0, As + f + 2048);
        load_lds16(Bg0 + k0, Bs + f);
        load_lds16(Bg1 + k0, Bs + f + 2048);
        __syncthreads();
        bf16x8 a[4], b[4];
        #pragma unroll
        for (int m = 0; m < 4; m++)
            a[m] = *(const bf16x8*)&As[(wr*64 + m*16 + l16) * 32 + lh*8];
        #pragma unroll
        for (int n = 0; n < 4; n++)
            b[n] = *(const bf16x8*)&Bs[(wc*64 + n*16 + l16) * 32 + lh*8];
        #pragma unroll
        for (int m = 0; m < 4; m++)
            #pragma unroll
            for (int n = 0; n < 4; n++)
                acc[m][n] = __builtin_amdgcn_mfma_f32_16x16x32_bf16(a[m], b[n], acc[m][n], 0, 0, 0);
    }

    #pragma unroll
    for (int m = 0; m < 4; m++) {
        const int grow_base = m0 + wr*64 + m*16 + lh*4;
        #pragma unroll
        for (int n = 0; n < 4; n++) {
            const int gcol = n0 + wc*64 + n*16 + l16;
            #pragma unroll
            for (int j = 0; j < 4; j++)
                Y[(size_t)(off + grow_base + j) * 2048 + gcol] = f2b(acc[m][n][j]);
        }
    }
}

// ---------------------------------------------------------------------------
__global__ void rope_f32_k(float* __restrict__ qkv)
{
    const int idx = blockIdx.x * 256 + threadIdx.x;
    const int d  = idx & 63;
    const int hh = (idx >> 6) & 15;
    const size_t base = (size_t)(idx >> 10) * 6144 + hh * HD;
    const int s = (idx >> 10) & 1023;
    const float fr = (float)s * powf(1.0e6f, -(float)d * (1.0f / 64.0f));
    float c, sn;
    sincosf(fr, &sn, &c);
    float q0 = qkv[base + d], q1 = qkv[base + d + 64];
    qkv[base + d]      = q0 * c - q1 * sn;
    qkv[base + d + 64] = q1 * c + q0 * sn;
    float k0 = qkv[base + 2048 + d], k1 = qkv[base + 2048 + d + 64];
    qkv[base + 2048 + d]      = k0 * c - k1 * sn;
    qkv[base + 2048 + d + 64] = k1 * c + k0 * sn;
}

// ---------------------------------------------------------------------------
__global__ __launch_bounds__(256) void transpose_v3_k(
    const float* __restrict__ qkv, bf16* __restrict__ vth, bf16* __restrict__ vtl)
{
    __shared__ float t[32][33];
    const int s0 = blockIdx.x * 32, d0 = blockIdx.y * 32;
    const int bh = blockIdx.z, b = bh >> 4, h = bh & 15;
    const int tx = threadIdx.x & 31, ty = threadIdx.x >> 5;
    const float* vb = qkv + ((size_t)b * SEQ) * 6144 + 4096 + h * HD;
    #pragma unroll
    for (int i = 0; i < 4; i++)
        t[ty + i*8][tx] = vb[(size_t)(s0 + ty + i*8) * 6144 + d0 + tx];
    __syncthreads();
    const size_t ob = ((size_t)bh * HD) * SEQ;
    #pragma unroll
    for (int i = 0; i < 4; i++) {
        float val = t[tx][ty + i*8];
        short hi, lo; split2(val, hi, lo);
        const size_t o = ob + (size_t)(d0 + ty + i*8) * SEQ + s0 + tx;
        vth[o] = __builtin_bit_cast(bf16, hi);
        vtl[o] = __builtin_bit_cast(bf16, lo);
    }
}

// ---------------------------------------------------------------------------
__global__ __launch_bounds__(256) void attn3_k(
    const float* __restrict__ qkv,
    const bf16* __restrict__ vth, const bf16* __restrict__ vtl,
    bf16* __restrict__ ctx2)
{
    __shared__ __align__(16) bf16 Ksh[32 * 128], Ksl[32 * 128];
    __shared__ __align__(16) bf16 Vth[128 * 32], Vtl[128 * 32];
    __shared__ __align__(16) bf16 Ph[4][16 * 32], Pl[4][16 * 32];
    const int tid = threadIdx.x, lane = tid & 63, wid = tid >> 6;
    const int l16 = lane & 15, lh = lane >> 4;
    const int bh = blockIdx.y, b = bh >> 4, h = bh & 15;
    const int qbase = blockIdx.x * 64;
    const int qw = qbase + wid * 16;
    const float* qp = qkv + ((size_t)b * SEQ) * 6144 + h * HD;
    const float* kp = qkv + ((size_t)b * SEQ) * 6144 + 2048 + h * HD;
    const bf16* vph = vth + ((size_t)bh * HD) * SEQ;
    const bf16* vpl = vtl + ((size_t)bh * HD) * SEQ;

    bf16x8 aqh[4], aql[4];
    #pragma unroll
    for (int c = 0; c < 4; c++) {
        const float* qrow = qp + (size_t)(qw + l16) * 6144 + c*32 + lh*8;
        #pragma unroll
        for (int u = 0; u < 8; u++) {
            short hi, lo; split2(qrow[u], hi, lo);
            aqh[c][u] = hi; aql[c][u] = lo;
        }
    }

    f32x4 o[8];
    #pragma unroll
    for (int n = 0; n < 8; n++) o[n] = (f32x4){0.f, 0.f, 0.f, 0.f};
    float mj[4], lj[4];
    #pragma unroll
    for (int j = 0; j < 4; j++) { mj[j] = -1e30f; lj[j] = 0.f; }

    const int f = tid * 8;
    const int kr = tid >> 3, kc = (tid & 7) * 16;
    const int kt_end = qbase / 32 + 2;
    for (int kt = 0; kt < kt_end; ++kt) {
        const int kv0 = kt * 32;
        __syncthreads();
        {
            const float* krow = kp + (size_t)(kv0 + kr) * 6144 + kc;
            #pragma unroll
            for (int u = 0; u < 4; u++) {
                float4 kv4 = *(const float4*)(krow + u*4);
                short h0, l0, h1, l1, h2s, l2s, h3, l3;
                split2(kv4.x, h0, l0); split2(kv4.y, h1, l1);
                split2(kv4.z, h2s, l2s); split2(kv4.w, h3, l3);
                bf16x4 h4, l4;
                h4[0] = h0; h4[1] = h1; h4[2] = h2s; h4[3] = h3;
                l4[0] = l0; l4[1] = l1; l4[2] = l2s; l4[3] = l3;
                *(bf16x4*)&Ksh[kr*128 + kc + u*4] = h4;
                *(bf16x4*)&Ksl[kr*128 + kc + u*4] = l4;
            }
        }
        load_lds16(vph + (size_t)(f >> 5) * SEQ + kv0 + (f & 31), Vth + f);
        load_lds16(vph + (size_t)((f >> 5) + 64) * SEQ + kv0 + (f & 31), Vth + f + 2048);
        load_lds16(vpl + (size_t)(f >> 5) * SEQ + kv0 + (f & 31), Vtl + f);
        load_lds16(vpl + (size_t)((f >> 5) + 64) * SEQ + kv0 + (f & 31), Vtl + f + 2048);
        __syncthreads();

        f32x4 s0a = (f32x4){0.f,0.f,0.f,0.f}, s1a = (f32x4){0.f,0.f,0.f,0.f};
        #pragma unroll
        for (int c = 0; c < 4; c++) {
            bf16x8 bk0h = *(const bf16x8*)&Ksh[(l16) * 128 + c*32 + lh*8];
            bf16x8 bk0l = *(const bf16x8*)&Ksl[(l16) * 128 + c*32 + lh*8];
            bf16x8 bk1h = *(const bf16x8*)&Ksh[(l16 + 16) * 128 + c*32 + lh*8];
            bf16x8 bk1l = *(const bf16x8*)&Ksl[(l16 + 16) * 128 + c*32 + lh*8];
            s0a = __builtin_amdgcn_mfma_f32_16x16x32_bf16(aqh[c], bk0h, s0a, 0, 0, 0);
            s0a = __builtin_amdgcn_mfma_f32_16x16x32_bf16(aql[c], bk0h, s0a, 0, 0, 0);
            s0a = __builtin_amdgcn_mfma_f32_16x16x32_bf16(aqh[c], bk0l, s0a, 0, 0, 0);
            s1a = __builtin_amdgcn_mfma_f32_16x16x32_bf16(aqh[c], bk1h, s1a, 0, 0, 0);
            s1a = __builtin_amdgcn_mfma_f32_16x16x32_bf16(aql[c], bk1h, s1a, 0, 0, 0);
            s1a = __builtin_amdgcn_mfma_f32_16x16x32_bf16(aqh[c], bk1l, s1a, 0, 0, 0);
        }
        const float scale = 0.08838834764831845f;
        #pragma unroll
        for (int j = 0; j < 4; j++) {
            const int qrow = qw + lh*4 + j;
            float s0 = s0a[j] * scale, s1 = s1a[j] * scale;
            if (kv0 + l16 > qrow)      s0 = -1e30f;
            if (kv0 + l16 + 16 > qrow) s1 = -1e30f;
            float mx = fmaxf(s0, s1);
            #pragma unroll
            for (int off = 1; off < 16; off <<= 1) mx = fmaxf(mx, __shfl_xor(mx, off, 16));
            const float nm = fmaxf(mj[j], mx);
            const float al = __expf(mj[j] - nm);
            const float p0 = __expf(s0 - nm), p1 = __expf(s1 - nm);
            float rs = p0 + p1;
            #pragma unroll
            for (int off = 1; off < 16; off <<= 1) rs += __shfl_xor(rs, off, 16);
            lj[j] = lj[j] * al + rs;
            mj[j] = nm;
            #pragma unroll
            for (int n = 0; n < 8; n++) o[n][j] *= al;
            short h0, l0, h1, l1;
            split2(p0, h0, l0); split2(p1, h1, l1);
            Ph[wid][(lh*4 + j) * 32 + l16]      = __builtin_bit_cast(bf16, h0);
            Pl[wid][(lh*4 + j) * 32 + l16]      = __builtin_bit_cast(bf16, l0);
            Ph[wid][(lh*4 + j) * 32 + l16 + 16] = __builtin_bit_cast(bf16, h1);
            Pl[wid][(lh*4 + j) * 32 + l16 + 16] = __builtin_bit_cast(bf16, l1);
        }
        __syncthreads();
        const bf16x8 aph = *(const bf16x8*)&Ph[wid][l16 * 32 + lh*8];
        const bf16x8 apl = *(const bf16x8*)&Pl[wid][l16 * 32 + lh*8];
        #pragma unroll
        for (int n = 0; n < 8; n++) {
            bf16x8 bvh = *(const bf16x8*)&Vth[(n*16 + l16) * 32 + lh*8];
            bf16x8 bvl = *(const bf16x8*)&Vtl[(n*16 + l16) * 32 + lh*8];
            o[n] = __builtin_amdgcn_mfma_f32_16x16x32_bf16(aph, bvh, o[n], 0, 0, 0);
            o[n] = __builtin_amdgcn_mfma_f32_16x16x32_bf16(apl, bvh, o[n], 0, 0, 0);
            o[n] = __builtin_amdgcn_mfma_f32_16x16x32_bf16(aph, bvl, o[n], 0, 0, 0);
        }
    }

    float inv[4];
    #pragma unroll
    for (int j = 0; j < 4; j++) inv[j] = 1.0f / lj[j];
    #pragma unroll
    for (int n = 0; n < 8; n++)
        #pragma unroll
        for (int j = 0; j < 4; j++) {
            const float v = o[n][j] * inv[j];
            short hi, lo; split2(v, hi, lo);
            const size_t base = ((size_t)b * SEQ + (qw + lh*4 + j)) * 4096 + h * HD + n*16 + l16;
            ctx2[base]        = __builtin_bit_cast(bf16, hi);
            ctx2[base + 2048] = __builtin_bit_cast(bf16, lo);
        }
}

// ---------------------------------------------------------------------------
__global__ __launch_bounds__(256) void combine_rms_k(
    const float* __restrict__ x, const float* __restrict__ xp,
    const float* __restrict__ w, float* __restrict__ x1, bf16* __restrict__ h2)
{
    const int row = blockIdx.x, tid = threadIdx.x;
    const size_t rb = (size_t)row * HIDDEN;
    const long zs = (long)TOKENS * HIDDEN;
    float4 v[2];
    #pragma unroll
    for (int u = 0; u < 2; u++) {
        const int i = tid + u * 256;
        float4 a  = ((const float4*)(x + rb))[i];
        float4 p0 = ((const float4*)(xp + rb))[i];
        float4 p1 = ((const float4*)(xp + zs + rb))[i];
        float4 p2 = ((const float4*)(xp + 2*zs + rb))[i];
        v[u].x = a.x + p0.x + p1.x + p2.x;
        v[u].y = a.y + p0.y + p1.y + p2.y;
        v[u].z = a.z + p0.z + p1.z + p2.z;
        v[u].w = a.w + p0.w + p1.w + p2.w;
        ((float4*)(x1 + rb))[i] = v[u];
    }
    float ss = v[0].x*v[0].x + v[0].y*v[0].y + v[0].z*v[0].z + v[0].w*v[0].w
             + v[1].x*v[1].x + v[1].y*v[1].y + v[1].z*v[1].z + v[1].w*v[1].w;
    #pragma unroll
    for (int off = 1; off < 64; off <<= 1) ss += __shfl_xor(ss, off);
    __shared__ float ps[4];
    if ((tid & 63) == 0) ps[tid >> 6] = ss;
    __syncthreads();
    float tot = ps[0] + ps[1] + ps[2] + ps[3];
    float r = rsqrtf(tot * (1.0f / HIDDEN) + 1e-6f);
    #pragma unroll
    for (int u = 0; u < 2; u++) {
        const int i = (tid + u * 256) * 4;
        h2[rb + i]     = f2b(v[u].x * r * w[i]);
        h2[rb + i + 1] = f2b(v[u].y * r * w[i+1]);
        h2[rb + i + 2] = f2b(v[u].z * r * w[i+2]);
        h2[rb + i + 3] = f2b(v[u].w * r * w[i+3]);
    }
}

// ---------------------------------------------------------------------------
__global__ __launch_bounds__(256) void router_k(
    const float* __restrict__ x1, const float* __restrict__ wln,
    const float* __restrict__ wr, const float* __restrict__ weg,
    float* __restrict__ combine, float* __restrict__ sigeg)
{
    const int wid = threadIdx.x >> 6, lane = threadIdx.x & 63;
    const int t = blockIdx.x * 4 + wid;
    const float* xr = x1 + (size_t)t * HIDDEN;
    float ss = 0.f;
    for (int c = lane; c < HIDDEN; c += 64) { const float v = xr[c]; ss += v * v; }
    #pragma unroll
    for (int off = 1; off < 64; off <<= 1) ss += __shfl_xor(ss, off);
    const float r = rsqrtf(ss * (1.0f / HIDDEN) + 1e-6f);

    float acc[9];
    #pragma unroll
    for (int e = 0; e < 9; e++) acc[e] = 0.f;
    for (int c = lane; c < HIDDEN; c += 64) {
        const float hv = xr[c] * r * wln[c];
        const float* wrow = wr + (size_t)c * 8;
        #pragma unroll
        for (int e = 0; e < 8; e++) acc[e] += hv * wrow[e];
        acc[8] += hv * weg[c];
    }
    #pragma unroll
    for (int e = 0; e < 9; e++)
        #pragma unroll
        for (int off = 1; off < 64; off <<= 1) acc[e] += __shfl_xor(acc[e], off);
    float mx = acc[0];
    #pragma unroll
    for (int e = 1; e < 8; e++) mx = fmaxf(mx, acc[e]);
    float p[8], s = 0.f;
    #pragma unroll
    for (int e = 0; e < 8; e++) { p[e] = expf(acc[e] - mx); s += p[e]; }
    const float invs = 1.0f / s;
    #pragma unroll
    for (int e = 0; e < 8; e++) p[e] *= invs;
    int i1 = 0;
    #pragma unroll
    for (int e = 1; e < 8; e++) if (p[e] > p[i1]) i1 = e;
    int i2 = (i1 == 0) ? 1 : 0;
    #pragma unroll
    for (int e = 0; e < 8; e++) if (e != i1 && p[e] > p[i2]) i2 = e;
    if (lane < 8) combine[(size_t)t * 8 + lane] = (lane == i1 || lane == i2) ? p[lane] : 0.f;
    if (lane == 0) sigeg[t] = 1.0f / (1.0f + expf(-acc[8]));
}

// ---------------------------------------------------------------------------
__global__ __launch_bounds__(256) void count_fill_k(
    const float* __restrict__ comb, int* __restrict__ offc, int* __restrict__ perm,
    float* __restrict__ scale, int* __restrict__ inv)
{
    __shared__ int cnt[8], off[9], fil[8];
    const int tid = threadIdx.x;
    if (tid < 8) { cnt[tid] = 0; fil[tid] = 0; }
    __syncthreads();
    for (int t = tid; t < TOKENS; t += 256)
        #pragma unroll
        for (int e = 0; e < 8; e++)
            if (comb[(size_t)t * 8 + e] > 0.f) atomicAdd(&cnt[e], 1);
    __syncthreads();
    if (tid == 0) {
        off[0] = 0;
        for (int e = 0; e < 8; e++) off[e+1] = off[e] + ((cnt[e] + 127) & ~127);
    }
    __syncthreads();
    for (int i = tid; i < MAXROWS; i += 256) { perm[i] = -1; scale[i] = 0.f; }
    __syncthreads();
    for (int t = tid; t < TOKENS; t += 256) {
        int j = 0;
        #pragma unroll
        for (int e = 0; e < 8; e++) {
            const float c = comb[(size_t)t * 8 + e];
            if (c > 0.f) {
                int s = atomicAdd(&fil[e], 1);
                int slot = off[e] + s;
                perm[slot] = t;
                scale[slot] = c;
                inv[t * 2 + j] = slot;
                j++;
            }
        }
    }
    __syncthreads();
    if (tid < 9) offc[8 + tid] = off[tid];
}

// ---------------------------------------------------------------------------
__global__ void silu_k(const bf16* __restrict__ g, bf16* __restrict__ a,
                       const float* __restrict__ rowScale,
                       int I, int ldg, int rowsConst, const int* __restrict__ rowsPtr)
{
    const int idx = (blockIdx.x * 256 + threadIdx.x) * 4;
    const int rows = rowsPtr ? *rowsPtr : rowsConst;
    const int row = idx / I;
    if (row >= rows) return;
    const int col = idx - row * I;
    const float s = rowScale[row];
    const bf16* gr = g + (size_t)row * ldg + col;
    bf16* ar = a + (size_t)row * I + col;
    #pragma unroll
    for (int c = 0; c < 4; c++) {
        const float gv = b2f(gr[c]), uv = b2f(gr[I + c]);
        ar[c] = f2b(s * gv / (1.0f + __expf(-gv)) * uv);
    }
}

// ---------------------------------------------------------------------------
__global__ void final_k(const float* __restrict__ x1, const bf16* __restrict__ y,
                        const int* __restrict__ inv, const float* __restrict__ ysh,
                        float* __restrict__ out)
{
    const int i = blockIdx.x * 256 + threadIdx.x;   // float4 index
    const int t = i >> 9;
    const int col = (i & 511) * 4;
    const int s0 = inv[t*2], s1 = inv[t*2 + 1];
    const long zs = (long)TOKENS * HIDDEN;
    float4 a  = ((const float4*)x1)[i];
    float4 h0 = ((const float4*)ysh)[i];
    float4 h1 = ((const float4*)(ysh + zs))[i];
    const bf16* y0 = y + (size_t)s0 * 2048 + col;
    const bf16* y1 = y + (size_t)s1 * 2048 + col;
    float4 r;
    r.x = a.x + h0.x + h1.x + b2f(y0[0]) + b2f(y1[0]);
    r.y = a.y + h0.y + h1.y + b2f(y0[1]) + b2f(y1[1]);
    r.z = a.z + h0.z + h1.z + b2f(y0[2]) + b2f(y1[2]);
    r.w = a.w + h0.w + h1.w + b2f(y0[3]) + b2f(y1[3]);
    ((float4*)out)[i] = r;
}

// ---------------------------------------------------------------------------
extern "C" void kernel_launch(void* const* d_in, const int* in_sizes, int n_in,
                              void* d_out, int out_size, void* d_ws, size_t ws_size,
                              hipStream_t stream)
{
    const float* x     = (const float*)d_in[0];
    const float* w_ln1 = (const float*)d_in[1];
    const float* wq    = (const float*)d_in[2];
    const float* bq    = (const float*)d_in[3];
    const float* wk    = (const float*)d_in[4];
    const float* bk    = (const float*)d_in[5];
    const float* wv    = (const float*)d_in[6];
    const float* bv    = (const float*)d_in[7];
    const float* wo    = (const float*)d_in[8];
    const float* w_ln2 = (const float*)d_in[9];
    const float* w_rt  = (const float*)d_in[10];
    const float* w_ge  = (const float*)d_in[11];
    const float* w_ue  = (const float*)d_in[12];
    const float* w_de  = (const float*)d_in[13];
    const float* w_sg  = (const float*)d_in[14];
    const float* w_su  = (const float*)d_in[15];
    const float* w_sd  = (const float*)d_in[16];
    const float* w_eg  = (const float*)d_in[17];
    float* out = (float*)d_out;
    (void)in_sizes; (void)n_in; (void)out_size; (void)ws_size;

    char* ws = (char*)d_ws;
    // persistent
    float* x1    = (float*)(ws + 0);
    bf16*  h2    = (bf16*)(ws + 16777216);
    float* comb  = (float*)(ws + 25165824);
    float* seg   = (float*)(ws + 25231360);
    int*   offc  = (int*)(ws + 25239552);
    float* scale = (float*)(ws + 25243648);
    int*   perm  = (int*)(ws + 25276416);
    int*   inv   = (int*)(ws + 25297920);
    float* bqkv  = (float*)(ws + 25314304);
    const size_t S = 25341952;
    // phase A
    bf16*  hcat  = (bf16*)(ws + S);
    bf16*  wtqkv = (bf16*)(ws + S + 16777216);
    float* qkvf  = (float*)(ws + S + 67108864);           // ends S+117440512 (~142.8M)
    bf16*  vth   = (bf16*)(ws + S);
    bf16*  vtl   = (bf16*)(ws + S + 8388608);
    bf16*  ctx2  = (bf16*)(ws + S + 16777216);
    bf16*  wt3o  = (bf16*)(ws + S + 33554432);
    float* xp    = (float*)(ws + S + 50331648);           // 3x16.78M, ends S+100663296
    // phase B
    bf16*  wtgu  = (bf16*)(ws + S);                       // 92.27M
    bf16*  gb    = (bf16*)(ws + S + 92274688);            // 28.84M, ends S+121110528 (~146.5M)
    bf16*  ab    = (bf16*)(ws + S);                       // 14.42M
    bf16*  wtd   = (bf16*)(ws + S + 14417920);            // 46.14M, ends S+60555264
    bf16*  ymoe  = (bf16*)(ws + S + 60555264);            // 20.97M, ends S+81526784
    // phase C
    bf16*  wtshgu = (bf16*)(ws + S);                      // 46.14M
    bf16*  gsh    = (bf16*)(ws + S + 81526784);           // 46.14M, ends S+127664128 (~153M)
    bf16*  ash    = (bf16*)(ws + S);                      // 23.07M
    bf16*  wtshd  = (bf16*)(ws + S + 23068672);           // 23.07M, ends S+46137344
    float* ysh    = (float*)(ws + S + 81526784);          // 2x16.78M over gsh

    // 1) RMSNorm1 -> hcat [T][4096]; QKV bias concat
    rmsnorm3_k<<<TOKENS, 256, 0, stream>>>(x, w_ln1, hcat);
    (void)hipMemcpyAsync(bqkv,        bq, 8192, hipMemcpyDeviceToDevice, stream);
    (void)hipMemcpyAsync(bqkv + 2048, bk, 8192, hipMemcpyDeviceToDevice, stream);
    (void)hipMemcpyAsync(bqkv + 4096, bv, 8192, hipMemcpyDeviceToDevice, stream);

    // 2) Fused QKV (limb3, N=6144, 768 blocks, plain stores)
    transpose_w3<<<dim3(64, 64), 256, 0, stream>>>(wq, wtqkv, HIDDEN, HIDDEN, 0);
    transpose_w3<<<dim3(64, 64), 256, 0, stream>>>(wk, wtqkv, HIDDEN, HIDDEN, 2048);
    transpose_w3<<<dim3(64, 64), 256, 0, stream>>>(wv, wtqkv, HIDDEN, HIDDEN, 4096);
    gemm_bt<<<dim3(16, 48, 1), 256, 0, stream>>>(hcat, wtqkv, qkvf, nullptr, bqkv,
                                                 TOKENS, 6144, K3, 4096, 4096, 6144, 0, 1, 5);

    // 3) RoPE + V transpose/split + attention
    rope_f32_k<<<8192, 256, 0, stream>>>(qkvf);
    transpose_v3_k<<<dim3(32, 4, 32), 256, 0, stream>>>(qkvf, vth, vtl);
    attn3_k<<<dim3(16, 32), 256, 0, stream>>>(qkvf, vth, vtl, ctx2);

    // 4) O-proj (limb3, split-K z=3, plain stores) + fused combine/rms
    transpose_w3<<<dim3(64, 64), 256, 0, stream>>>(wo, wt3o, HIDDEN, HIDDEN, 0);
    gemm_bt<<<dim3(16, 16, 3), 256, 0, stream>>>(ctx2, wt3o, xp, nullptr, nullptr,
                                                 TOKENS, HIDDEN, 2048, 4096, 4096, 2048,
                                                 (long)TOKENS * HIDDEN, 1, 4);
    combine_rms_k<<<TOKENS, 256, 0, stream>>>(x, xp, w_ln2, x1, h2);

    // 5) Router + expert lists
    router_k<<<TOKENS / 4, 256, 0, stream>>>(x1, w_ln2, w_rt, w_eg, comb, seg);
    count_fill_k<<<1, 256, 0, stream>>>(comb, offc, perm, scale, inv);

    // 6) Sparse MoE (combine folded into silu; plain-store down GEMM)
    transpose_wz<<<dim3(44, 64, 8), 256, 0, stream>>>(w_ge, wtgu, HIDDEN, MOE_I, 0,
                                                      (long)HIDDEN*MOE_I, (long)2816*HIDDEN);
    transpose_wz<<<dim3(44, 64, 8), 256, 0, stream>>>(w_ue, wtgu, HIDDEN, MOE_I, MOE_I,
                                                      (long)HIDDEN*MOE_I, (long)2816*HIDDEN);
    gemm_gu<<<dim3(MAXROWS/128, 22, 8), 256, 0, stream>>>(h2, wtgu, offc, perm, gb);
    silu_k<<<(MAXROWS * MOE_I) / 1024, 256, 0, stream>>>(gb, ab, scale, MOE_I, 2816, 0, offc + 16);
    transpose_wz<<<dim3(64, 44, 8), 256, 0, stream>>>(w_de, wtd, MOE_I, HIDDEN, 0,
                                                      (long)MOE_I*HIDDEN, (long)HIDDEN*MOE_I);
    gemm_down<<<dim3(MAXROWS/128, 16, 8), 256, 0, stream>>>(ab, wtd, offc, ymoe);

    // 7) Shared expert (seg folded into silu; split-K z=2 plain stores)
    transpose_wz<<<dim3(176, 64, 1), 256, 0, stream>>>(w_sg, wtshgu, HIDDEN, SH_I, 0, 0, 0);
    transpose_wz<<<dim3(176, 64, 1), 256, 0, stream>>>(w_su, wtshgu, HIDDEN, SH_I, SH_I, 0, 0);
    gemm_bt<<<dim3(16, 88, 1), 256, 0, stream>>>(h2, wtshgu, nullptr, gsh, nullptr,
                                                 TOKENS, 2*SH_I, HIDDEN, HIDDEN, HIDDEN, 2*SH_I, 0, 0, 0);
    silu_k<<<(TOKENS * SH_I) / 1024, 256, 0, stream>>>(gsh, ash, seg, SH_I, 2*SH_I, TOKENS, nullptr);
    transpose_wz<<<dim3(64, 176, 1), 256, 0, stream>>>(w_sd, wtshd, SH_I, HIDDEN, 0, 0, 0);
    gemm_bt<<<dim3(16, 16, 2), 256, 0, stream>>>(ash, wtshd, ysh, nullptr, nullptr,
                                                 TOKENS, HIDDEN, SH_I/2, SH_I, SH_I, 2048,
                                                 (long)TOKENS * HIDDEN, 0, 4);

    // 8) Final gather-sum
    final_k<<<(TOKENS * HIDDEN) / 1024, 256, 0, stream>>>(x1, ymoe, inv, ysh, out);
}

// Round 7
// 1155.113 us; speedup vs baseline: 2.2882x; 1.0105x over previous
//
#include <hip/hip_runtime.h>
#include <hip/hip_bf16.h>
#include <math.h>

#define TOKENS 2048
#define HIDDEN 2048
#define NH 16
#define HD 128
#define SEQ 1024
#define MOE_I 1408
#define SH_I 5632
#define K3 6144       // logical cat-K (hi.hi + lo.hi + hi.lo)
#define MAXROWS 5120

typedef __hip_bfloat16 bf16;
typedef short bf16x8 __attribute__((ext_vector_type(8)));
typedef short bf16x4 __attribute__((ext_vector_type(4)));
typedef float f32x4 __attribute__((ext_vector_type(4)));
typedef float f32x16 __attribute__((ext_vector_type(16)));

__device__ __forceinline__ float b2f(bf16 x) { return __bfloat162float(x); }
__device__ __forceinline__ bf16 f2b(float x) { return __float2bfloat16(x); }
__device__ __forceinline__ void split2(float v, short& hi, short& lo) {
    bf16 h = f2b(v);
    bf16 l = f2b(v - b2f(h));
    hi = __builtin_bit_cast(short, h); lo = __builtin_bit_cast(short, l);
}

__device__ __forceinline__ void load_lds16(const void* g, void* l) {
    __builtin_amdgcn_global_load_lds(
        (const __attribute__((address_space(1))) unsigned int*)g,
        (__attribute__((address_space(3))) unsigned int*)l, 16, 0, 0);
}

// ---------------------------------------------------------------------------
__global__ __launch_bounds__(256) void rmsnorm3_k(
    const float* __restrict__ x, const float* __restrict__ w, bf16* __restrict__ out)
{
    const int row = blockIdx.x, tid = threadIdx.x;
    const float4* xr = (const float4*)(x + (size_t)row * HIDDEN);
    float4 v1 = xr[tid], v2 = xr[tid + 256];
    float ss = v1.x*v1.x + v1.y*v1.y + v1.z*v1.z + v1.w*v1.w
             + v2.x*v2.x + v2.y*v2.y + v2.z*v2.z + v2.w*v2.w;
    #pragma unroll
    for (int off = 1; off < 64; off <<= 1) ss += __shfl_xor(ss, off);
    __shared__ float ps[4];
    if ((tid & 63) == 0) ps[tid >> 6] = ss;
    __syncthreads();
    float tot = ps[0] + ps[1] + ps[2] + ps[3];
    float r = rsqrtf(tot * (1.0f / HIDDEN) + 1e-6f);
    bf16* o = out + (size_t)row * 4096;
    float vv[8] = {v1.x, v1.y, v1.z, v1.w, v2.x, v2.y, v2.z, v2.w};
    int idx[8]  = {tid*4, tid*4+1, tid*4+2, tid*4+3,
                   1024+tid*4, 1024+tid*4+1, 1024+tid*4+2, 1024+tid*4+3};
    #pragma unroll
    for (int u = 0; u < 8; u++) {
        short hi, lo; split2(vv[u] * r * w[idx[u]], hi, lo);
        o[idx[u]]        = __builtin_bit_cast(bf16, hi);
        o[2048 + idx[u]] = __builtin_bit_cast(bf16, lo);
    }
}

// ---------------------------------------------------------------------------
__global__ __launch_bounds__(256) void transpose_wz(
    const float* __restrict__ W, bf16* __restrict__ Wt, int K, int N,
    int nOff, long zsrc, long zdst)
{
    __shared__ float t[32][33];
    W  += (size_t)blockIdx.z * zsrc;
    Wt += (size_t)blockIdx.z * zdst;
    const int n0 = blockIdx.x * 32, k0 = blockIdx.y * 32;
    const int tx = threadIdx.x & 31, ty = threadIdx.x >> 5;
    #pragma unroll
    for (int i = 0; i < 4; i++)
        t[ty + i*8][tx] = W[(size_t)(k0 + ty + i*8) * N + n0 + tx];
    __syncthreads();
    #pragma unroll
    for (int i = 0; i < 4; i++)
        Wt[(size_t)(nOff + n0 + ty + i*8) * K + k0 + tx] = f2b(t[tx][ty + i*8]);
}

__global__ __launch_bounds__(256) void transpose_w3(
    const float* __restrict__ W, bf16* __restrict__ Wt2, int K, int N, int nOff)
{
    __shared__ float t[32][33];
    const int n0 = blockIdx.x * 32, k0 = blockIdx.y * 32;
    const int tx = threadIdx.x & 31, ty = threadIdx.x >> 5;
    #pragma unroll
    for (int i = 0; i < 4; i++)
        t[ty + i*8][tx] = W[(size_t)(k0 + ty + i*8) * N + n0 + tx];
    __syncthreads();
    #pragma unroll
    for (int i = 0; i < 4; i++) {
        float v = t[tx][ty + i*8];
        short hi, lo; split2(v, hi, lo);
        bf16* o = Wt2 + (size_t)(nOff + n0 + ty + i*8) * (2*K) + k0 + tx;
        o[0] = __builtin_bit_cast(bf16, hi);
        o[K] = __builtin_bit_cast(bf16, lo);
    }
}

// ---------------------------------------------------------------------------
// GEMM: C[M,N] = A @ Bt^T, 128x128x32 tile, 32x32x16 MFMA (2x2 frags/wave).
// XCD-bijective block swizzle (m204) for L2 panel reuse.
// limb3: A/B phys [hi|lo], logical kcat in [0,6144) remapped.
// epi: 0 = bf16 store; 4 = f32 store at Cf + z*zCstride; 5 = f32 + bias store.
__global__ __launch_bounds__(256) void gemm_bt(
    const bf16* __restrict__ A, const bf16* __restrict__ Bt,
    float* __restrict__ Cf, bf16* __restrict__ Cb, const float* __restrict__ bias,
    int M, int N, int K, int ldA, int ldB, int ldC, long zCstride, int limb3, int epi)
{
    __shared__ __align__(16) bf16 As[128 * 32];
    __shared__ __align__(16) bf16 Bs[128 * 32];
    const int tid = threadIdx.x;
    const int lane = tid & 63, wid = tid >> 6;
    const int l32 = lane & 31, lh2 = lane >> 5;
    const int wr = wid >> 1, wc = wid & 1;
    // XCD-bijective swizzle over (x,y)
    int lid = blockIdx.y * gridDim.x + blockIdx.x;
    {
        const int nwg = gridDim.x * gridDim.y;
        const int q = nwg >> 3, r = nwg & 7;
        const int xcd = lid & 7, idx = lid >> 3;
        lid = (xcd < r ? xcd * (q + 1) : r * (q + 1) + (xcd - r) * q) + idx;
    }
    const int m0 = (lid % gridDim.x) * 128, n0 = (lid / gridDim.x) * 128;
    const int f = tid * 8;
    const int r0 = f >> 5, c0 = f & 31;
    const int koff = blockIdx.z * K;

    f32x16 acc[2][2];
    #pragma unroll
    for (int m = 0; m < 2; m++)
        #pragma unroll
        for (int n = 0; n < 2; n++)
            #pragma unroll
            for (int j = 0; j < 16; j++) acc[m][n][j] = 0.f;

    const bf16* Ag0 = A + (size_t)(m0 + r0) * ldA + c0;
    const bf16* Ag1 = Ag0 + (size_t)64 * ldA;
    const bf16* Bg0 = Bt + (size_t)(n0 + r0) * ldB + c0;
    const bf16* Bg1 = Bg0 + (size_t)64 * ldB;

    for (int k0 = 0; k0 < K; k0 += 32) {
        const int kcat = koff + k0;
        int ka = kcat, kb = kcat;
        if (limb3) {
            ka = (kcat >= 4096) ? kcat - 4096 : kcat;
            kb = (kcat >= 2048) ? kcat - 2048 : kcat;
        }
        __syncthreads();
        load_lds16(Ag0 + ka, As + f);
        load_lds16(Ag1 + ka, As + f + 2048);
        load_lds16(Bg0 + kb, Bs + f);
        load_lds16(Bg1 + kb, Bs + f + 2048);
        __syncthreads();
        bf16x8 a[2][2], b[2][2];
        #pragma unroll
        for (int m = 0; m < 2; m++)
            #pragma unroll
            for (int kk = 0; kk < 2; kk++)
                a[m][kk] = *(const bf16x8*)&As[(wr*64 + m*32 + l32) * 32 + kk*16 + lh2*8];
        #pragma unroll
        for (int n = 0; n < 2; n++)
            #pragma unroll
            for (int kk = 0; kk < 2; kk++)
                b[n][kk] = *(const bf16x8*)&Bs[(wc*64 + n*32 + l32) * 32 + kk*16 + lh2*8];
        #pragma unroll
        for (int m = 0; m < 2; m++)
            #pragma unroll
            for (int n = 0; n < 2; n++)
                #pragma unroll
                for (int kk = 0; kk < 2; kk++)
                    acc[m][n] = __builtin_amdgcn_mfma_f32_32x32x16_bf16(a[m][kk], b[n][kk], acc[m][n], 0, 0, 0);
    }

    float* Cz = Cf + (size_t)blockIdx.z * zCstride;
    #pragma unroll
    for (int m = 0; m < 2; m++) {
        const int base_m = m0 + wr*64 + m*32 + 4*lh2;
        #pragma unroll
        for (int n = 0; n < 2; n++) {
            const int gcol = n0 + wc*64 + n*32 + l32;
            #pragma unroll
            for (int reg = 0; reg < 16; reg++) {
                const int grow = base_m + (reg & 3) + 8*(reg >> 2);
                const size_t o = (size_t)grow * ldC + gcol;
                const float v = acc[m][n][reg];
                if (epi == 0)      Cb[o] = f2b(v);
                else if (epi == 4) Cz[o] = v;
                else               Cf[o] = v + bias[gcol];
            }
        }
    }
}

// ---------------------------------------------------------------------------
__global__ __launch_bounds__(256) void gemm_gu(
    const bf16* __restrict__ A, const bf16* __restrict__ BtAll,
    const int* __restrict__ offc, const int* __restrict__ perm,
    bf16* __restrict__ C)
{
    const int e = blockIdx.z;
    const int off = offc[8 + e];
    const int padCnt = offc[9 + e] - off;
    const int m0 = blockIdx.x * 128;
    if (m0 >= padCnt) return;
    __shared__ __align__(16) bf16 As[128 * 32];
    __shared__ __align__(16) bf16 Bs[128 * 32];
    const int tid = threadIdx.x;
    const int lane = tid & 63, wid = tid >> 6;
    const int l32 = lane & 31, lh2 = lane >> 5;
    const int wr = wid >> 1, wc = wid & 1;
    const int n0 = blockIdx.y * 128;
    const int f = tid * 8;
    const int r0 = f >> 5, c0 = f & 31;
    const bf16* Bt = BtAll + (size_t)e * 2816 * 2048;

    int t0 = perm[off + m0 + r0];      if (t0 < 0) t0 = 0;
    int t1 = perm[off + m0 + r0 + 64]; if (t1 < 0) t1 = 0;

    f32x16 acc[2][2];
    #pragma unroll
    for (int m = 0; m < 2; m++)
        #pragma unroll
        for (int n = 0; n < 2; n++)
            #pragma unroll
            for (int j = 0; j < 16; j++) acc[m][n][j] = 0.f;

    const bf16* Ag0 = A + (size_t)t0 * 2048 + c0;
    const bf16* Ag1 = A + (size_t)t1 * 2048 + c0;
    const bf16* Bg0 = Bt + (size_t)(n0 + r0) * 2048 + c0;
    const bf16* Bg1 = Bg0 + (size_t)64 * 2048;

    for (int k0 = 0; k0 < 2048; k0 += 32) {
        __syncthreads();
        load_lds16(Ag0 + k0, As + f);
        load_lds16(Ag1 + k0, As + f + 2048);
        load_lds16(Bg0 + k0, Bs + f);
        load_lds16(Bg1 + k0, Bs + f + 2048);
        __syncthreads();
        bf16x8 a[2][2], b[2][2];
        #pragma unroll
        for (int m = 0; m < 2; m++)
            #pragma unroll
            for (int kk = 0; kk < 2; kk++)
                a[m][kk] = *(const bf16x8*)&As[(wr*64 + m*32 + l32) * 32 + kk*16 + lh2*8];
        #pragma unroll
        for (int n = 0; n < 2; n++)
            #pragma unroll
            for (int kk = 0; kk < 2; kk++)
                b[n][kk] = *(const bf16x8*)&Bs[(wc*64 + n*32 + l32) * 32 + kk*16 + lh2*8];
        #pragma unroll
        for (int m = 0; m < 2; m++)
            #pragma unroll
            for (int n = 0; n < 2; n++)
                #pragma unroll
                for (int kk = 0; kk < 2; kk++)
                    acc[m][n] = __builtin_amdgcn_mfma_f32_32x32x16_bf16(a[m][kk], b[n][kk], acc[m][n], 0, 0, 0);
    }

    #pragma unroll
    for (int m = 0; m < 2; m++) {
        const int base_m = m0 + wr*64 + m*32 + 4*lh2;
        #pragma unroll
        for (int n = 0; n < 2; n++) {
            const int gcol = n0 + wc*64 + n*32 + l32;
            #pragma unroll
            for (int reg = 0; reg < 16; reg++) {
                const int grow = base_m + (reg & 3) + 8*(reg >> 2);
                C[(size_t)(off + grow) * 2816 + gcol] = f2b(acc[m][n][reg]);
            }
        }
    }
}

__global__ __launch_bounds__(256) void gemm_down(
    const bf16* __restrict__ A, const bf16* __restrict__ BtAll,
    const int* __restrict__ offc, bf16* __restrict__ Y)
{
    const int e = blockIdx.z;
    const int off = offc[8 + e];
    const int padCnt = offc[9 + e] - off;
    const int m0 = blockIdx.x * 128;
    if (m0 >= padCnt) return;
    __shared__ __align__(16) bf16 As[128 * 32];
    __shared__ __align__(16) bf16 Bs[128 * 32];
    const int tid = threadIdx.x;
    const int lane = tid & 63, wid = tid >> 6;
    const int l32 = lane & 31, lh2 = lane >> 5;
    const int wr = wid >> 1, wc = wid & 1;
    const int n0 = blockIdx.y * 128;
    const int f = tid * 8;
    const int r0 = f >> 5, c0 = f & 31;
    const bf16* Bt = BtAll + (size_t)e * 2048 * 1408;

    f32x16 acc[2][2];
    #pragma unroll
    for (int m = 0; m < 2; m++)
        #pragma unroll
        for (int n = 0; n < 2; n++)
            #pragma unroll
            for (int j = 0; j < 16; j++) acc[m][n][j] = 0.f;

    const bf16* Ag0 = A + (size_t)(off + m0 + r0) * 1408 + c0;
    const bf16* Ag1 = Ag0 + (size_t)64 * 1408;
    const bf16* Bg0 = Bt + (size_t)(n0 + r0) * 1408 + c0;
    const bf16* Bg1 = Bg0 + (size_t)64 * 1408;

    for (int k0 = 0; k0 < 1408; k0 += 32) {
        __syncthreads();
        load_lds16(Ag0 + k0, As + f);
        load_lds16(Ag1 + k0, As + f + 2048);
        load_lds16(Bg0 + k0, Bs + f);
        load_lds16(Bg1 + k0, Bs + f + 2048);
        __syncthreads();
        bf16x8 a[2][2], b[2][2];
        #pragma unroll
        for (int m = 0; m < 2; m++)
            #pragma unroll
            for (int kk = 0; kk < 2; kk++)
                a[m][kk] = *(const bf16x8*)&As[(wr*64 + m*32 + l32) * 32 + kk*16 + lh2*8];
        #pragma unroll
        for (int n = 0; n < 2; n++)
            #pragma unroll
            for (int kk = 0; kk < 2; kk++)
                b[n][kk] = *(const bf16x8*)&Bs[(wc*64 + n*32 + l32) * 32 + kk*16 + lh2*8];
        #pragma unroll
        for (int m = 0; m < 2; m++)
            #pragma unroll
            for (int n = 0; n < 2; n++)
                #pragma unroll
                for (int kk = 0; kk < 2; kk++)
                    acc[m][n] = __builtin_amdgcn_mfma_f32_32x32x16_bf16(a[m][kk], b[n][kk], acc[m][n], 0, 0, 0);
    }

    #pragma unroll
    for (int m = 0; m < 2; m++) {
        const int base_m = m0 + wr*64 + m*32 + 4*lh2;
        #pragma unroll
        for (int n = 0; n < 2; n++) {
            const int gcol = n0 + wc*64 + n*32 + l32;
            #pragma unroll
            for (int reg = 0; reg < 16; reg++) {
                const int grow = base_m + (reg & 3) + 8*(reg >> 2);
                Y[(size_t)(off + grow) * 2048 + gcol] = f2b(acc[m][n][reg]);
            }
        }
    }
}

// ---------------------------------------------------------------------------
// RoPE cos/sin table: cs[s][d] for s in [0,1024), d in [0,64)
__global__ void rope_table_k(float2* __restrict__ cs)
{
    const int i = blockIdx.x * 256 + threadIdx.x;   // < 65536
    const int s = i >> 6, d = i & 63;
    const float fr = (float)s * powf(1.0e6f, -(float)d * (1.0f / 64.0f));
    float c, sn;
    sincosf(fr, &sn, &c);
    cs[i] = make_float2(c, sn);
}

__global__ void rope_f32_k(float* __restrict__ qkv, const float2* __restrict__ cs)
{
    const int idx = blockIdx.x * 256 + threadIdx.x;
    const int d  = idx & 63;
    const int hh = (idx >> 6) & 15;
    const size_t base = (size_t)(idx >> 10) * 6144 + hh * HD;
    const int s = (idx >> 10) & 1023;
    const float2 t = cs[(s << 6) | d];
    const float c = t.x, sn = t.y;
    float q0 = qkv[base + d], q1 = qkv[base + d + 64];
    qkv[base + d]      = q0 * c - q1 * sn;
    qkv[base + d + 64] = q1 * c + q0 * sn;
    float k0 = qkv[base + 2048 + d], k1 = qkv[base + 2048 + d + 64];
    qkv[base + 2048 + d]      = k0 * c - k1 * sn;
    qkv[base + 2048 + d + 64] = k1 * c + k0 * sn;
}

// ---------------------------------------------------------------------------
__global__ __launch_bounds__(256) void transpose_v3_k(
    const float* __restrict__ qkv, bf16* __restrict__ vth, bf16* __restrict__ vtl)
{
    __shared__ float t[32][33];
    const int s0 = blockIdx.x * 32, d0 = blockIdx.y * 32;
    const int bh = blockIdx.z, b = bh >> 4, h = bh & 15;
    const int tx = threadIdx.x & 31, ty = threadIdx.x >> 5;
    const float* vb = qkv + ((size_t)b * SEQ) * 6144 + 4096 + h * HD;
    #pragma unroll
    for (int i = 0; i < 4; i++)
        t[ty + i*8][tx] = vb[(size_t)(s0 + ty + i*8) * 6144 + d0 + tx];
    __syncthreads();
    const size_t ob = ((size_t)bh * HD) * SEQ;
    #pragma unroll
    for (int i = 0; i < 4; i++) {
        float val = t[tx][ty + i*8];
        short hi, lo; split2(val, hi, lo);
        const size_t o = ob + (size_t)(d0 + ty + i*8) * SEQ + s0 + tx;
        vth[o] = __builtin_bit_cast(bf16, hi);
        vtl[o] = __builtin_bit_cast(bf16, lo);
    }
}

// ---------------------------------------------------------------------------
__global__ __launch_bounds__(256) void attn3_k(
    const float* __restrict__ qkv,
    const bf16* __restrict__ vth, const bf16* __restrict__ vtl,
    bf16* __restrict__ ctx2)
{
    __shared__ __align__(16) bf16 Ksh[32 * 128], Ksl[32 * 128];
    __shared__ __align__(16) bf16 Vth[128 * 32], Vtl[128 * 32];
    __shared__ __align__(16) bf16 Ph[4][16 * 32], Pl[4][16 * 32];
    const int tid = threadIdx.x, lane = tid & 63, wid = tid >> 6;
    const int l16 = lane & 15, lh = lane >> 4;
    const int bh = blockIdx.y, b = bh >> 4, h = bh & 15;
    const int qbase = blockIdx.x * 64;
    const int qw = qbase + wid * 16;
    const float* qp = qkv + ((size_t)b * SEQ) * 6144 + h * HD;
    const float* kp = qkv + ((size_t)b * SEQ) * 6144 + 2048 + h * HD;
    const bf16* vph = vth + ((size_t)bh * HD) * SEQ;
    const bf16* vpl = vtl + ((size_t)bh * HD) * SEQ;

    bf16x8 aqh[4], aql[4];
    #pragma unroll
    for (int c = 0; c < 4; c++) {
        const float* qrow = qp + (size_t)(qw + l16) * 6144 + c*32 + lh*8;
        #pragma unroll
        for (int u = 0; u < 8; u++) {
            short hi, lo; split2(qrow[u], hi, lo);
            aqh[c][u] = hi; aql[c][u] = lo;
        }
    }

    f32x4 o[8];
    #pragma unroll
    for (int n = 0; n < 8; n++) o[n] = (f32x4){0.f, 0.f, 0.f, 0.f};
    float mj[4], lj[4];
    #pragma unroll
    for (int j = 0; j < 4; j++) { mj[j] = -1e30f; lj[j] = 0.f; }

    const int f = tid * 8;
    const int kr = tid >> 3, kc = (tid & 7) * 16;
    const int kt_end = qbase / 32 + 2;
    for (int kt = 0; kt < kt_end; ++kt) {
        const int kv0 = kt * 32;
        __syncthreads();
        {
            const float* krow = kp + (size_t)(kv0 + kr) * 6144 + kc;
            #pragma unroll
            for (int u = 0; u < 4; u++) {
                float4 kv4 = *(const float4*)(krow + u*4);
                short h0, l0, h1, l1, h2s, l2s, h3, l3;
                split2(kv4.x, h0, l0); split2(kv4.y, h1, l1);
                split2(kv4.z, h2s, l2s); split2(kv4.w, h3, l3);
                bf16x4 h4, l4;
                h4[0] = h0; h4[1] = h1; h4[2] = h2s; h4[3] = h3;
                l4[0] = l0; l4[1] = l1; l4[2] = l2s; l4[3] = l3;
                *(bf16x4*)&Ksh[kr*128 + kc + u*4] = h4;
                *(bf16x4*)&Ksl[kr*128 + kc + u*4] = l4;
            }
        }
        load_lds16(vph + (size_t)(f >> 5) * SEQ + kv0 + (f & 31), Vth + f);
        load_lds16(vph + (size_t)((f >> 5) + 64) * SEQ + kv0 + (f & 31), Vth + f + 2048);
        load_lds16(vpl + (size_t)(f >> 5) * SEQ + kv0 + (f & 31), Vtl + f);
        load_lds16(vpl + (size_t)((f >> 5) + 64) * SEQ + kv0 + (f & 31), Vtl + f + 2048);
        __syncthreads();

        f32x4 s0a = (f32x4){0.f,0.f,0.f,0.f}, s1a = (f32x4){0.f,0.f,0.f,0.f};
        #pragma unroll
        for (int c = 0; c < 4; c++) {
            bf16x8 bk0h = *(const bf16x8*)&Ksh[(l16) * 128 + c*32 + lh*8];
            bf16x8 bk0l = *(const bf16x8*)&Ksl[(l16) * 128 + c*32 + lh*8];
            bf16x8 bk1h = *(const bf16x8*)&Ksh[(l16 + 16) * 128 + c*32 + lh*8];
            bf16x8 bk1l = *(const bf16x8*)&Ksl[(l16 + 16) * 128 + c*32 + lh*8];
            s0a = __builtin_amdgcn_mfma_f32_16x16x32_bf16(aqh[c], bk0h, s0a, 0, 0, 0);
            s0a = __builtin_amdgcn_mfma_f32_16x16x32_bf16(aql[c], bk0h, s0a, 0, 0, 0);
            s0a = __builtin_amdgcn_mfma_f32_16x16x32_bf16(aqh[c], bk0l, s0a, 0, 0, 0);
            s1a = __builtin_amdgcn_mfma_f32_16x16x32_bf16(aqh[c], bk1h, s1a, 0, 0, 0);
            s1a = __builtin_amdgcn_mfma_f32_16x16x32_bf16(aql[c], bk1h, s1a, 0, 0, 0);
            s1a = __builtin_amdgcn_mfma_f32_16x16x32_bf16(aqh[c], bk1l, s1a, 0, 0, 0);
        }
        const float scale = 0.08838834764831845f;
        #pragma unroll
        for (int j = 0; j < 4; j++) {
            const int qrow = qw + lh*4 + j;
            float s0 = s0a[j] * scale, s1 = s1a[j] * scale;
            if (kv0 + l16 > qrow)      s0 = -1e30f;
            if (kv0 + l16 + 16 > qrow) s1 = -1e30f;
            float mx = fmaxf(s0, s1);
            #pragma unroll
            for (int off = 1; off < 16; off <<= 1) mx = fmaxf(mx, __shfl_xor(mx, off, 16));
            const float nm = fmaxf(mj[j], mx);
            const float al = __expf(mj[j] - nm);
            const float p0 = __expf(s0 - nm), p1 = __expf(s1 - nm);
            float rs = p0 + p1;
            #pragma unroll
            for (int off = 1; off < 16; off <<= 1) rs += __shfl_xor(rs, off, 16);
            lj[j] = lj[j] * al + rs;
            mj[j] = nm;
            #pragma unroll
            for (int n = 0; n < 8; n++) o[n][j] *= al;
            short h0, l0, h1, l1;
            split2(p0, h0, l0); split2(p1, h1, l1);
            Ph[wid][(lh*4 + j) * 32 + l16]      = __builtin_bit_cast(bf16, h0);
            Pl[wid][(lh*4 + j) * 32 + l16]      = __builtin_bit_cast(bf16, l0);
            Ph[wid][(lh*4 + j) * 32 + l16 + 16] = __builtin_bit_cast(bf16, h1);
            Pl[wid][(lh*4 + j) * 32 + l16 + 16] = __builtin_bit_cast(bf16, l1);
        }
        __syncthreads();
        const bf16x8 aph = *(const bf16x8*)&Ph[wid][l16 * 32 + lh*8];
        const bf16x8 apl = *(const bf16x8*)&Pl[wid][l16 * 32 + lh*8];
        #pragma unroll
        for (int n = 0; n < 8; n++) {
            bf16x8 bvh = *(const bf16x8*)&Vth[(n*16 + l16) * 32 + lh*8];
            bf16x8 bvl = *(const bf16x8*)&Vtl[(n*16 + l16) * 32 + lh*8];
            o[n] = __builtin_amdgcn_mfma_f32_16x16x32_bf16(aph, bvh, o[n], 0, 0, 0);
            o[n] = __builtin_amdgcn_mfma_f32_16x16x32_bf16(apl, bvh, o[n], 0, 0, 0);
            o[n] = __builtin_amdgcn_mfma_f32_16x16x32_bf16(aph, bvl, o[n], 0, 0, 0);
        }
    }

    float inv[4];
    #pragma unroll
    for (int j = 0; j < 4; j++) inv[j] = 1.0f / lj[j];
    #pragma unroll
    for (int n = 0; n < 8; n++)
        #pragma unroll
        for (int j = 0; j < 4; j++) {
            const float v = o[n][j] * inv[j];
            short hi, lo; split2(v, hi, lo);
            const size_t base = ((size_t)b * SEQ + (qw + lh*4 + j)) * 4096 + h * HD + n*16 + l16;
            ctx2[base]        = __builtin_bit_cast(bf16, hi);
            ctx2[base + 2048] = __builtin_bit_cast(bf16, lo);
        }
}

// ---------------------------------------------------------------------------
__global__ __launch_bounds__(256) void combine_rms_k(
    const float* __restrict__ x, const float* __restrict__ xp,
    const float* __restrict__ w, float* __restrict__ x1, bf16* __restrict__ h2)
{
    const int row = blockIdx.x, tid = threadIdx.x;
    const size_t rb = (size_t)row * HIDDEN;
    const long zs = (long)TOKENS * HIDDEN;
    float4 v[2];
    #pragma unroll
    for (int u = 0; u < 2; u++) {
        const int i = tid + u * 256;
        float4 a  = ((const float4*)(x + rb))[i];
        float4 p0 = ((const float4*)(xp + rb))[i];
        float4 p1 = ((const float4*)(xp + zs + rb))[i];
        float4 p2 = ((const float4*)(xp + 2*zs + rb))[i];
        v[u].x = a.x + p0.x + p1.x + p2.x;
        v[u].y = a.y + p0.y + p1.y + p2.y;
        v[u].z = a.z + p0.z + p1.z + p2.z;
        v[u].w = a.w + p0.w + p1.w + p2.w;
        ((float4*)(x1 + rb))[i] = v[u];
    }
    float ss = v[0].x*v[0].x + v[0].y*v[0].y + v[0].z*v[0].z + v[0].w*v[0].w
             + v[1].x*v[1].x + v[1].y*v[1].y + v[1].z*v[1].z + v[1].w*v[1].w;
    #pragma unroll
    for (int off = 1; off < 64; off <<= 1) ss += __shfl_xor(ss, off);
    __shared__ float ps[4];
    if ((tid & 63) == 0) ps[tid >> 6] = ss;
    __syncthreads();
    float tot = ps[0] + ps[1] + ps[2] + ps[3];
    float r = rsqrtf(tot * (1.0f / HIDDEN) + 1e-6f);
    #pragma unroll
    for (int u = 0; u < 2; u++) {
        const int i = (tid + u * 256) * 4;
        h2[rb + i]     = f2b(v[u].x * r * w[i]);
        h2[rb + i + 1] = f2b(v[u].y * r * w[i+1]);
        h2[rb + i + 2] = f2b(v[u].z * r * w[i+2]);
        h2[rb + i + 3] = f2b(v[u].w * r * w[i+3]);
    }
}

// ---------------------------------------------------------------------------
__global__ __launch_bounds__(256) void router_k(
    const float* __restrict__ x1, const float* __restrict__ wln,
    const float* __restrict__ wr, const float* __restrict__ weg,
    float* __restrict__ combine, float* __restrict__ sigeg)
{
    const int wid = threadIdx.x >> 6, lane = threadIdx.x & 63;
    const int t = blockIdx.x * 4 + wid;
    const float* xr = x1 + (size_t)t * HIDDEN;
    float ss = 0.f;
    for (int c = lane; c < HIDDEN; c += 64) { const float v = xr[c]; ss += v * v; }
    #pragma unroll
    for (int off = 1; off < 64; off <<= 1) ss += __shfl_xor(ss, off);
    const float r = rsqrtf(ss * (1.0f / HIDDEN) + 1e-6f);

    float acc[9];
    #pragma unroll
    for (int e = 0; e < 9; e++) acc[e] = 0.f;
    for (int c = lane; c < HIDDEN; c += 64) {
        const float hv = xr[c] * r * wln[c];
        const float* wrow = wr + (size_t)c * 8;
        #pragma unroll
        for (int e = 0; e < 8; e++) acc[e] += hv * wrow[e];
        acc[8] += hv * weg[c];
    }
    #pragma unroll
    for (int e = 0; e < 9; e++)
        #pragma unroll
        for (int off = 1; off < 64; off <<= 1) acc[e] += __shfl_xor(acc[e], off);
    float mx = acc[0];
    #pragma unroll
    for (int e = 1; e < 8; e++) mx = fmaxf(mx, acc[e]);
    float p[8], s = 0.f;
    #pragma unroll
    for (int e = 0; e < 8; e++) { p[e] = expf(acc[e] - mx); s += p[e]; }
    const float invs = 1.0f / s;
    #pragma unroll
    for (int e = 0; e < 8; e++) p[e] *= invs;
    int i1 = 0;
    #pragma unroll
    for (int e = 1; e < 8; e++) if (p[e] > p[i1]) i1 = e;
    int i2 = (i1 == 0) ? 1 : 0;
    #pragma unroll
    for (int e = 0; e < 8; e++) if (e != i1 && p[e] > p[i2]) i2 = e;
    if (lane < 8) combine[(size_t)t * 8 + lane] = (lane == i1 || lane == i2) ? p[lane] : 0.f;
    if (lane == 0) sigeg[t] = 1.0f / (1.0f + expf(-acc[8]));
}

// ---------------------------------------------------------------------------
__global__ __launch_bounds__(256) void count_fill_k(
    const float* __restrict__ comb, int* __restrict__ offc, int* __restrict__ perm,
    float* __restrict__ scale, int* __restrict__ inv)
{
    __shared__ int cnt[8], off[9], fil[8];
    const int tid = threadIdx.x;
    if (tid < 8) { cnt[tid] = 0; fil[tid] = 0; }
    __syncthreads();
    for (int t = tid; t < TOKENS; t += 256)
        #pragma unroll
        for (int e = 0; e < 8; e++)
            if (comb[(size_t)t * 8 + e] > 0.f) atomicAdd(&cnt[e], 1);
    __syncthreads();
    if (tid == 0) {
        off[0] = 0;
        for (int e = 0; e < 8; e++) off[e+1] = off[e] + ((cnt[e] + 127) & ~127);
    }
    __syncthreads();
    for (int i = tid; i < MAXROWS; i += 256) { perm[i] = -1; scale[i] = 0.f; }
    __syncthreads();
    for (int t = tid; t < TOKENS; t += 256) {
        int j = 0;
        #pragma unroll
        for (int e = 0; e < 8; e++) {
            const float c = comb[(size_t)t * 8 + e];
            if (c > 0.f) {
                int s = atomicAdd(&fil[e], 1);
                int slot = off[e] + s;
                perm[slot] = t;
                scale[slot] = c;
                inv[t * 2 + j] = slot;
                j++;
            }
        }
    }
    __syncthreads();
    if (tid < 9) offc[8 + tid] = off[tid];
}

// ---------------------------------------------------------------------------
__global__ void silu_k(const bf16* __restrict__ g, bf16* __restrict__ a,
                       const float* __restrict__ rowScale,
                       int I, int ldg, int rowsConst, const int* __restrict__ rowsPtr)
{
    const int idx = (blockIdx.x * 256 + threadIdx.x) * 4;
    const int rows = rowsPtr ? *rowsPtr : rowsConst;
    const int row = idx / I;
    if (row >= rows) return;
    const int col = idx - row * I;
    const float s = rowScale[row];
    const bf16* gr = g + (size_t)row * ldg + col;
    bf16* ar = a + (size_t)row * I + col;
    #pragma unroll
    for (int c = 0; c < 4; c++) {
        const float gv = b2f(gr[c]), uv = b2f(gr[I + c]);
        ar[c] = f2b(s * gv / (1.0f + __expf(-gv)) * uv);
    }
}

// ---------------------------------------------------------------------------
__global__ void final_k(const float* __restrict__ x1, const bf16* __restrict__ y,
                        const int* __restrict__ inv, const float* __restrict__ ysh,
                        float* __restrict__ out)
{
    const int i = blockIdx.x * 256 + threadIdx.x;   // float4 index
    const int t = i >> 9;
    const int col = (i & 511) * 4;
    const int s0 = inv[t*2], s1 = inv[t*2 + 1];
    const long zs = (long)TOKENS * HIDDEN;
    float4 a  = ((const float4*)x1)[i];
    float4 h0 = ((const float4*)ysh)[i];
    float4 h1 = ((const float4*)(ysh + zs))[i];
    const bf16* y0 = y + (size_t)s0 * 2048 + col;
    const bf16* y1 = y + (size_t)s1 * 2048 + col;
    float4 r;
    r.x = a.x + h0.x + h1.x + b2f(y0[0]) + b2f(y1[0]);
    r.y = a.y + h0.y + h1.y + b2f(y0[1]) + b2f(y1[1]);
    r.z = a.z + h0.z + h1.z + b2f(y0[2]) + b2f(y1[2]);
    r.w = a.w + h0.w + h1.w + b2f(y0[3]) + b2f(y1[3]);
    ((float4*)out)[i] = r;
}

// ---------------------------------------------------------------------------
extern "C" void kernel_launch(void* const* d_in, const int* in_sizes, int n_in,
                              void* d_out, int out_size, void* d_ws, size_t ws_size,
                              hipStream_t stream)
{
    const float* x     = (const float*)d_in[0];
    const float* w_ln1 = (const float*)d_in[1];
    const float* wq    = (const float*)d_in[2];
    const float* bq    = (const float*)d_in[3];
    const float* wk    = (const float*)d_in[4];
    const float* bk    = (const float*)d_in[5];
    const float* wv    = (const float*)d_in[6];
    const float* bv    = (const float*)d_in[7];
    const float* wo    = (const float*)d_in[8];
    const float* w_ln2 = (const float*)d_in[9];
    const float* w_rt  = (const float*)d_in[10];
    const float* w_ge  = (const float*)d_in[11];
    const float* w_ue  = (const float*)d_in[12];
    const float* w_de  = (const float*)d_in[13];
    const float* w_sg  = (const float*)d_in[14];
    const float* w_su  = (const float*)d_in[15];
    const float* w_sd  = (const float*)d_in[16];
    const float* w_eg  = (const float*)d_in[17];
    float* out = (float*)d_out;
    (void)in_sizes; (void)n_in; (void)out_size; (void)ws_size;

    char* ws = (char*)d_ws;
    // persistent
    float* x1    = (float*)(ws + 0);
    bf16*  h2    = (bf16*)(ws + 16777216);
    float* comb  = (float*)(ws + 25165824);
    float* seg   = (float*)(ws + 25231360);
    int*   offc  = (int*)(ws + 25239552);
    float* scale = (float*)(ws + 25243648);
    int*   perm  = (int*)(ws + 25276416);
    int*   inv   = (int*)(ws + 25297920);
    float* bqkv  = (float*)(ws + 25314304);
    float2* ropecs = (float2*)(ws + 25338880);          // 512KB -> ends 25863168
    const size_t S = 25863168;
    // phase A
    bf16*  hcat  = (bf16*)(ws + S);
    bf16*  wtqkv = (bf16*)(ws + S + 16777216);
    float* qkvf  = (float*)(ws + S + 67108864);          // ends S+117440512
    bf16*  vth   = (bf16*)(ws + S);
    bf16*  vtl   = (bf16*)(ws + S + 8388608);
    bf16*  ctx2  = (bf16*)(ws + S + 16777216);
    bf16*  wt3o  = (bf16*)(ws + S + 33554432);
    float* xp    = (float*)(ws + S + 50331648);          // 3x16.78M
    // phase B
    bf16*  wtgu  = (bf16*)(ws + S);
    bf16*  gb    = (bf16*)(ws + S + 92274688);
    bf16*  ab    = (bf16*)(ws + S);
    bf16*  wtd   = (bf16*)(ws + S + 14417920);
    bf16*  ymoe  = (bf16*)(ws + S + 60555264);
    // phase C
    bf16*  wtshgu = (bf16*)(ws + S);
    bf16*  gsh    = (bf16*)(ws + S + 81526784);
    bf16*  ash    = (bf16*)(ws + S);
    bf16*  wtshd  = (bf16*)(ws + S + 23068672);
    float* ysh    = (float*)(ws + S + 81526784);

    // 1) RMSNorm1 -> hcat; QKV bias concat; rope table
    rmsnorm3_k<<<TOKENS, 256, 0, stream>>>(x, w_ln1, hcat);
    (void)hipMemcpyAsync(bqkv,        bq, 8192, hipMemcpyDeviceToDevice, stream);
    (void)hipMemcpyAsync(bqkv + 2048, bk, 8192, hipMemcpyDeviceToDevice, stream);
    (void)hipMemcpyAsync(bqkv + 4096, bv, 8192, hipMemcpyDeviceToDevice, stream);
    rope_table_k<<<256, 256, 0, stream>>>(ropecs);

    // 2) Fused QKV (limb3, N=6144, plain stores)
    transpose_w3<<<dim3(64, 64), 256, 0, stream>>>(wq, wtqkv, HIDDEN, HIDDEN, 0);
    transpose_w3<<<dim3(64, 64), 256, 0, stream>>>(wk, wtqkv, HIDDEN, HIDDEN, 2048);
    transpose_w3<<<dim3(64, 64), 256, 0, stream>>>(wv, wtqkv, HIDDEN, HIDDEN, 4096);
    gemm_bt<<<dim3(16, 48, 1), 256, 0, stream>>>(hcat, wtqkv, qkvf, nullptr, bqkv,
                                                 TOKENS, 6144, K3, 4096, 4096, 6144, 0, 1, 5);

    // 3) RoPE + V transpose/split + attention
    rope_f32_k<<<8192, 256, 0, stream>>>(qkvf, ropecs);
    transpose_v3_k<<<dim3(32, 4, 32), 256, 0, stream>>>(qkvf, vth, vtl);
    attn3_k<<<dim3(16, 32), 256, 0, stream>>>(qkvf, vth, vtl, ctx2);

    // 4) O-proj (limb3, split-K z=3, plain stores) + fused combine/rms
    transpose_w3<<<dim3(64, 64), 256, 0, stream>>>(wo, wt3o, HIDDEN, HIDDEN, 0);
    gemm_bt<<<dim3(16, 16, 3), 256, 0, stream>>>(ctx2, wt3o, xp, nullptr, nullptr,
                                                 TOKENS, HIDDEN, 2048, 4096, 4096, 2048,
                                                 (long)TOKENS * HIDDEN, 1, 4);
    combine_rms_k<<<TOKENS, 256, 0, stream>>>(x, xp, w_ln2, x1, h2);

    // 5) Router + expert lists
    router_k<<<TOKENS / 4, 256, 0, stream>>>(x1, w_ln2, w_rt, w_eg, comb, seg);
    count_fill_k<<<1, 256, 0, stream>>>(comb, offc, perm, scale, inv);

    // 6) Sparse MoE
    transpose_wz<<<dim3(44, 64, 8), 256, 0, stream>>>(w_ge, wtgu, HIDDEN, MOE_I, 0,
                                                      (long)HIDDEN*MOE_I, (long)2816*HIDDEN);
    transpose_wz<<<dim3(44, 64, 8), 256, 0, stream>>>(w_ue, wtgu, HIDDEN, MOE_I, MOE_I,
                                                      (long)HIDDEN*MOE_I, (long)2816*HIDDEN);
    gemm_gu<<<dim3(MAXROWS/128, 22, 8), 256, 0, stream>>>(h2, wtgu, offc, perm, gb);
    silu_k<<<(MAXROWS * MOE_I) / 1024, 256, 0, stream>>>(gb, ab, scale, MOE_I, 2816, 0, offc + 16);
    transpose_wz<<<dim3(64, 44, 8), 256, 0, stream>>>(w_de, wtd, MOE_I, HIDDEN, 0,
                                                      (long)MOE_I*HIDDEN, (long)HIDDEN*MOE_I);
    gemm_down<<<dim3(MAXROWS/128, 16, 8), 256, 0, stream>>>(ab, wtd, offc, ymoe);

    // 7) Shared expert
    transpose_wz<<<dim3(176, 64, 1), 256, 0, stream>>>(w_sg, wtshgu, HIDDEN, SH_I, 0, 0, 0);
    transpose_wz<<<dim3(176, 64, 1), 256, 0, stream>>>(w_su, wtshgu, HIDDEN, SH_I, SH_I, 0, 0);
    gemm_bt<<<dim3(16, 88, 1), 256, 0, stream>>>(h2, wtshgu, nullptr, gsh, nullptr,
                                                 TOKENS, 2*SH_I, HIDDEN, HIDDEN, HIDDEN, 2*SH_I, 0, 0, 0);
    silu_k<<<(TOKENS * SH_I) / 1024, 256, 0, stream>>>(gsh, ash, seg, SH_I, 2*SH_I, TOKENS, nullptr);
    transpose_wz<<<dim3(64, 176, 1), 256, 0, stream>>>(w_sd, wtshd, SH_I, HIDDEN, 0, 0, 0);
    gemm_bt<<<dim3(16, 16, 2), 256, 0, stream>>>(ash, wtshd, ysh, nullptr, nullptr,
                                                 TOKENS, HIDDEN, SH_I/2, SH_I, SH_I, 2048,
                                                 (long)TOKENS * HIDDEN, 0, 4);

    // 8) Final gather-sum
    final_k<<<(TOKENS * HIDDEN) / 1024, 256, 0, stream>>>(x1, ymoe, inv, ysh, out);
}

// Round 8
// 1024.994 us; speedup vs baseline: 2.5787x; 1.1269x over previous
//
#include <hip/hip_runtime.h>
#include <hip/hip_bf16.h>
#include <math.h>

#define TOKENS 2048
#define HIDDEN 2048
#define NH 16
#define HD 128
#define SEQ 1024
#define MOE_I 1408
#define SH_I 5632
#define K3 6144       // logical cat-K (hi.hi + lo.hi + hi.lo)
#define MAXROWS 5120

typedef __hip_bfloat16 bf16;
typedef short bf16x8 __attribute__((ext_vector_type(8)));
typedef short bf16x4 __attribute__((ext_vector_type(4)));
typedef float f32x4 __attribute__((ext_vector_type(4)));
typedef float f32x16 __attribute__((ext_vector_type(16)));

__device__ __forceinline__ float b2f(bf16 x) { return __bfloat162float(x); }
__device__ __forceinline__ bf16 f2b(float x) { return __float2bfloat16(x); }
__device__ __forceinline__ void split2(float v, short& hi, short& lo) {
    bf16 h = f2b(v);
    bf16 l = f2b(v - b2f(h));
    hi = __builtin_bit_cast(short, h); lo = __builtin_bit_cast(short, l);
}

__device__ __forceinline__ void load_lds16(const void* g, void* l) {
    __builtin_amdgcn_global_load_lds(
        (const __attribute__((address_space(1))) unsigned int*)g,
        (__attribute__((address_space(3))) unsigned int*)l, 16, 0, 0);
}

// ---------------------------------------------------------------------------
__global__ __launch_bounds__(256) void rmsnorm3_k(
    const float* __restrict__ x, const float* __restrict__ w, bf16* __restrict__ out)
{
    const int row = blockIdx.x, tid = threadIdx.x;
    const float4* xr = (const float4*)(x + (size_t)row * HIDDEN);
    float4 v1 = xr[tid], v2 = xr[tid + 256];
    float ss = v1.x*v1.x + v1.y*v1.y + v1.z*v1.z + v1.w*v1.w
             + v2.x*v2.x + v2.y*v2.y + v2.z*v2.z + v2.w*v2.w;
    #pragma unroll
    for (int off = 1; off < 64; off <<= 1) ss += __shfl_xor(ss, off);
    __shared__ float ps[4];
    if ((tid & 63) == 0) ps[tid >> 6] = ss;
    __syncthreads();
    float tot = ps[0] + ps[1] + ps[2] + ps[3];
    float r = rsqrtf(tot * (1.0f / HIDDEN) + 1e-6f);
    bf16* o = out + (size_t)row * 4096;
    float vv[8] = {v1.x, v1.y, v1.z, v1.w, v2.x, v2.y, v2.z, v2.w};
    int idx[8]  = {tid*4, tid*4+1, tid*4+2, tid*4+3,
                   1024+tid*4, 1024+tid*4+1, 1024+tid*4+2, 1024+tid*4+3};
    #pragma unroll
    for (int u = 0; u < 8; u++) {
        short hi, lo; split2(vv[u] * r * w[idx[u]], hi, lo);
        o[idx[u]]        = __builtin_bit_cast(bf16, hi);
        o[2048 + idx[u]] = __builtin_bit_cast(bf16, lo);
    }
}

// ---------------------------------------------------------------------------
__global__ __launch_bounds__(256) void transpose_wz(
    const float* __restrict__ W, bf16* __restrict__ Wt, int K, int N,
    int nOff, long zsrc, long zdst)
{
    __shared__ float t[32][33];
    W  += (size_t)blockIdx.z * zsrc;
    Wt += (size_t)blockIdx.z * zdst;
    const int n0 = blockIdx.x * 32, k0 = blockIdx.y * 32;
    const int tx = threadIdx.x & 31, ty = threadIdx.x >> 5;
    #pragma unroll
    for (int i = 0; i < 4; i++)
        t[ty + i*8][tx] = W[(size_t)(k0 + ty + i*8) * N + n0 + tx];
    __syncthreads();
    #pragma unroll
    for (int i = 0; i < 4; i++)
        Wt[(size_t)(nOff + n0 + ty + i*8) * K + k0 + tx] = f2b(t[tx][ty + i*8]);
}

__global__ __launch_bounds__(256) void transpose_w3(
    const float* __restrict__ W, bf16* __restrict__ Wt2, int K, int N, int nOff)
{
    __shared__ float t[32][33];
    const int n0 = blockIdx.x * 32, k0 = blockIdx.y * 32;
    const int tx = threadIdx.x & 31, ty = threadIdx.x >> 5;
    #pragma unroll
    for (int i = 0; i < 4; i++)
        t[ty + i*8][tx] = W[(size_t)(k0 + ty + i*8) * N + n0 + tx];
    __syncthreads();
    #pragma unroll
    for (int i = 0; i < 4; i++) {
        float v = t[tx][ty + i*8];
        short hi, lo; split2(v, hi, lo);
        bf16* o = Wt2 + (size_t)(nOff + n0 + ty + i*8) * (2*K) + k0 + tx;
        o[0] = __builtin_bit_cast(bf16, hi);
        o[K] = __builtin_bit_cast(bf16, lo);
    }
}

// ---------------------------------------------------------------------------
// GEMM: C[M,N] = A @ Bt^T, 128x128x64 tile, 32x32x16 MFMA (2x2 frags/wave).
// LDS [128][64] bf16 (128B rows) with slot^=(row&7) XOR swizzle (T2, rule #21:
// pre-swizzled GLOBAL source + linear LDS dest + swizzled read).
// XCD-bijective block swizzle. limb3: A/B phys [hi|lo], logical kcat remapped.
// epi: 0 = bf16 store; 4 = f32 store at Cf + z*zCstride; 5 = f32 + bias store.
__global__ __launch_bounds__(256) void gemm_bt(
    const bf16* __restrict__ A, const bf16* __restrict__ Bt,
    float* __restrict__ Cf, bf16* __restrict__ Cb, const float* __restrict__ bias,
    int M, int N, int K, int ldA, int ldB, int ldC, long zCstride, int limb3, int epi)
{
    __shared__ __align__(16) bf16 As[128 * 64];
    __shared__ __align__(16) bf16 Bs[128 * 64];
    const int tid = threadIdx.x;
    const int lane = tid & 63, wid = tid >> 6;
    const int l32 = lane & 31, lh2 = lane >> 5;
    const int wr = wid >> 1, wc = wid & 1;
    // XCD-bijective swizzle over (x,y)
    int lid = blockIdx.y * gridDim.x + blockIdx.x;
    {
        const int nwg = gridDim.x * gridDim.y;
        const int q = nwg >> 3, r = nwg & 7;
        const int xcd = lid & 7, idx = lid >> 3;
        lid = (xcd < r ? xcd * (q + 1) : r * (q + 1) + (xcd - r) * q) + idx;
    }
    const int m0 = (lid % gridDim.x) * 128, n0 = (lid / gridDim.x) * 128;
    const int koff = blockIdx.z * K;

    // staging map: chunk c = tid + 256*i -> LDS row c>>3, slot c&7 holds
    // GLOBAL (row, (c&7)^(row&7))  [inverse-swizzled source]
    int srow[4], sslot[4];
    #pragma unroll
    for (int i = 0; i < 4; i++) {
        const int c = tid + 256*i;
        srow[i]  = c >> 3;
        sslot[i] = (((c & 7) ^ (srow[i] & 7)) << 3);   // element offset
    }

    f32x16 acc[2][2];
    #pragma unroll
    for (int m = 0; m < 2; m++)
        #pragma unroll
        for (int n = 0; n < 2; n++)
            #pragma unroll
            for (int j = 0; j < 16; j++) acc[m][n][j] = 0.f;

    for (int k0 = 0; k0 < K; k0 += 64) {
        const int kcat = koff + k0;
        int ka = kcat, kb = kcat;
        if (limb3) {
            ka = (kcat >= 4096) ? kcat - 4096 : kcat;
            kb = (kcat >= 2048) ? kcat - 2048 : kcat;
        }
        __syncthreads();
        #pragma unroll
        for (int i = 0; i < 4; i++) {
            load_lds16(A  + (size_t)(m0 + srow[i]) * ldA + ka + sslot[i], As + (tid + 256*i) * 8);
            load_lds16(Bt + (size_t)(n0 + srow[i]) * ldB + kb + sslot[i], Bs + (tid + 256*i) * 8);
        }
        __syncthreads();
        bf16x8 a[2][4], b[2][4];
        #pragma unroll
        for (int m = 0; m < 2; m++) {
            const int r = wr*64 + m*32 + l32, rx = r & 7;
            #pragma unroll
            for (int kk = 0; kk < 4; kk++)
                a[m][kk] = *(const bf16x8*)&As[r*64 + ((((kk<<1)|lh2) ^ rx) << 3)];
        }
        #pragma unroll
        for (int n = 0; n < 2; n++) {
            const int r = wc*64 + n*32 + l32, rx = r & 7;
            #pragma unroll
            for (int kk = 0; kk < 4; kk++)
                b[n][kk] = *(const bf16x8*)&Bs[r*64 + ((((kk<<1)|lh2) ^ rx) << 3)];
        }
        #pragma unroll
        for (int kk = 0; kk < 4; kk++)
            #pragma unroll
            for (int m = 0; m < 2; m++)
                #pragma unroll
                for (int n = 0; n < 2; n++)
                    acc[m][n] = __builtin_amdgcn_mfma_f32_32x32x16_bf16(a[m][kk], b[n][kk], acc[m][n], 0, 0, 0);
    }

    float* Cz = Cf + (size_t)blockIdx.z * zCstride;
    #pragma unroll
    for (int m = 0; m < 2; m++) {
        const int base_m = m0 + wr*64 + m*32 + 4*lh2;
        #pragma unroll
        for (int n = 0; n < 2; n++) {
            const int gcol = n0 + wc*64 + n*32 + l32;
            #pragma unroll
            for (int reg = 0; reg < 16; reg++) {
                const int grow = base_m + (reg & 3) + 8*(reg >> 2);
                const size_t o = (size_t)grow * ldC + gcol;
                const float v = acc[m][n][reg];
                if (epi == 0)      Cb[o] = f2b(v);
                else if (epi == 4) Cz[o] = v;
                else               Cf[o] = v + bias[gcol];
            }
        }
    }
}

// ---------------------------------------------------------------------------
__global__ __launch_bounds__(256) void gemm_gu(
    const bf16* __restrict__ A, const bf16* __restrict__ BtAll,
    const int* __restrict__ offc, const int* __restrict__ perm,
    bf16* __restrict__ C)
{
    const int e = blockIdx.z;
    const int off = offc[8 + e];
    const int padCnt = offc[9 + e] - off;
    const int m0 = blockIdx.x * 128;
    if (m0 >= padCnt) return;
    __shared__ __align__(16) bf16 As[128 * 64];
    __shared__ __align__(16) bf16 Bs[128 * 64];
    const int tid = threadIdx.x;
    const int lane = tid & 63, wid = tid >> 6;
    const int l32 = lane & 31, lh2 = lane >> 5;
    const int wr = wid >> 1, wc = wid & 1;
    const int n0 = blockIdx.y * 128;
    const bf16* Bt = BtAll + (size_t)e * 2816 * 2048;

    int srow[4], sslot[4], tok[4];
    #pragma unroll
    for (int i = 0; i < 4; i++) {
        const int c = tid + 256*i;
        srow[i]  = c >> 3;
        sslot[i] = (((c & 7) ^ (srow[i] & 7)) << 3);
        int t = perm[off + m0 + srow[i]];
        tok[i] = (t < 0) ? 0 : t;
    }

    f32x16 acc[2][2];
    #pragma unroll
    for (int m = 0; m < 2; m++)
        #pragma unroll
        for (int n = 0; n < 2; n++)
            #pragma unroll
            for (int j = 0; j < 16; j++) acc[m][n][j] = 0.f;

    for (int k0 = 0; k0 < 2048; k0 += 64) {
        __syncthreads();
        #pragma unroll
        for (int i = 0; i < 4; i++) {
            load_lds16(A  + (size_t)tok[i] * 2048 + k0 + sslot[i], As + (tid + 256*i) * 8);
            load_lds16(Bt + (size_t)(n0 + srow[i]) * 2048 + k0 + sslot[i], Bs + (tid + 256*i) * 8);
        }
        __syncthreads();
        bf16x8 a[2][4], b[2][4];
        #pragma unroll
        for (int m = 0; m < 2; m++) {
            const int r = wr*64 + m*32 + l32, rx = r & 7;
            #pragma unroll
            for (int kk = 0; kk < 4; kk++)
                a[m][kk] = *(const bf16x8*)&As[r*64 + ((((kk<<1)|lh2) ^ rx) << 3)];
        }
        #pragma unroll
        for (int n = 0; n < 2; n++) {
            const int r = wc*64 + n*32 + l32, rx = r & 7;
            #pragma unroll
            for (int kk = 0; kk < 4; kk++)
                b[n][kk] = *(const bf16x8*)&Bs[r*64 + ((((kk<<1)|lh2) ^ rx) << 3)];
        }
        #pragma unroll
        for (int kk = 0; kk < 4; kk++)
            #pragma unroll
            for (int m = 0; m < 2; m++)
                #pragma unroll
                for (int n = 0; n < 2; n++)
                    acc[m][n] = __builtin_amdgcn_mfma_f32_32x32x16_bf16(a[m][kk], b[n][kk], acc[m][n], 0, 0, 0);
    }

    #pragma unroll
    for (int m = 0; m < 2; m++) {
        const int base_m = m0 + wr*64 + m*32 + 4*lh2;
        #pragma unroll
        for (int n = 0; n < 2; n++) {
            const int gcol = n0 + wc*64 + n*32 + l32;
            #pragma unroll
            for (int reg = 0; reg < 16; reg++) {
                const int grow = base_m + (reg & 3) + 8*(reg >> 2);
                C[(size_t)(off + grow) * 2816 + gcol] = f2b(acc[m][n][reg]);
            }
        }
    }
}

__global__ __launch_bounds__(256) void gemm_down(
    const bf16* __restrict__ A, const bf16* __restrict__ BtAll,
    const int* __restrict__ offc, bf16* __restrict__ Y)
{
    const int e = blockIdx.z;
    const int off = offc[8 + e];
    const int padCnt = offc[9 + e] - off;
    const int m0 = blockIdx.x * 128;
    if (m0 >= padCnt) return;
    __shared__ __align__(16) bf16 As[128 * 64];
    __shared__ __align__(16) bf16 Bs[128 * 64];
    const int tid = threadIdx.x;
    const int lane = tid & 63, wid = tid >> 6;
    const int l32 = lane & 31, lh2 = lane >> 5;
    const int wr = wid >> 1, wc = wid & 1;
    const int n0 = blockIdx.y * 128;
    const bf16* Bt = BtAll + (size_t)e * 2048 * 1408;

    int srow[4], sslot[4];
    #pragma unroll
    for (int i = 0; i < 4; i++) {
        const int c = tid + 256*i;
        srow[i]  = c >> 3;
        sslot[i] = (((c & 7) ^ (srow[i] & 7)) << 3);
    }

    f32x16 acc[2][2];
    #pragma unroll
    for (int m = 0; m < 2; m++)
        #pragma unroll
        for (int n = 0; n < 2; n++)
            #pragma unroll
            for (int j = 0; j < 16; j++) acc[m][n][j] = 0.f;

    for (int k0 = 0; k0 < 1408; k0 += 64) {
        __syncthreads();
        #pragma unroll
        for (int i = 0; i < 4; i++) {
            load_lds16(A  + (size_t)(off + m0 + srow[i]) * 1408 + k0 + sslot[i], As + (tid + 256*i) * 8);
            load_lds16(Bt + (size_t)(n0 + srow[i]) * 1408 + k0 + sslot[i], Bs + (tid + 256*i) * 8);
        }
        __syncthreads();
        bf16x8 a[2][4], b[2][4];
        #pragma unroll
        for (int m = 0; m < 2; m++) {
            const int r = wr*64 + m*32 + l32, rx = r & 7;
            #pragma unroll
            for (int kk = 0; kk < 4; kk++)
                a[m][kk] = *(const bf16x8*)&As[r*64 + ((((kk<<1)|lh2) ^ rx) << 3)];
        }
        #pragma unroll
        for (int n = 0; n < 2; n++) {
            const int r = wc*64 + n*32 + l32, rx = r & 7;
            #pragma unroll
            for (int kk = 0; kk < 4; kk++)
                b[n][kk] = *(const bf16x8*)&Bs[r*64 + ((((kk<<1)|lh2) ^ rx) << 3)];
        }
        #pragma unroll
        for (int kk = 0; kk < 4; kk++)
            #pragma unroll
            for (int m = 0; m < 2; m++)
                #pragma unroll
                for (int n = 0; n < 2; n++)
                    acc[m][n] = __builtin_amdgcn_mfma_f32_32x32x16_bf16(a[m][kk], b[n][kk], acc[m][n], 0, 0, 0);
    }

    #pragma unroll
    for (int m = 0; m < 2; m++) {
        const int base_m = m0 + wr*64 + m*32 + 4*lh2;
        #pragma unroll
        for (int n = 0; n < 2; n++) {
            const int gcol = n0 + wc*64 + n*32 + l32;
            #pragma unroll
            for (int reg = 0; reg < 16; reg++) {
                const int grow = base_m + (reg & 3) + 8*(reg >> 2);
                Y[(size_t)(off + grow) * 2048 + gcol] = f2b(acc[m][n][reg]);
            }
        }
    }
}

// ---------------------------------------------------------------------------
__global__ void rope_table_k(float2* __restrict__ cs)
{
    const int i = blockIdx.x * 256 + threadIdx.x;   // < 65536
    const int s = i >> 6, d = i & 63;
    const float fr = (float)s * powf(1.0e6f, -(float)d * (1.0f / 64.0f));
    float c, sn;
    sincosf(fr, &sn, &c);
    cs[i] = make_float2(c, sn);
}

__global__ void rope_f32_k(float* __restrict__ qkv, const float2* __restrict__ cs)
{
    const int idx = blockIdx.x * 256 + threadIdx.x;
    const int d  = idx & 63;
    const int hh = (idx >> 6) & 15;
    const size_t base = (size_t)(idx >> 10) * 6144 + hh * HD;
    const int s = (idx >> 10) & 1023;
    const float2 t = cs[(s << 6) | d];
    const float c = t.x, sn = t.y;
    float q0 = qkv[base + d], q1 = qkv[base + d + 64];
    qkv[base + d]      = q0 * c - q1 * sn;
    qkv[base + d + 64] = q1 * c + q0 * sn;
    float k0 = qkv[base + 2048 + d], k1 = qkv[base + 2048 + d + 64];
    qkv[base + 2048 + d]      = k0 * c - k1 * sn;
    qkv[base + 2048 + d + 64] = k1 * c + k0 * sn;
}

// ---------------------------------------------------------------------------
__global__ __launch_bounds__(256) void transpose_v3_k(
    const float* __restrict__ qkv, bf16* __restrict__ vth, bf16* __restrict__ vtl)
{
    __shared__ float t[32][33];
    const int s0 = blockIdx.x * 32, d0 = blockIdx.y * 32;
    const int bh = blockIdx.z, b = bh >> 4, h = bh & 15;
    const int tx = threadIdx.x & 31, ty = threadIdx.x >> 5;
    const float* vb = qkv + ((size_t)b * SEQ) * 6144 + 4096 + h * HD;
    #pragma unroll
    for (int i = 0; i < 4; i++)
        t[ty + i*8][tx] = vb[(size_t)(s0 + ty + i*8) * 6144 + d0 + tx];
    __syncthreads();
    const size_t ob = ((size_t)bh * HD) * SEQ;
    #pragma unroll
    for (int i = 0; i < 4; i++) {
        float val = t[tx][ty + i*8];
        short hi, lo; split2(val, hi, lo);
        const size_t o = ob + (size_t)(d0 + ty + i*8) * SEQ + s0 + tx;
        vth[o] = __builtin_bit_cast(bf16, hi);
        vtl[o] = __builtin_bit_cast(bf16, lo);
    }
}

// ---------------------------------------------------------------------------
__global__ __launch_bounds__(256) void attn3_k(
    const float* __restrict__ qkv,
    const bf16* __restrict__ vth, const bf16* __restrict__ vtl,
    bf16* __restrict__ ctx2)
{
    __shared__ __align__(16) bf16 Ksh[32 * 128], Ksl[32 * 128];
    __shared__ __align__(16) bf16 Vth[128 * 32], Vtl[128 * 32];
    __shared__ __align__(16) bf16 Ph[4][16 * 32], Pl[4][16 * 32];
    const int tid = threadIdx.x, lane = tid & 63, wid = tid >> 6;
    const int l16 = lane & 15, lh = lane >> 4;
    const int bh = blockIdx.y, b = bh >> 4, h = bh & 15;
    const int qbase = blockIdx.x * 64;
    const int qw = qbase + wid * 16;
    const float* qp = qkv + ((size_t)b * SEQ) * 6144 + h * HD;
    const float* kp = qkv + ((size_t)b * SEQ) * 6144 + 2048 + h * HD;
    const bf16* vph = vth + ((size_t)bh * HD) * SEQ;
    const bf16* vpl = vtl + ((size_t)bh * HD) * SEQ;

    bf16x8 aqh[4], aql[4];
    #pragma unroll
    for (int c = 0; c < 4; c++) {
        const float* qrow = qp + (size_t)(qw + l16) * 6144 + c*32 + lh*8;
        #pragma unroll
        for (int u = 0; u < 8; u++) {
            short hi, lo; split2(qrow[u], hi, lo);
            aqh[c][u] = hi; aql[c][u] = lo;
        }
    }

    f32x4 o[8];
    #pragma unroll
    for (int n = 0; n < 8; n++) o[n] = (f32x4){0.f, 0.f, 0.f, 0.f};
    float mj[4], lj[4];
    #pragma unroll
    for (int j = 0; j < 4; j++) { mj[j] = -1e30f; lj[j] = 0.f; }

    const int f = tid * 8;
    const int kr = tid >> 3, kc = (tid & 7) * 16;
    const int kt_end = qbase / 32 + 2;
    for (int kt = 0; kt < kt_end; ++kt) {
        const int kv0 = kt * 32;
        __syncthreads();
        {
            const float* krow = kp + (size_t)(kv0 + kr) * 6144 + kc;
            #pragma unroll
            for (int u = 0; u < 4; u++) {
                float4 kv4 = *(const float4*)(krow + u*4);
                short h0, l0, h1, l1, h2s, l2s, h3, l3;
                split2(kv4.x, h0, l0); split2(kv4.y, h1, l1);
                split2(kv4.z, h2s, l2s); split2(kv4.w, h3, l3);
                bf16x4 h4, l4;
                h4[0] = h0; h4[1] = h1; h4[2] = h2s; h4[3] = h3;
                l4[0] = l0; l4[1] = l1; l4[2] = l2s; l4[3] = l3;
                *(bf16x4*)&Ksh[kr*128 + kc + u*4] = h4;
                *(bf16x4*)&Ksl[kr*128 + kc + u*4] = l4;
            }
        }
        load_lds16(vph + (size_t)(f >> 5) * SEQ + kv0 + (f & 31), Vth + f);
        load_lds16(vph + (size_t)((f >> 5) + 64) * SEQ + kv0 + (f & 31), Vth + f + 2048);
        load_lds16(vpl + (size_t)(f >> 5) * SEQ + kv0 + (f & 31), Vtl + f);
        load_lds16(vpl + (size_t)((f >> 5) + 64) * SEQ + kv0 + (f & 31), Vtl + f + 2048);
        __syncthreads();

        f32x4 s0a = (f32x4){0.f,0.f,0.f,0.f}, s1a = (f32x4){0.f,0.f,0.f,0.f};
        #pragma unroll
        for (int c = 0; c < 4; c++) {
            bf16x8 bk0h = *(const bf16x8*)&Ksh[(l16) * 128 + c*32 + lh*8];
            bf16x8 bk0l = *(const bf16x8*)&Ksl[(l16) * 128 + c*32 + lh*8];
            bf16x8 bk1h = *(const bf16x8*)&Ksh[(l16 + 16) * 128 + c*32 + lh*8];
            bf16x8 bk1l = *(const bf16x8*)&Ksl[(l16 + 16) * 128 + c*32 + lh*8];
            s0a = __builtin_amdgcn_mfma_f32_16x16x32_bf16(aqh[c], bk0h, s0a, 0, 0, 0);
            s0a = __builtin_amdgcn_mfma_f32_16x16x32_bf16(aql[c], bk0h, s0a, 0, 0, 0);
            s0a = __builtin_amdgcn_mfma_f32_16x16x32_bf16(aqh[c], bk0l, s0a, 0, 0, 0);
            s1a = __builtin_amdgcn_mfma_f32_16x16x32_bf16(aqh[c], bk1h, s1a, 0, 0, 0);
            s1a = __builtin_amdgcn_mfma_f32_16x16x32_bf16(aql[c], bk1h, s1a, 0, 0, 0);
            s1a = __builtin_amdgcn_mfma_f32_16x16x32_bf16(aqh[c], bk1l, s1a, 0, 0, 0);
        }
        const float scale = 0.08838834764831845f;
        #pragma unroll
        for (int j = 0; j < 4; j++) {
            const int qrow = qw + lh*4 + j;
            float s0 = s0a[j] * scale, s1 = s1a[j] * scale;
            if (kv0 + l16 > qrow)      s0 = -1e30f;
            if (kv0 + l16 + 16 > qrow) s1 = -1e30f;
            float mx = fmaxf(s0, s1);
            #pragma unroll
            for (int off = 1; off < 16; off <<= 1) mx = fmaxf(mx, __shfl_xor(mx, off, 16));
            const float nm = fmaxf(mj[j], mx);
            const float al = __expf(mj[j] - nm);
            const float p0 = __expf(s0 - nm), p1 = __expf(s1 - nm);
            float rs = p0 + p1;
            #pragma unroll
            for (int off = 1; off < 16; off <<= 1) rs += __shfl_xor(rs, off, 16);
            lj[j] = lj[j] * al + rs;
            mj[j] = nm;
            #pragma unroll
            for (int n = 0; n < 8; n++) o[n][j] *= al;
            short h0, l0, h1, l1;
            split2(p0, h0, l0); split2(p1, h1, l1);
            Ph[wid][(lh*4 + j) * 32 + l16]      = __builtin_bit_cast(bf16, h0);
            Pl[wid][(lh*4 + j) * 32 + l16]      = __builtin_bit_cast(bf16, l0);
            Ph[wid][(lh*4 + j) * 32 + l16 + 16] = __builtin_bit_cast(bf16, h1);
            Pl[wid][(lh*4 + j) * 32 + l16 + 16] = __builtin_bit_cast(bf16, l1);
        }
        __syncthreads();
        const bf16x8 aph = *(const bf16x8*)&Ph[wid][l16 * 32 + lh*8];
        const bf16x8 apl = *(const bf16x8*)&Pl[wid][l16 * 32 + lh*8];
        #pragma unroll
        for (int n = 0; n < 8; n++) {
            bf16x8 bvh = *(const bf16x8*)&Vth[(n*16 + l16) * 32 + lh*8];
            bf16x8 bvl = *(const bf16x8*)&Vtl[(n*16 + l16) * 32 + lh*8];
            o[n] = __builtin_amdgcn_mfma_f32_16x16x32_bf16(aph, bvh, o[n], 0, 0, 0);
            o[n] = __builtin_amdgcn_mfma_f32_16x16x32_bf16(apl, bvh, o[n], 0, 0, 0);
            o[n] = __builtin_amdgcn_mfma_f32_16x16x32_bf16(aph, bvl, o[n], 0, 0, 0);
        }
    }

    float inv[4];
    #pragma unroll
    for (int j = 0; j < 4; j++) inv[j] = 1.0f / lj[j];
    #pragma unroll
    for (int n = 0; n < 8; n++)
        #pragma unroll
        for (int j = 0; j < 4; j++) {
            const float v = o[n][j] * inv[j];
            short hi, lo; split2(v, hi, lo);
            const size_t base = ((size_t)b * SEQ + (qw + lh*4 + j)) * 4096 + h * HD + n*16 + l16;
            ctx2[base]        = __builtin_bit_cast(bf16, hi);
            ctx2[base + 2048] = __builtin_bit_cast(bf16, lo);
        }
}

// ---------------------------------------------------------------------------
__global__ __launch_bounds__(256) void combine_rms_k(
    const float* __restrict__ x, const float* __restrict__ xp,
    const float* __restrict__ w, float* __restrict__ x1, bf16* __restrict__ h2)
{
    const int row = blockIdx.x, tid = threadIdx.x;
    const size_t rb = (size_t)row * HIDDEN;
    const long zs = (long)TOKENS * HIDDEN;
    float4 v[2];
    #pragma unroll
    for (int u = 0; u < 2; u++) {
        const int i = tid + u * 256;
        float4 a  = ((const float4*)(x + rb))[i];
        float4 p0 = ((const float4*)(xp + rb))[i];
        float4 p1 = ((const float4*)(xp + zs + rb))[i];
        float4 p2 = ((const float4*)(xp + 2*zs + rb))[i];
        v[u].x = a.x + p0.x + p1.x + p2.x;
        v[u].y = a.y + p0.y + p1.y + p2.y;
        v[u].z = a.z + p0.z + p1.z + p2.z;
        v[u].w = a.w + p0.w + p1.w + p2.w;
        ((float4*)(x1 + rb))[i] = v[u];
    }
    float ss = v[0].x*v[0].x + v[0].y*v[0].y + v[0].z*v[0].z + v[0].w*v[0].w
             + v[1].x*v[1].x + v[1].y*v[1].y + v[1].z*v[1].z + v[1].w*v[1].w;
    #pragma unroll
    for (int off = 1; off < 64; off <<= 1) ss += __shfl_xor(ss, off);
    __shared__ float ps[4];
    if ((tid & 63) == 0) ps[tid >> 6] = ss;
    __syncthreads();
    float tot = ps[0] + ps[1] + ps[2] + ps[3];
    float r = rsqrtf(tot * (1.0f / HIDDEN) + 1e-6f);
    #pragma unroll
    for (int u = 0; u < 2; u++) {
        const int i = (tid + u * 256) * 4;
        h2[rb + i]     = f2b(v[u].x * r * w[i]);
        h2[rb + i + 1] = f2b(v[u].y * r * w[i+1]);
        h2[rb + i + 2] = f2b(v[u].z * r * w[i+2]);
        h2[rb + i + 3] = f2b(v[u].w * r * w[i+3]);
    }
}

// ---------------------------------------------------------------------------
__global__ __launch_bounds__(256) void router_k(
    const float* __restrict__ x1, const float* __restrict__ wln,
    const float* __restrict__ wr, const float* __restrict__ weg,
    float* __restrict__ combine, float* __restrict__ sigeg)
{
    const int wid = threadIdx.x >> 6, lane = threadIdx.x & 63;
    const int t = blockIdx.x * 4 + wid;
    const float* xr = x1 + (size_t)t * HIDDEN;
    float ss = 0.f;
    for (int c = lane; c < HIDDEN; c += 64) { const float v = xr[c]; ss += v * v; }
    #pragma unroll
    for (int off = 1; off < 64; off <<= 1) ss += __shfl_xor(ss, off);
    const float r = rsqrtf(ss * (1.0f / HIDDEN) + 1e-6f);

    float acc[9];
    #pragma unroll
    for (int e = 0; e < 9; e++) acc[e] = 0.f;
    for (int c = lane; c < HIDDEN; c += 64) {
        const float hv = xr[c] * r * wln[c];
        const float* wrow = wr + (size_t)c * 8;
        #pragma unroll
        for (int e = 0; e < 8; e++) acc[e] += hv * wrow[e];
        acc[8] += hv * weg[c];
    }
    #pragma unroll
    for (int e = 0; e < 9; e++)
        #pragma unroll
        for (int off = 1; off < 64; off <<= 1) acc[e] += __shfl_xor(acc[e], off);
    float mx = acc[0];
    #pragma unroll
    for (int e = 1; e < 8; e++) mx = fmaxf(mx, acc[e]);
    float p[8], s = 0.f;
    #pragma unroll
    for (int e = 0; e < 8; e++) { p[e] = expf(acc[e] - mx); s += p[e]; }
    const float invs = 1.0f / s;
    #pragma unroll
    for (int e = 0; e < 8; e++) p[e] *= invs;
    int i1 = 0;
    #pragma unroll
    for (int e = 1; e < 8; e++) if (p[e] > p[i1]) i1 = e;
    int i2 = (i1 == 0) ? 1 : 0;
    #pragma unroll
    for (int e = 0; e < 8; e++) if (e != i1 && p[e] > p[i2]) i2 = e;
    if (lane < 8) combine[(size_t)t * 8 + lane] = (lane == i1 || lane == i2) ? p[lane] : 0.f;
    if (lane == 0) sigeg[t] = 1.0f / (1.0f + expf(-acc[8]));
}

// ---------------------------------------------------------------------------
__global__ __launch_bounds__(256) void count_fill_k(
    const float* __restrict__ comb, int* __restrict__ offc, int* __restrict__ perm,
    float* __restrict__ scale, int* __restrict__ inv)
{
    __shared__ int cnt[8], off[9], fil[8];
    const int tid = threadIdx.x;
    if (tid < 8) { cnt[tid] = 0; fil[tid] = 0; }
    __syncthreads();
    for (int t = tid; t < TOKENS; t += 256)
        #pragma unroll
        for (int e = 0; e < 8; e++)
            if (comb[(size_t)t * 8 + e] > 0.f) atomicAdd(&cnt[e], 1);
    __syncthreads();
    if (tid == 0) {
        off[0] = 0;
        for (int e = 0; e < 8; e++) off[e+1] = off[e] + ((cnt[e] + 127) & ~127);
    }
    __syncthreads();
    for (int i = tid; i < MAXROWS; i += 256) { perm[i] = -1; scale[i] = 0.f; }
    __syncthreads();
    for (int t = tid; t < TOKENS; t += 256) {
        int j = 0;
        #pragma unroll
        for (int e = 0; e < 8; e++) {
            const float c = comb[(size_t)t * 8 + e];
            if (c > 0.f) {
                int s = atomicAdd(&fil[e], 1);
                int slot = off[e] + s;
                perm[slot] = t;
                scale[slot] = c;
                inv[t * 2 + j] = slot;
                j++;
            }
        }
    }
    __syncthreads();
    if (tid < 9) offc[8 + tid] = off[tid];
}

// ---------------------------------------------------------------------------
__global__ void silu_k(const bf16* __restrict__ g, bf16* __restrict__ a,
                       const float* __restrict__ rowScale,
                       int I, int ldg, int rowsConst, const int* __restrict__ rowsPtr)
{
    const int idx = (blockIdx.x * 256 + threadIdx.x) * 4;
    const int rows = rowsPtr ? *rowsPtr : rowsConst;
    const int row = idx / I;
    if (row >= rows) return;
    const int col = idx - row * I;
    const float s = rowScale[row];
    const bf16* gr = g + (size_t)row * ldg + col;
    bf16* ar = a + (size_t)row * I + col;
    #pragma unroll
    for (int c = 0; c < 4; c++) {
        const float gv = b2f(gr[c]), uv = b2f(gr[I + c]);
        ar[c] = f2b(s * gv / (1.0f + __expf(-gv)) * uv);
    }
}

// ---------------------------------------------------------------------------
__global__ void final_k(const float* __restrict__ x1, const bf16* __restrict__ y,
                        const int* __restrict__ inv, const float* __restrict__ ysh,
                        float* __restrict__ out)
{
    const int i = blockIdx.x * 256 + threadIdx.x;   // float4 index
    const int t = i >> 9;
    const int col = (i & 511) * 4;
    const int s0 = inv[t*2], s1 = inv[t*2 + 1];
    const long zs = (long)TOKENS * HIDDEN;
    float4 a  = ((const float4*)x1)[i];
    float4 h0 = ((const float4*)ysh)[i];
    float4 h1 = ((const float4*)(ysh + zs))[i];
    const bf16* y0 = y + (size_t)s0 * 2048 + col;
    const bf16* y1 = y + (size_t)s1 * 2048 + col;
    float4 r;
    r.x = a.x + h0.x + h1.x + b2f(y0[0]) + b2f(y1[0]);
    r.y = a.y + h0.y + h1.y + b2f(y0[1]) + b2f(y1[1]);
    r.z = a.z + h0.z + h1.z + b2f(y0[2]) + b2f(y1[2]);
    r.w = a.w + h0.w + h1.w + b2f(y0[3]) + b2f(y1[3]);
    ((float4*)out)[i] = r;
}

// ---------------------------------------------------------------------------
extern "C" void kernel_launch(void* const* d_in, const int* in_sizes, int n_in,
                              void* d_out, int out_size, void* d_ws, size_t ws_size,
                              hipStream_t stream)
{
    const float* x     = (const float*)d_in[0];
    const float* w_ln1 = (const float*)d_in[1];
    const float* wq    = (const float*)d_in[2];
    const float* bq    = (const float*)d_in[3];
    const float* wk    = (const float*)d_in[4];
    const float* bk    = (const float*)d_in[5];
    const float* wv    = (const float*)d_in[6];
    const float* bv    = (const float*)d_in[7];
    const float* wo    = (const float*)d_in[8];
    const float* w_ln2 = (const float*)d_in[9];
    const float* w_rt  = (const float*)d_in[10];
    const float* w_ge  = (const float*)d_in[11];
    const float* w_ue  = (const float*)d_in[12];
    const float* w_de  = (const float*)d_in[13];
    const float* w_sg  = (const float*)d_in[14];
    const float* w_su  = (const float*)d_in[15];
    const float* w_sd  = (const float*)d_in[16];
    const float* w_eg  = (const float*)d_in[17];
    float* out = (float*)d_out;
    (void)in_sizes; (void)n_in; (void)out_size; (void)ws_size;

    char* ws = (char*)d_ws;
    // persistent
    float* x1    = (float*)(ws + 0);
    bf16*  h2    = (bf16*)(ws + 16777216);
    float* comb  = (float*)(ws + 25165824);
    float* seg   = (float*)(ws + 25231360);
    int*   offc  = (int*)(ws + 25239552);
    float* scale = (float*)(ws + 25243648);
    int*   perm  = (int*)(ws + 25276416);
    int*   inv   = (int*)(ws + 25297920);
    float* bqkv  = (float*)(ws + 25314304);
    float2* ropecs = (float2*)(ws + 25338880);          // 512KB -> ends 25863168
    const size_t S = 25863168;
    // phase A
    bf16*  hcat  = (bf16*)(ws + S);
    bf16*  wtqkv = (bf16*)(ws + S + 16777216);
    float* qkvf  = (float*)(ws + S + 67108864);          // ends S+117440512
    bf16*  vth   = (bf16*)(ws + S);
    bf16*  vtl   = (bf16*)(ws + S + 8388608);
    bf16*  ctx2  = (bf16*)(ws + S + 16777216);
    bf16*  wt3o  = (bf16*)(ws + S + 33554432);
    float* xp    = (float*)(ws + S + 50331648);          // 3x16.78M
    // phase B
    bf16*  wtgu  = (bf16*)(ws + S);
    bf16*  gb    = (bf16*)(ws + S + 92274688);
    bf16*  ab    = (bf16*)(ws + S);
    bf16*  wtd   = (bf16*)(ws + S + 14417920);
    bf16*  ymoe  = (bf16*)(ws + S + 60555264);
    // phase C
    bf16*  wtshgu = (bf16*)(ws + S);
    bf16*  gsh    = (bf16*)(ws + S + 81526784);
    bf16*  ash    = (bf16*)(ws + S);
    bf16*  wtshd  = (bf16*)(ws + S + 23068672);
    float* ysh    = (float*)(ws + S + 81526784);

    // 1) RMSNorm1 -> hcat; QKV bias concat; rope table
    rmsnorm3_k<<<TOKENS, 256, 0, stream>>>(x, w_ln1, hcat);
    (void)hipMemcpyAsync(bqkv,        bq, 8192, hipMemcpyDeviceToDevice, stream);
    (void)hipMemcpyAsync(bqkv + 2048, bk, 8192, hipMemcpyDeviceToDevice, stream);
    (void)hipMemcpyAsync(bqkv + 4096, bv, 8192, hipMemcpyDeviceToDevice, stream);
    rope_table_k<<<256, 256, 0, stream>>>(ropecs);

    // 2) Fused QKV (limb3, N=6144, plain stores)
    transpose_w3<<<dim3(64, 64), 256, 0, stream>>>(wq, wtqkv, HIDDEN, HIDDEN, 0);
    transpose_w3<<<dim3(64, 64), 256, 0, stream>>>(wk, wtqkv, HIDDEN, HIDDEN, 2048);
    transpose_w3<<<dim3(64, 64), 256, 0, stream>>>(wv, wtqkv, HIDDEN, HIDDEN, 4096);
    gemm_bt<<<dim3(16, 48, 1), 256, 0, stream>>>(hcat, wtqkv, qkvf, nullptr, bqkv,
                                                 TOKENS, 6144, K3, 4096, 4096, 6144, 0, 1, 5);

    // 3) RoPE + V transpose/split + attention
    rope_f32_k<<<8192, 256, 0, stream>>>(qkvf, ropecs);
    transpose_v3_k<<<dim3(32, 4, 32), 256, 0, stream>>>(qkvf, vth, vtl);
    attn3_k<<<dim3(16, 32), 256, 0, stream>>>(qkvf, vth, vtl, ctx2);

    // 4) O-proj (limb3, split-K z=3, plain stores) + fused combine/rms
    transpose_w3<<<dim3(64, 64), 256, 0, stream>>>(wo, wt3o, HIDDEN, HIDDEN, 0);
    gemm_bt<<<dim3(16, 16, 3), 256, 0, stream>>>(ctx2, wt3o, xp, nullptr, nullptr,
                                                 TOKENS, HIDDEN, 2048, 4096, 4096, 2048,
                                                 (long)TOKENS * HIDDEN, 1, 4);
    combine_rms_k<<<TOKENS, 256, 0, stream>>>(x, xp, w_ln2, x1, h2);

    // 5) Router + expert lists
    router_k<<<TOKENS / 4, 256, 0, stream>>>(x1, w_ln2, w_rt, w_eg, comb, seg);
    count_fill_k<<<1, 256, 0, stream>>>(comb, offc, perm, scale, inv);

    // 6) Sparse MoE
    transpose_wz<<<dim3(44, 64, 8), 256, 0, stream>>>(w_ge, wtgu, HIDDEN, MOE_I, 0,
                                                      (long)HIDDEN*MOE_I, (long)2816*HIDDEN);
    transpose_wz<<<dim3(44, 64, 8), 256, 0, stream>>>(w_ue, wtgu, HIDDEN, MOE_I, MOE_I,
                                                      (long)HIDDEN*MOE_I, (long)2816*HIDDEN);
    gemm_gu<<<dim3(MAXROWS/128, 22, 8), 256, 0, stream>>>(h2, wtgu, offc, perm, gb);
    silu_k<<<(MAXROWS * MOE_I) / 1024, 256, 0, stream>>>(gb, ab, scale, MOE_I, 2816, 0, offc + 16);
    transpose_wz<<<dim3(64, 44, 8), 256, 0, stream>>>(w_de, wtd, MOE_I, HIDDEN, 0,
                                                      (long)MOE_I*HIDDEN, (long)HIDDEN*MOE_I);
    gemm_down<<<dim3(MAXROWS/128, 16, 8), 256, 0, stream>>>(ab, wtd, offc, ymoe);

    // 7) Shared expert
    transpose_wz<<<dim3(176, 64, 1), 256, 0, stream>>>(w_sg, wtshgu, HIDDEN, SH_I, 0, 0, 0);
    transpose_wz<<<dim3(176, 64, 1), 256, 0, stream>>>(w_su, wtshgu, HIDDEN, SH_I, SH_I, 0, 0);
    gemm_bt<<<dim3(16, 88, 1), 256, 0, stream>>>(h2, wtshgu, nullptr, gsh, nullptr,
                                                 TOKENS, 2*SH_I, HIDDEN, HIDDEN, HIDDEN, 2*SH_I, 0, 0, 0);
    silu_k<<<(TOKENS * SH_I) / 1024, 256, 0, stream>>>(gsh, ash, seg, SH_I, 2*SH_I, TOKENS, nullptr);
    transpose_wz<<<dim3(64, 176, 1), 256, 0, stream>>>(w_sd, wtshd, SH_I, HIDDEN, 0, 0, 0);
    gemm_bt<<<dim3(16, 16, 2), 256, 0, stream>>>(ash, wtshd, ysh, nullptr, nullptr,
                                                 TOKENS, HIDDEN, SH_I/2, SH_I, SH_I, 2048,
                                                 (long)TOKENS * HIDDEN, 0, 4);

    // 8) Final gather-sum
    final_k<<<(TOKENS * HIDDEN) / 1024, 256, 0, stream>>>(x1, ymoe, inv, ysh, out);
}

// Round 9
// 971.589 us; speedup vs baseline: 2.7205x; 1.0550x over previous
//
#include <hip/hip_runtime.h>
#include <hip/hip_bf16.h>
#include <math.h>

#define TOKENS 2048
#define HIDDEN 2048
#define NH 16
#define HD 128
#define SEQ 1024
#define MOE_I 1408
#define SH_I 5632
#define K3 6144
#define MAXROWS 5120

typedef __hip_bfloat16 bf16;
typedef short bf16x8 __attribute__((ext_vector_type(8)));
typedef short bf16x4 __attribute__((ext_vector_type(4)));
typedef float f32x4 __attribute__((ext_vector_type(4)));
typedef float f32x16 __attribute__((ext_vector_type(16)));

__device__ __forceinline__ float b2f(bf16 x) { return __bfloat162float(x); }
__device__ __forceinline__ bf16 f2b(float x) { return __float2bfloat16(x); }
__device__ __forceinline__ void split2(float v, short& hi, short& lo) {
    bf16 h = f2b(v);
    bf16 l = f2b(v - b2f(h));
    hi = __builtin_bit_cast(short, h); lo = __builtin_bit_cast(short, l);
}

__device__ __forceinline__ void load_lds16(const void* g, void* l) {
    __builtin_amdgcn_global_load_lds(
        (const __attribute__((address_space(1))) unsigned int*)g,
        (__attribute__((address_space(3))) unsigned int*)l, 16, 0, 0);
}

// ---------------------------------------------------------------------------
__global__ __launch_bounds__(256) void rmsnorm3_k(
    const float* __restrict__ x, const float* __restrict__ w, bf16* __restrict__ out)
{
    const int row = blockIdx.x, tid = threadIdx.x;
    const float4* xr = (const float4*)(x + (size_t)row * HIDDEN);
    float4 v1 = xr[tid], v2 = xr[tid + 256];
    float ss = v1.x*v1.x + v1.y*v1.y + v1.z*v1.z + v1.w*v1.w
             + v2.x*v2.x + v2.y*v2.y + v2.z*v2.z + v2.w*v2.w;
    #pragma unroll
    for (int off = 1; off < 64; off <<= 1) ss += __shfl_xor(ss, off);
    __shared__ float ps[4];
    if ((tid & 63) == 0) ps[tid >> 6] = ss;
    __syncthreads();
    float tot = ps[0] + ps[1] + ps[2] + ps[3];
    float r = rsqrtf(tot * (1.0f / HIDDEN) + 1e-6f);
    bf16* o = out + (size_t)row * 4096;
    float vv[8] = {v1.x, v1.y, v1.z, v1.w, v2.x, v2.y, v2.z, v2.w};
    int idx[8]  = {tid*4, tid*4+1, tid*4+2, tid*4+3,
                   1024+tid*4, 1024+tid*4+1, 1024+tid*4+2, 1024+tid*4+3};
    #pragma unroll
    for (int u = 0; u < 8; u++) {
        short hi, lo; split2(vv[u] * r * w[idx[u]], hi, lo);
        o[idx[u]]        = __builtin_bit_cast(bf16, hi);
        o[2048 + idx[u]] = __builtin_bit_cast(bf16, lo);
    }
}

// ---------------------------------------------------------------------------
// Generic plain transpose (used for w_de, w_sd)
__global__ __launch_bounds__(256) void transpose_wz(
    const float* __restrict__ W, bf16* __restrict__ Wt, int K, int N,
    int nOff, long zsrc, long zdst)
{
    __shared__ float t[32][33];
    W  += (size_t)blockIdx.z * zsrc;
    Wt += (size_t)blockIdx.z * zdst;
    const int n0 = blockIdx.x * 32, k0 = blockIdx.y * 32;
    const int tx = threadIdx.x & 31, ty = threadIdx.x >> 5;
    #pragma unroll
    for (int i = 0; i < 4; i++)
        t[ty + i*8][tx] = W[(size_t)(k0 + ty + i*8) * N + n0 + tx];
    __syncthreads();
    #pragma unroll
    for (int i = 0; i < 4; i++)
        Wt[(size_t)(nOff + n0 + ty + i*8) * K + k0 + tx] = f2b(t[tx][ty + i*8]);
}

// Fused QKVO split-transpose: z=0..2 -> wtqkv rows z*2048.., z=3 -> wt3o.
__global__ __launch_bounds__(256) void transpose_qkvo_k(
    const float* __restrict__ wq, const float* __restrict__ wk,
    const float* __restrict__ wv, const float* __restrict__ wo,
    bf16* __restrict__ wtqkv, bf16* __restrict__ wt3o)
{
    const int z = blockIdx.z;
    const float* W = (z == 0) ? wq : (z == 1) ? wk : (z == 2) ? wv : wo;
    bf16* Wt2 = (z < 3) ? wtqkv : wt3o;
    const int nOff = (z < 3) ? z * 2048 : 0;
    __shared__ float t[32][33];
    const int n0 = blockIdx.x * 32, k0 = blockIdx.y * 32;
    const int tx = threadIdx.x & 31, ty = threadIdx.x >> 5;
    #pragma unroll
    for (int i = 0; i < 4; i++)
        t[ty + i*8][tx] = W[(size_t)(k0 + ty + i*8) * 2048 + n0 + tx];
    __syncthreads();
    #pragma unroll
    for (int i = 0; i < 4; i++) {
        float v = t[tx][ty + i*8];
        short hi, lo; split2(v, hi, lo);
        bf16* o = Wt2 + (size_t)(nOff + n0 + ty + i*8) * 4096 + k0 + tx;
        o[0]    = __builtin_bit_cast(bf16, hi);
        o[2048] = __builtin_bit_cast(bf16, lo);
    }
}

// Fused MoE gate|up transpose: z<8 -> gate expert z, z>=8 -> up expert z-8.
__global__ __launch_bounds__(256) void transpose_moegu_k(
    const float* __restrict__ ge, const float* __restrict__ ue, bf16* __restrict__ wtgu)
{
    const int z = blockIdx.z, e = z & 7;
    const float* W = ((z < 8) ? ge : ue) + (size_t)e * HIDDEN * MOE_I;
    bf16* Wt = wtgu + (size_t)e * 2816 * HIDDEN;
    const int nOff = (z < 8) ? 0 : MOE_I;
    __shared__ float t[32][33];
    const int n0 = blockIdx.x * 32, k0 = blockIdx.y * 32;
    const int tx = threadIdx.x & 31, ty = threadIdx.x >> 5;
    #pragma unroll
    for (int i = 0; i < 4; i++)
        t[ty + i*8][tx] = W[(size_t)(k0 + ty + i*8) * MOE_I + n0 + tx];
    __syncthreads();
    #pragma unroll
    for (int i = 0; i < 4; i++)
        Wt[(size_t)(nOff + n0 + ty + i*8) * HIDDEN + k0 + tx] = f2b(t[tx][ty + i*8]);
}

// Fused shared gate|up transpose: z=0 gate, z=1 up.
__global__ __launch_bounds__(256) void transpose_shgu_k(
    const float* __restrict__ sg, const float* __restrict__ su, bf16* __restrict__ dst)
{
    const int z = blockIdx.z;
    const float* W = z ? su : sg;
    const int nOff = z * SH_I;
    __shared__ float t[32][33];
    const int n0 = blockIdx.x * 32, k0 = blockIdx.y * 32;
    const int tx = threadIdx.x & 31, ty = threadIdx.x >> 5;
    #pragma unroll
    for (int i = 0; i < 4; i++)
        t[ty + i*8][tx] = W[(size_t)(k0 + ty + i*8) * SH_I + n0 + tx];
    __syncthreads();
    #pragma unroll
    for (int i = 0; i < 4; i++)
        dst[(size_t)(nOff + n0 + ty + i*8) * HIDDEN + k0 + tx] = f2b(t[tx][ty + i*8]);
}

// ---------------------------------------------------------------------------
// GEMM (unchanged from R8): 128x128x64 tile, 32x32x16 MFMA, XOR-swizzled LDS.
__global__ __launch_bounds__(256) void gemm_bt(
    const bf16* __restrict__ A, const bf16* __restrict__ Bt,
    float* __restrict__ Cf, bf16* __restrict__ Cb, const float* __restrict__ bias,
    int M, int N, int K, int ldA, int ldB, int ldC, long zCstride, int limb3, int epi)
{
    __shared__ __align__(16) bf16 As[128 * 64];
    __shared__ __align__(16) bf16 Bs[128 * 64];
    const int tid = threadIdx.x;
    const int lane = tid & 63, wid = tid >> 6;
    const int l32 = lane & 31, lh2 = lane >> 5;
    const int wr = wid >> 1, wc = wid & 1;
    int lid = blockIdx.y * gridDim.x + blockIdx.x;
    {
        const int nwg = gridDim.x * gridDim.y;
        const int q = nwg >> 3, r = nwg & 7;
        const int xcd = lid & 7, idx = lid >> 3;
        lid = (xcd < r ? xcd * (q + 1) : r * (q + 1) + (xcd - r) * q) + idx;
    }
    const int m0 = (lid % gridDim.x) * 128, n0 = (lid / gridDim.x) * 128;
    const int koff = blockIdx.z * K;

    int srow[4], sslot[4];
    #pragma unroll
    for (int i = 0; i < 4; i++) {
        const int c = tid + 256*i;
        srow[i]  = c >> 3;
        sslot[i] = (((c & 7) ^ (srow[i] & 7)) << 3);
    }

    f32x16 acc[2][2];
    #pragma unroll
    for (int m = 0; m < 2; m++)
        #pragma unroll
        for (int n = 0; n < 2; n++)
            #pragma unroll
            for (int j = 0; j < 16; j++) acc[m][n][j] = 0.f;

    for (int k0 = 0; k0 < K; k0 += 64) {
        const int kcat = koff + k0;
        int ka = kcat, kb = kcat;
        if (limb3) {
            ka = (kcat >= 4096) ? kcat - 4096 : kcat;
            kb = (kcat >= 2048) ? kcat - 2048 : kcat;
        }
        __syncthreads();
        #pragma unroll
        for (int i = 0; i < 4; i++) {
            load_lds16(A  + (size_t)(m0 + srow[i]) * ldA + ka + sslot[i], As + (tid + 256*i) * 8);
            load_lds16(Bt + (size_t)(n0 + srow[i]) * ldB + kb + sslot[i], Bs + (tid + 256*i) * 8);
        }
        __syncthreads();
        bf16x8 a[2][4], b[2][4];
        #pragma unroll
        for (int m = 0; m < 2; m++) {
            const int r = wr*64 + m*32 + l32, rx = r & 7;
            #pragma unroll
            for (int kk = 0; kk < 4; kk++)
                a[m][kk] = *(const bf16x8*)&As[r*64 + ((((kk<<1)|lh2) ^ rx) << 3)];
        }
        #pragma unroll
        for (int n = 0; n < 2; n++) {
            const int r = wc*64 + n*32 + l32, rx = r & 7;
            #pragma unroll
            for (int kk = 0; kk < 4; kk++)
                b[n][kk] = *(const bf16x8*)&Bs[r*64 + ((((kk<<1)|lh2) ^ rx) << 3)];
        }
        #pragma unroll
        for (int kk = 0; kk < 4; kk++)
            #pragma unroll
            for (int m = 0; m < 2; m++)
                #pragma unroll
                for (int n = 0; n < 2; n++)
                    acc[m][n] = __builtin_amdgcn_mfma_f32_32x32x16_bf16(a[m][kk], b[n][kk], acc[m][n], 0, 0, 0);
    }

    float* Cz = Cf + (size_t)blockIdx.z * zCstride;
    #pragma unroll
    for (int m = 0; m < 2; m++) {
        const int base_m = m0 + wr*64 + m*32 + 4*lh2;
        #pragma unroll
        for (int n = 0; n < 2; n++) {
            const int gcol = n0 + wc*64 + n*32 + l32;
            #pragma unroll
            for (int reg = 0; reg < 16; reg++) {
                const int grow = base_m + (reg & 3) + 8*(reg >> 2);
                const size_t o = (size_t)grow * ldC + gcol;
                const float v = acc[m][n][reg];
                if (epi == 0)      Cb[o] = f2b(v);
                else if (epi == 4) Cz[o] = v;
                else               Cf[o] = v + bias[gcol];
            }
        }
    }
}

// ---------------------------------------------------------------------------
__global__ __launch_bounds__(256) void gemm_gu(
    const bf16* __restrict__ A, const bf16* __restrict__ BtAll,
    const int* __restrict__ offc, const int* __restrict__ perm,
    bf16* __restrict__ C)
{
    const int e = blockIdx.z;
    const int off = offc[8 + e];
    const int padCnt = offc[9 + e] - off;
    const int m0 = blockIdx.x * 128;
    if (m0 >= padCnt) return;
    __shared__ __align__(16) bf16 As[128 * 64];
    __shared__ __align__(16) bf16 Bs[128 * 64];
    const int tid = threadIdx.x;
    const int lane = tid & 63, wid = tid >> 6;
    const int l32 = lane & 31, lh2 = lane >> 5;
    const int wr = wid >> 1, wc = wid & 1;
    const int n0 = blockIdx.y * 128;
    const bf16* Bt = BtAll + (size_t)e * 2816 * 2048;

    int srow[4], sslot[4], tok[4];
    #pragma unroll
    for (int i = 0; i < 4; i++) {
        const int c = tid + 256*i;
        srow[i]  = c >> 3;
        sslot[i] = (((c & 7) ^ (srow[i] & 7)) << 3);
        int t = perm[off + m0 + srow[i]];
        tok[i] = (t < 0) ? 0 : t;
    }

    f32x16 acc[2][2];
    #pragma unroll
    for (int m = 0; m < 2; m++)
        #pragma unroll
        for (int n = 0; n < 2; n++)
            #pragma unroll
            for (int j = 0; j < 16; j++) acc[m][n][j] = 0.f;

    for (int k0 = 0; k0 < 2048; k0 += 64) {
        __syncthreads();
        #pragma unroll
        for (int i = 0; i < 4; i++) {
            load_lds16(A  + (size_t)tok[i] * 2048 + k0 + sslot[i], As + (tid + 256*i) * 8);
            load_lds16(Bt + (size_t)(n0 + srow[i]) * 2048 + k0 + sslot[i], Bs + (tid + 256*i) * 8);
        }
        __syncthreads();
        bf16x8 a[2][4], b[2][4];
        #pragma unroll
        for (int m = 0; m < 2; m++) {
            const int r = wr*64 + m*32 + l32, rx = r & 7;
            #pragma unroll
            for (int kk = 0; kk < 4; kk++)
                a[m][kk] = *(const bf16x8*)&As[r*64 + ((((kk<<1)|lh2) ^ rx) << 3)];
        }
        #pragma unroll
        for (int n = 0; n < 2; n++) {
            const int r = wc*64 + n*32 + l32, rx = r & 7;
            #pragma unroll
            for (int kk = 0; kk < 4; kk++)
                b[n][kk] = *(const bf16x8*)&Bs[r*64 + ((((kk<<1)|lh2) ^ rx) << 3)];
        }
        #pragma unroll
        for (int kk = 0; kk < 4; kk++)
            #pragma unroll
            for (int m = 0; m < 2; m++)
                #pragma unroll
                for (int n = 0; n < 2; n++)
                    acc[m][n] = __builtin_amdgcn_mfma_f32_32x32x16_bf16(a[m][kk], b[n][kk], acc[m][n], 0, 0, 0);
    }

    #pragma unroll
    for (int m = 0; m < 2; m++) {
        const int base_m = m0 + wr*64 + m*32 + 4*lh2;
        #pragma unroll
        for (int n = 0; n < 2; n++) {
            const int gcol = n0 + wc*64 + n*32 + l32;
            #pragma unroll
            for (int reg = 0; reg < 16; reg++) {
                const int grow = base_m + (reg & 3) + 8*(reg >> 2);
                C[(size_t)(off + grow) * 2816 + gcol] = f2b(acc[m][n][reg]);
            }
        }
    }
}

__global__ __launch_bounds__(256) void gemm_down(
    const bf16* __restrict__ A, const bf16* __restrict__ BtAll,
    const int* __restrict__ offc, bf16* __restrict__ Y)
{
    const int e = blockIdx.z;
    const int off = offc[8 + e];
    const int padCnt = offc[9 + e] - off;
    const int m0 = blockIdx.x * 128;
    if (m0 >= padCnt) return;
    __shared__ __align__(16) bf16 As[128 * 64];
    __shared__ __align__(16) bf16 Bs[128 * 64];
    const int tid = threadIdx.x;
    const int lane = tid & 63, wid = tid >> 6;
    const int l32 = lane & 31, lh2 = lane >> 5;
    const int wr = wid >> 1, wc = wid & 1;
    const int n0 = blockIdx.y * 128;
    const bf16* Bt = BtAll + (size_t)e * 2048 * 1408;

    int srow[4], sslot[4];
    #pragma unroll
    for (int i = 0; i < 4; i++) {
        const int c = tid + 256*i;
        srow[i]  = c >> 3;
        sslot[i] = (((c & 7) ^ (srow[i] & 7)) << 3);
    }

    f32x16 acc[2][2];
    #pragma unroll
    for (int m = 0; m < 2; m++)
        #pragma unroll
        for (int n = 0; n < 2; n++)
            #pragma unroll
            for (int j = 0; j < 16; j++) acc[m][n][j] = 0.f;

    for (int k0 = 0; k0 < 1408; k0 += 64) {
        __syncthreads();
        #pragma unroll
        for (int i = 0; i < 4; i++) {
            load_lds16(A  + (size_t)(off + m0 + srow[i]) * 1408 + k0 + sslot[i], As + (tid + 256*i) * 8);
            load_lds16(Bt + (size_t)(n0 + srow[i]) * 1408 + k0 + sslot[i], Bs + (tid + 256*i) * 8);
        }
        __syncthreads();
        bf16x8 a[2][4], b[2][4];
        #pragma unroll
        for (int m = 0; m < 2; m++) {
            const int r = wr*64 + m*32 + l32, rx = r & 7;
            #pragma unroll
            for (int kk = 0; kk < 4; kk++)
                a[m][kk] = *(const bf16x8*)&As[r*64 + ((((kk<<1)|lh2) ^ rx) << 3)];
        }
        #pragma unroll
        for (int n = 0; n < 2; n++) {
            const int r = wc*64 + n*32 + l32, rx = r & 7;
            #pragma unroll
            for (int kk = 0; kk < 4; kk++)
                b[n][kk] = *(const bf16x8*)&Bs[r*64 + ((((kk<<1)|lh2) ^ rx) << 3)];
        }
        #pragma unroll
        for (int kk = 0; kk < 4; kk++)
            #pragma unroll
            for (int m = 0; m < 2; m++)
                #pragma unroll
                for (int n = 0; n < 2; n++)
                    acc[m][n] = __builtin_amdgcn_mfma_f32_32x32x16_bf16(a[m][kk], b[n][kk], acc[m][n], 0, 0, 0);
    }

    #pragma unroll
    for (int m = 0; m < 2; m++) {
        const int base_m = m0 + wr*64 + m*32 + 4*lh2;
        #pragma unroll
        for (int n = 0; n < 2; n++) {
            const int gcol = n0 + wc*64 + n*32 + l32;
            #pragma unroll
            for (int reg = 0; reg < 16; reg++) {
                const int grow = base_m + (reg & 3) + 8*(reg >> 2);
                Y[(size_t)(off + grow) * 2048 + gcol] = f2b(acc[m][n][reg]);
            }
        }
    }
}

// ---------------------------------------------------------------------------
__global__ void rope_table_k(float2* __restrict__ cs)
{
    const int i = blockIdx.x * 256 + threadIdx.x;   // < 65536
    const int s = i >> 6, d = i & 63;
    const float fr = (float)s * powf(1.0e6f, -(float)d * (1.0f / 64.0f));
    float c, sn;
    sincosf(fr, &sn, &c);
    cs[i] = make_float2(c, sn);
}

__global__ void rope_f32_k(float* __restrict__ qkv, const float2* __restrict__ cs)
{
    const int idx = blockIdx.x * 256 + threadIdx.x;
    const int d  = idx & 63;
    const int hh = (idx >> 6) & 15;
    const size_t base = (size_t)(idx >> 10) * 6144 + hh * HD;
    const int s = (idx >> 10) & 1023;
    const float2 t = cs[(s << 6) | d];
    const float c = t.x, sn = t.y;
    float q0 = qkv[base + d], q1 = qkv[base + d + 64];
    qkv[base + d]      = q0 * c - q1 * sn;
    qkv[base + d + 64] = q1 * c + q0 * sn;
    float k0 = qkv[base + 2048 + d], k1 = qkv[base + 2048 + d + 64];
    qkv[base + 2048 + d]      = k0 * c - k1 * sn;
    qkv[base + 2048 + d + 64] = k1 * c + k0 * sn;
}

// ---------------------------------------------------------------------------
__global__ __launch_bounds__(256) void transpose_v3_k(
    const float* __restrict__ qkv, bf16* __restrict__ vth, bf16* __restrict__ vtl)
{
    __shared__ float t[32][33];
    const int s0 = blockIdx.x * 32, d0 = blockIdx.y * 32;
    const int bh = blockIdx.z, b = bh >> 4, h = bh & 15;
    const int tx = threadIdx.x & 31, ty = threadIdx.x >> 5;
    const float* vb = qkv + ((size_t)b * SEQ) * 6144 + 4096 + h * HD;
    #pragma unroll
    for (int i = 0; i < 4; i++)
        t[ty + i*8][tx] = vb[(size_t)(s0 + ty + i*8) * 6144 + d0 + tx];
    __syncthreads();
    const size_t ob = ((size_t)bh * HD) * SEQ;
    #pragma unroll
    for (int i = 0; i < 4; i++) {
        float val = t[tx][ty + i*8];
        short hi, lo; split2(val, hi, lo);
        const size_t o = ob + (size_t)(d0 + ty + i*8) * SEQ + s0 + tx;
        vth[o] = __builtin_bit_cast(bf16, hi);
        vtl[o] = __builtin_bit_cast(bf16, lo);
    }
}

// ---------------------------------------------------------------------------
// Flash attention, causal, 2-limb, KVBLK=64, XOR-swizzled K/V/P LDS.
// LDS = 64 KB exactly: Ksh/Ksl [64][128], Vth/Vtl [128][64]; Ph/Pl alias Ksh
// (dead after QK; extra barrier between QK-reads and P-writes).
__global__ __launch_bounds__(256) void attn3_k(
    const float* __restrict__ qkv,
    const bf16* __restrict__ vthg, const bf16* __restrict__ vtlg,
    bf16* __restrict__ ctx2)
{
    __shared__ __align__(16) bf16 SM[32768];   // 64 KB
    bf16* Ksh = SM;            // [64][128] swizzled: elem(r,c) at r*128+(((c>>3)^(r&15))<<3)+(c&7)
    bf16* Ksl = SM + 8192;
    bf16* Vth = SM + 16384;    // [128][64] swizzled: elem(r,c) at r*64+(((c>>3)^(r&7))<<3)+(c&7)
    bf16* Vtl = SM + 24576;
    bf16* Ph  = SM;            // [4][16][64] swizzled like V (row&7) — aliases Ksh
    bf16* Pl  = SM + 4096;

    const int tid = threadIdx.x, lane = tid & 63, wid = tid >> 6;
    const int l16 = lane & 15, lh = lane >> 4;
    const int bh = blockIdx.y, b = bh >> 4, h = bh & 15;
    const int qbase = blockIdx.x * 64;
    const int qw = qbase + wid * 16;
    const float* qp = qkv + ((size_t)b * SEQ) * 6144 + h * HD;
    const float* kp = qkv + ((size_t)b * SEQ) * 6144 + 2048 + h * HD;
    const bf16* vph = vthg + ((size_t)bh * HD) * SEQ;
    const bf16* vpl = vtlg + ((size_t)bh * HD) * SEQ;

    bf16x8 aqh[4], aql[4];
    #pragma unroll
    for (int c = 0; c < 4; c++) {
        const float* qrow = qp + (size_t)(qw + l16) * 6144 + c*32 + lh*8;
        #pragma unroll
        for (int u = 0; u < 8; u++) {
            short hi, lo; split2(qrow[u], hi, lo);
            aqh[c][u] = hi; aql[c][u] = lo;
        }
    }

    f32x4 o[8];
    #pragma unroll
    for (int n = 0; n < 8; n++) o[n] = (f32x4){0.f, 0.f, 0.f, 0.f};
    float mj[4], lj[4];
    #pragma unroll
    for (int j = 0; j < 4; j++) { mj[j] = -1e30f; lj[j] = 0.f; }

    const int kr = tid >> 2;          // K stage row 0..63
    const int kc = (tid & 3) * 32;    // col base
    const int krx = kr & 15;
    const int kt_end = blockIdx.x + 1;
    for (int kt = 0; kt < kt_end; ++kt) {
        const int kv0 = kt * 64;
        __syncthreads();
        // K stage: fp32 -> split -> swizzled LDS (per-lane ds writes)
        {
            const float* krow = kp + (size_t)(kv0 + kr) * 6144 + kc;
            #pragma unroll
            for (int u = 0; u < 8; u++) {
                float4 kv4 = *(const float4*)(krow + u*4);
                short h0, l0, h1, l1, h2s, l2s, h3, l3;
                split2(kv4.x, h0, l0); split2(kv4.y, h1, l1);
                split2(kv4.z, h2s, l2s); split2(kv4.w, h3, l3);
                bf16x4 h4, l4;
                h4[0] = h0; h4[1] = h1; h4[2] = h2s; h4[3] = h3;
                l4[0] = l0; l4[1] = l1; l4[2] = l2s; l4[3] = l3;
                const int s = (((kc + u*4) >> 3) ^ krx);
                const int dst = kr*128 + (s << 3) + ((u & 1) * 4);
                *(bf16x4*)&Ksh[dst] = h4;
                *(bf16x4*)&Ksl[dst] = l4;
            }
        }
        // V stage: pre-swizzled global source, linear LDS dest (rule #21)
        #pragma unroll
        for (int i = 0; i < 4; i++) {
            const int c = tid + 256*i;
            const int row = c >> 3, sl = (c & 7) ^ (row & 7);
            load_lds16(vph + (size_t)row * SEQ + kv0 + (sl << 3), Vth + c*8);
            load_lds16(vpl + (size_t)row * SEQ + kv0 + (sl << 3), Vtl + c*8);
        }
        __syncthreads();

        // QK^T: 4 col-groups x 4 c x 3 limb products
        f32x4 sg[4];
        #pragma unroll
        for (int g = 0; g < 4; g++) sg[g] = (f32x4){0.f,0.f,0.f,0.f};
        #pragma unroll
        for (int c = 0; c < 4; c++) {
            #pragma unroll
            for (int g = 0; g < 4; g++) {
                const int row = l16 + g*16;
                const int sl = (((c*4 + lh) ^ (row & 15)) << 3);
                bf16x8 bkh = *(const bf16x8*)&Ksh[row*128 + sl];
                bf16x8 bkl = *(const bf16x8*)&Ksl[row*128 + sl];
                sg[g] = __builtin_amdgcn_mfma_f32_16x16x32_bf16(aqh[c], bkh, sg[g], 0, 0, 0);
                sg[g] = __builtin_amdgcn_mfma_f32_16x16x32_bf16(aql[c], bkh, sg[g], 0, 0, 0);
                sg[g] = __builtin_amdgcn_mfma_f32_16x16x32_bf16(aqh[c], bkl, sg[g], 0, 0, 0);
            }
        }
        __syncthreads();   // all K reads done before P overwrites Ksh region

        const float scale = 0.08838834764831845f;  // 1/sqrt(128)
        #pragma unroll
        for (int j = 0; j < 4; j++) {
            const int qrow = qw + lh*4 + j;
            float sv[4];
            #pragma unroll
            for (int g = 0; g < 4; g++) {
                sv[g] = sg[g][j] * scale;
                if (kv0 + l16 + g*16 > qrow) sv[g] = -1e30f;
            }
            float mx = fmaxf(fmaxf(sv[0], sv[1]), fmaxf(sv[2], sv[3]));
            #pragma unroll
            for (int off = 1; off < 16; off <<= 1) mx = fmaxf(mx, __shfl_xor(mx, off, 16));
            const float nm = fmaxf(mj[j], mx);
            const float al = __expf(mj[j] - nm);
            float pg[4], rs = 0.f;
            #pragma unroll
            for (int g = 0; g < 4; g++) { pg[g] = __expf(sv[g] - nm); rs += pg[g]; }
            #pragma unroll
            for (int off = 1; off < 16; off <<= 1) rs += __shfl_xor(rs, off, 16);
            lj[j] = lj[j] * al + rs;
            mj[j] = nm;
            #pragma unroll
            for (int n = 0; n < 8; n++) o[n][j] *= al;
            const int prow = lh*4 + j;
            #pragma unroll
            for (int g = 0; g < 4; g++) {
                short hi, lo; split2(pg[g], hi, lo);
                const int col = l16 + g*16;
                const int addr = wid*1024 + prow*64 + ((((col >> 3) ^ (prow & 7)) << 3)) + (col & 7);
                Ph[addr] = __builtin_bit_cast(bf16, hi);
                Pl[addr] = __builtin_bit_cast(bf16, lo);
            }
        }
        // P is warp-private (wave-ordered LDS) — no barrier needed before PV.
        #pragma unroll
        for (int ks = 0; ks < 2; ks++) {
            const int psl = (((ks*4 + lh) ^ (l16 & 7)) << 3);
            bf16x8 aph = *(const bf16x8*)&Ph[wid*1024 + l16*64 + psl];
            bf16x8 apl = *(const bf16x8*)&Pl[wid*1024 + l16*64 + psl];
            #pragma unroll
            for (int n = 0; n < 8; n++) {
                const int row = n*16 + l16;
                const int vsl = (((ks*4 + lh) ^ (row & 7)) << 3);
                bf16x8 bvh = *(const bf16x8*)&Vth[row*64 + vsl];
                bf16x8 bvl = *(const bf16x8*)&Vtl[row*64 + vsl];
                o[n] = __builtin_amdgcn_mfma_f32_16x16x32_bf16(aph, bvh, o[n], 0, 0, 0);
                o[n] = __builtin_amdgcn_mfma_f32_16x16x32_bf16(apl, bvh, o[n], 0, 0, 0);
                o[n] = __builtin_amdgcn_mfma_f32_16x16x32_bf16(aph, bvl, o[n], 0, 0, 0);
            }
        }
    }

    float inv[4];
    #pragma unroll
    for (int j = 0; j < 4; j++) inv[j] = 1.0f / lj[j];
    #pragma unroll
    for (int n = 0; n < 8; n++)
        #pragma unroll
        for (int j = 0; j < 4; j++) {
            const float v = o[n][j] * inv[j];
            short hi, lo; split2(v, hi, lo);
            const size_t base = ((size_t)b * SEQ + (qw + lh*4 + j)) * 4096 + h * HD + n*16 + l16;
            ctx2[base]        = __builtin_bit_cast(bf16, hi);
            ctx2[base + 2048] = __builtin_bit_cast(bf16, lo);
        }
}

// ---------------------------------------------------------------------------
// x1 = x + xp0+xp1+xp2; h2 = rms(x1)*w; PLUS router (fp32 logits, top-2) and
// shared-expert sigmoid gate — one pass over x1, one block per token.
__global__ __launch_bounds__(256) void combine_rms_router_k(
    const float* __restrict__ x, const float* __restrict__ xp,
    const float* __restrict__ wln, const float* __restrict__ wr,
    const float* __restrict__ weg,
    float* __restrict__ x1, bf16* __restrict__ h2,
    float* __restrict__ comb, float* __restrict__ sigeg)
{
    const int row = blockIdx.x, tid = threadIdx.x;
    const size_t rb = (size_t)row * HIDDEN;
    const long zs = (long)TOKENS * HIDDEN;
    __shared__ float ps[4];
    __shared__ float pacc[4][9];
    float4 v[2];
    #pragma unroll
    for (int u = 0; u < 2; u++) {
        const int i = tid + u * 256;
        float4 a  = ((const float4*)(x + rb))[i];
        float4 p0 = ((const float4*)(xp + rb))[i];
        float4 p1 = ((const float4*)(xp + zs + rb))[i];
        float4 p2 = ((const float4*)(xp + 2*zs + rb))[i];
        v[u].x = a.x + p0.x + p1.x + p2.x;
        v[u].y = a.y + p0.y + p1.y + p2.y;
        v[u].z = a.z + p0.z + p1.z + p2.z;
        v[u].w = a.w + p0.w + p1.w + p2.w;
        ((float4*)(x1 + rb))[i] = v[u];
    }
    float ss = v[0].x*v[0].x + v[0].y*v[0].y + v[0].z*v[0].z + v[0].w*v[0].w
             + v[1].x*v[1].x + v[1].y*v[1].y + v[1].z*v[1].z + v[1].w*v[1].w;
    #pragma unroll
    for (int off = 1; off < 64; off <<= 1) ss += __shfl_xor(ss, off);
    if ((tid & 63) == 0) ps[tid >> 6] = ss;
    __syncthreads();
    const float tot = ps[0] + ps[1] + ps[2] + ps[3];
    const float r = rsqrtf(tot * (1.0f / HIDDEN) + 1e-6f);

    float acc[9];
    #pragma unroll
    for (int e = 0; e < 9; e++) acc[e] = 0.f;
    #pragma unroll
    for (int u = 0; u < 2; u++) {
        const int i = (tid + u * 256) * 4;
        const float vv[4] = {v[u].x, v[u].y, v[u].z, v[u].w};
        #pragma unroll
        for (int q = 0; q < 4; q++) {
            const float hv = vv[q] * r * wln[i + q];
            h2[rb + i + q] = f2b(hv);
            const float* wrow = wr + (size_t)(i + q) * 8;
            #pragma unroll
            for (int e = 0; e < 8; e++) acc[e] += hv * wrow[e];
            acc[8] += hv * weg[i + q];
        }
    }
    #pragma unroll
    for (int e = 0; e < 9; e++)
        #pragma unroll
        for (int off = 1; off < 64; off <<= 1) acc[e] += __shfl_xor(acc[e], off);
    if ((tid & 63) == 0)
        #pragma unroll
        for (int e = 0; e < 9; e++) pacc[tid >> 6][e] = acc[e];
    __syncthreads();
    if (tid == 0) {
        float lg[9];
        #pragma unroll
        for (int e = 0; e < 9; e++) lg[e] = pacc[0][e] + pacc[1][e] + pacc[2][e] + pacc[3][e];
        float mx = lg[0];
        #pragma unroll
        for (int e = 1; e < 8; e++) mx = fmaxf(mx, lg[e]);
        float p[8], s = 0.f;
        #pragma unroll
        for (int e = 0; e < 8; e++) { p[e] = expf(lg[e] - mx); s += p[e]; }
        const float invs = 1.0f / s;
        #pragma unroll
        for (int e = 0; e < 8; e++) p[e] *= invs;
        int i1 = 0;
        #pragma unroll
        for (int e = 1; e < 8; e++) if (p[e] > p[i1]) i1 = e;
        int i2 = (i1 == 0) ? 1 : 0;
        #pragma unroll
        for (int e = 0; e < 8; e++) if (e != i1 && p[e] > p[i2]) i2 = e;
        #pragma unroll
        for (int e = 0; e < 8; e++)
            comb[(size_t)row * 8 + e] = (e == i1 || e == i2) ? p[e] : 0.f;
        sigeg[row] = 1.0f / (1.0f + expf(-lg[8]));
    }
}

// ---------------------------------------------------------------------------
__global__ __launch_bounds__(256) void count_fill_k(
    const float* __restrict__ comb, int* __restrict__ offc, int* __restrict__ perm,
    float* __restrict__ scale, int* __restrict__ inv)
{
    __shared__ int cnt[8], off[9], fil[8];
    const int tid = threadIdx.x;
    if (tid < 8) { cnt[tid] = 0; fil[tid] = 0; }
    __syncthreads();
    for (int t = tid; t < TOKENS; t += 256)
        #pragma unroll
        for (int e = 0; e < 8; e++)
            if (comb[(size_t)t * 8 + e] > 0.f) atomicAdd(&cnt[e], 1);
    __syncthreads();
    if (tid == 0) {
        off[0] = 0;
        for (int e = 0; e < 8; e++) off[e+1] = off[e] + ((cnt[e] + 127) & ~127);
    }
    __syncthreads();
    for (int i = tid; i < MAXROWS; i += 256) { perm[i] = -1; scale[i] = 0.f; }
    __syncthreads();
    for (int t = tid; t < TOKENS; t += 256) {
        int j = 0;
        #pragma unroll
        for (int e = 0; e < 8; e++) {
            const float c = comb[(size_t)t * 8 + e];
            if (c > 0.f) {
                int s = atomicAdd(&fil[e], 1);
                int slot = off[e] + s;
                perm[slot] = t;
                scale[slot] = c;
                inv[t * 2 + j] = slot;
                j++;
            }
        }
    }
    __syncthreads();
    if (tid < 9) offc[8 + tid] = off[tid];
}

// ---------------------------------------------------------------------------
__global__ void silu_k(const bf16* __restrict__ g, bf16* __restrict__ a,
                       const float* __restrict__ rowScale,
                       int I, int ldg, int rowsConst, const int* __restrict__ rowsPtr)
{
    const int idx = (blockIdx.x * 256 + threadIdx.x) * 4;
    const int rows = rowsPtr ? *rowsPtr : rowsConst;
    const int row = idx / I;
    if (row >= rows) return;
    const int col = idx - row * I;
    const float s = rowScale[row];
    const bf16* gr = g + (size_t)row * ldg + col;
    bf16* ar = a + (size_t)row * I + col;
    #pragma unroll
    for (int c = 0; c < 4; c++) {
        const float gv = b2f(gr[c]), uv = b2f(gr[I + c]);
        ar[c] = f2b(s * gv / (1.0f + __expf(-gv)) * uv);
    }
}

// ---------------------------------------------------------------------------
__global__ void final_k(const float* __restrict__ x1, const bf16* __restrict__ y,
                        const int* __restrict__ inv, const float* __restrict__ ysh,
                        float* __restrict__ out)
{
    const int i = blockIdx.x * 256 + threadIdx.x;   // float4 index
    const int t = i >> 9;
    const int col = (i & 511) * 4;
    const int s0 = inv[t*2], s1 = inv[t*2 + 1];
    const long zs = (long)TOKENS * HIDDEN;
    float4 a  = ((const float4*)x1)[i];
    float4 h0 = ((const float4*)ysh)[i];
    float4 h1 = ((const float4*)(ysh + zs))[i];
    const bf16* y0 = y + (size_t)s0 * 2048 + col;
    const bf16* y1 = y + (size_t)s1 * 2048 + col;
    float4 r;
    r.x = a.x + h0.x + h1.x + b2f(y0[0]) + b2f(y1[0]);
    r.y = a.y + h0.y + h1.y + b2f(y0[1]) + b2f(y1[1]);
    r.z = a.z + h0.z + h1.z + b2f(y0[2]) + b2f(y1[2]);
    r.w = a.w + h0.w + h1.w + b2f(y0[3]) + b2f(y1[3]);
    ((float4*)out)[i] = r;
}

// ---------------------------------------------------------------------------
extern "C" void kernel_launch(void* const* d_in, const int* in_sizes, int n_in,
                              void* d_out, int out_size, void* d_ws, size_t ws_size,
                              hipStream_t stream)
{
    const float* x     = (const float*)d_in[0];
    const float* w_ln1 = (const float*)d_in[1];
    const float* wq    = (const float*)d_in[2];
    const float* bq    = (const float*)d_in[3];
    const float* wk    = (const float*)d_in[4];
    const float* bk    = (const float*)d_in[5];
    const float* wv    = (const float*)d_in[6];
    const float* bv    = (const float*)d_in[7];
    const float* wo    = (const float*)d_in[8];
    const float* w_ln2 = (const float*)d_in[9];
    const float* w_rt  = (const float*)d_in[10];
    const float* w_ge  = (const float*)d_in[11];
    const float* w_ue  = (const float*)d_in[12];
    const float* w_de  = (const float*)d_in[13];
    const float* w_sg  = (const float*)d_in[14];
    const float* w_su  = (const float*)d_in[15];
    const float* w_sd  = (const float*)d_in[16];
    const float* w_eg  = (const float*)d_in[17];
    float* out = (float*)d_out;
    (void)in_sizes; (void)n_in; (void)out_size; (void)ws_size;

    char* ws = (char*)d_ws;
    // persistent
    float* x1    = (float*)(ws + 0);
    bf16*  h2    = (bf16*)(ws + 16777216);
    float* comb  = (float*)(ws + 25165824);
    float* seg   = (float*)(ws + 25231360);
    int*   offc  = (int*)(ws + 25239552);
    float* scale = (float*)(ws + 25243648);
    int*   perm  = (int*)(ws + 25276416);
    int*   inv   = (int*)(ws + 25297920);
    float* bqkv  = (float*)(ws + 25314304);
    float2* ropecs = (float2*)(ws + 25338880);          // 512KB -> ends 25863168
    const size_t S = 25863168;
    // phase A
    bf16*  hcat  = (bf16*)(ws + S);
    bf16*  wtqkv = (bf16*)(ws + S + 16777216);
    float* qkvf  = (float*)(ws + S + 67108864);          // ends S+117440512
    bf16*  wt3o  = (bf16*)(ws + S + 117440512);          // 16.78M (moved: written early)
    bf16*  vth   = (bf16*)(ws + S);
    bf16*  vtl   = (bf16*)(ws + S + 8388608);
    bf16*  ctx2  = (bf16*)(ws + S + 16777216);
    float* xp    = (float*)(ws + S + 50331648);          // 3x16.78M
    // phase B
    bf16*  wtgu  = (bf16*)(ws + S);
    bf16*  gb    = (bf16*)(ws + S + 92274688);
    bf16*  ab    = (bf16*)(ws + S);
    bf16*  wtd   = (bf16*)(ws + S + 14417920);
    bf16*  ymoe  = (bf16*)(ws + S + 60555264);
    // phase C
    bf16*  wtshgu = (bf16*)(ws + S);
    bf16*  gsh    = (bf16*)(ws + S + 81526784);
    bf16*  ash    = (bf16*)(ws + S);
    bf16*  wtshd  = (bf16*)(ws + S + 23068672);
    float* ysh    = (float*)(ws + S + 81526784);

    // 1) RMSNorm1 -> hcat; QKV bias concat; rope table
    rmsnorm3_k<<<TOKENS, 256, 0, stream>>>(x, w_ln1, hcat);
    (void)hipMemcpyAsync(bqkv,        bq, 8192, hipMemcpyDeviceToDevice, stream);
    (void)hipMemcpyAsync(bqkv + 2048, bk, 8192, hipMemcpyDeviceToDevice, stream);
    (void)hipMemcpyAsync(bqkv + 4096, bv, 8192, hipMemcpyDeviceToDevice, stream);
    rope_table_k<<<256, 256, 0, stream>>>(ropecs);

    // 2) All 4 attention weight transposes in one launch; fused QKV GEMM
    transpose_qkvo_k<<<dim3(64, 64, 4), 256, 0, stream>>>(wq, wk, wv, wo, wtqkv, wt3o);
    gemm_bt<<<dim3(16, 48, 1), 256, 0, stream>>>(hcat, wtqkv, qkvf, nullptr, bqkv,
                                                 TOKENS, 6144, K3, 4096, 4096, 6144, 0, 1, 5);

    // 3) RoPE + V transpose/split + attention (KVBLK=64, swizzled)
    rope_f32_k<<<8192, 256, 0, stream>>>(qkvf, ropecs);
    transpose_v3_k<<<dim3(32, 4, 32), 256, 0, stream>>>(qkvf, vth, vtl);
    attn3_k<<<dim3(16, 32), 256, 0, stream>>>(qkvf, vth, vtl, ctx2);

    // 4) O-proj (limb3, split-K z=3, plain stores) + fused combine/rms/router
    gemm_bt<<<dim3(16, 16, 3), 256, 0, stream>>>(ctx2, wt3o, xp, nullptr, nullptr,
                                                 TOKENS, HIDDEN, 2048, 4096, 4096, 2048,
                                                 (long)TOKENS * HIDDEN, 1, 4);
    combine_rms_router_k<<<TOKENS, 256, 0, stream>>>(x, xp, w_ln2, w_rt, w_eg,
                                                     x1, h2, comb, seg);
    count_fill_k<<<1, 256, 0, stream>>>(comb, offc, perm, scale, inv);

    // 5) Sparse MoE
    transpose_moegu_k<<<dim3(44, 64, 16), 256, 0, stream>>>(w_ge, w_ue, wtgu);
    gemm_gu<<<dim3(MAXROWS/128, 22, 8), 256, 0, stream>>>(h2, wtgu, offc, perm, gb);
    silu_k<<<(MAXROWS * MOE_I) / 1024, 256, 0, stream>>>(gb, ab, scale, MOE_I, 2816, 0, offc + 16);
    transpose_wz<<<dim3(64, 44, 8), 256, 0, stream>>>(w_de, wtd, MOE_I, HIDDEN, 0,
                                                      (long)MOE_I*HIDDEN, (long)HIDDEN*MOE_I);
    gemm_down<<<dim3(MAXROWS/128, 16, 8), 256, 0, stream>>>(ab, wtd, offc, ymoe);

    // 6) Shared expert
    transpose_shgu_k<<<dim3(176, 64, 2), 256, 0, stream>>>(w_sg, w_su, wtshgu);
    gemm_bt<<<dim3(16, 88, 1), 256, 0, stream>>>(h2, wtshgu, nullptr, gsh, nullptr,
                                                 TOKENS, 2*SH_I, HIDDEN, HIDDEN, HIDDEN, 2*SH_I, 0, 0, 0);
    silu_k<<<(TOKENS * SH_I) / 1024, 256, 0, stream>>>(gsh, ash, seg, SH_I, 2*SH_I, TOKENS, nullptr);
    transpose_wz<<<dim3(64, 176, 1), 256, 0, stream>>>(w_sd, wtshd, SH_I, HIDDEN, 0, 0, 0);
    gemm_bt<<<dim3(16, 16, 2), 256, 0, stream>>>(ash, wtshd, ysh, nullptr, nullptr,
                                                 TOKENS, HIDDEN, SH_I/2, SH_I, SH_I, 2048,
                                                 (long)TOKENS * HIDDEN, 0, 4);

    // 7) Final gather-sum
    final_k<<<(TOKENS * HIDDEN) / 1024, 256, 0, stream>>>(x1, ymoe, inv, ysh, out);
}